// Round 8
// baseline (809.095 us; speedup 1.0000x reference)
//
#include <hip/hip_runtime.h>

typedef __attribute__((ext_vector_type(8))) _Float16 half8;
typedef __attribute__((ext_vector_type(4))) _Float16 half4;
typedef __attribute__((ext_vector_type(4))) float f32x4;

constexpr int Bn = 4;
constexpr int Nn = 160;
constexpr int SEGN = Bn * Nn * Nn;        // 102400 segments
constexpr unsigned NEG_FLIP = 0x007FFFFFu; // flip(-inf)

__device__ __forceinline__ unsigned flipf(float f) {
  unsigned u = __float_as_uint(f);
  return (u & 0x80000000u) ? ~u : (u | 0x80000000u);
}
__device__ __forceinline__ float unflipf(unsigned s) {
  return __uint_as_float((s & 0x80000000u) ? (s ^ 0x80000000u) : ~s);
}

// ---------------- init segment buffer to flip(-inf) ----------------
__global__ void k_init(uint4* __restrict__ seg, int n4) {
  int i = blockIdx.x * blockDim.x + threadIdx.x;
  int stride = gridDim.x * blockDim.x;
  uint4 v = make_uint4(NEG_FLIP, NEG_FLIP, NEG_FLIP, NEG_FLIP);
  for (; i < n4; i += stride) seg[i] = v;
}

// ------- weight prepass: f32 [K][N] -> f16 chunk-blocked [k/32][N][32] -------
// (wf3: [512][16] -> [16][512] plain transpose)
__global__ void k_prep(const float* __restrict__ w1, const float* __restrict__ w2,
                       const float* __restrict__ w3, const float* __restrict__ wf1,
                       const float* __restrict__ wf2, const float* __restrict__ wf3,
                       _Float16* __restrict__ o1, _Float16* __restrict__ o2,
                       _Float16* __restrict__ o3, _Float16* __restrict__ of1,
                       _Float16* __restrict__ of2, _Float16* __restrict__ of3) {
  int t = blockIdx.x * 256 + threadIdx.x;
  const float* src; _Float16* dst; int N, local; bool is3 = false;
  if (t < 32768)       { src = w1;  dst = o1;  N = 256; local = t; }
  else if (t < 163840) { src = w2;  dst = o2;  N = 512; local = t - 32768; }
  else if (t < 425984) { src = w3;  dst = o3;  N = 512; local = t - 163840; }
  else if (t < 688128) { src = wf1; dst = of1; N = 512; local = t - 425984; }
  else if (t < 950272) { src = wf2; dst = of2; N = 512; local = t - 688128; }
  else if (t < 958464) { src = wf3; dst = of3; N = 16;  local = t - 950272; is3 = true; }
  else return;
  int k = local / N;
  int n = local - k * N;
  if (is3) dst[n * 512 + k] = (_Float16)src[local];
  else dst[(size_t)((k >> 5) * N + n) * 32 + (k & 31)] = (_Float16)src[local];
}

// ---------------- MFMA slice, B direct from global (L2-resident) ----------------
// A in LDS: f16 [M][K], rowB = 2K bytes, byte ^= ((row&7)<<4).
// W chunk-blocked global [c][NSTRIDE][32] f16: a wave's (n-tile, kg) half8 is a
// coalesced 16B slice of a contiguous 1KB region.
template <int MT, int K, int C0, int CN, int NSTRIDE, int NT>
__device__ __forceinline__ void do_slice(const _Float16* __restrict__ wt,
                                         const char* a_base, int nbase,
                                         f32x4 (&acc)[MT][NT], int tid) {
  constexpr int rowB = K * 2;
  const int w = tid >> 6, lane = tid & 63, ln15 = lane & 15, kg = lane >> 4;
  const char* wb = (const char*)wt;
#pragma unroll
  for (int c = 0; c < CN; ++c) {
    half8 a[MT], b[NT];
#pragma unroll
    for (int nt = 0; nt < NT; ++nt) {
      int n = nbase + (w * NT + nt) * 16 + ln15;
      b[nt] = *(const half8*)(wb + (size_t)(C0 + c) * (NSTRIDE * 64) + n * 64 + kg * 16);
    }
#pragma unroll
    for (int mt = 0; mt < MT; ++mt) {
      int row = mt * 16 + ln15;
      int byte = (row * rowB + c * 64 + kg * 16) ^ ((row & 7) << 4);
      a[mt] = *(const half8*)(a_base + byte);
    }
#pragma unroll
    for (int mt = 0; mt < MT; ++mt)
#pragma unroll
      for (int nt = 0; nt < NT; ++nt)
        acc[mt][nt] = __builtin_amdgcn_mfma_f32_16x16x32_f16(a[mt], b[nt], acc[mt][nt], 0, 0, 0);
  }
}

template <int MT, int NT>
__device__ __forceinline__ void init_accn(const float* __restrict__ bias, int nbase,
                                          f32x4 (&acc)[MT][NT], int tid) {
  const int w = tid >> 6, ln15 = tid & 15;
#pragma unroll
  for (int nt = 0; nt < NT; ++nt) {
    float bv = bias[nbase + (w * NT + nt) * 16 + ln15];
    f32x4 s = {bv, bv, bv, bv};
#pragma unroll
    for (int mt = 0; mt < MT; ++mt) acc[mt][nt] = s;
  }
}

// C layout: col = lane&15, row = (lane>>4)*4 + j  [m89 verified]
template <int MT, int NT, bool RELU>
__device__ __forceinline__ void store_hn(char* h, int rowB, int nbase,
                                         const f32x4 (&acc)[MT][NT], int tid) {
  const int w = tid >> 6, lane = tid & 63, ln15 = lane & 15, kg = lane >> 4;
#pragma unroll
  for (int mt = 0; mt < MT; ++mt)
#pragma unroll
    for (int nt = 0; nt < NT; ++nt)
#pragma unroll
      for (int j = 0; j < 4; ++j) {
        int row = mt * 16 + kg * 4 + j;
        int n = nbase + (w * NT + nt) * 16 + ln15;
        float v = acc[mt][nt][j];
        if (RELU) v = fmaxf(v, 0.f);
        *(_Float16*)(h + ((row * rowB + n * 2) ^ ((row & 7) << 4))) = (_Float16)v;
      }
}

// ---------------- fused edge MLP (MFMA) + scatter-max ----------------
// M=32 edges/block, 512 threads. LDS 48KB -> 3 blocks/CU (24 waves/CU, 6/SIMD).
// Per-wave acc halves vs M=64 (~70-80 VGPR, under the 85 cap for 6 waves/SIMD).
__global__ __launch_bounds__(512, 3) void k_edge(
    const int* __restrict__ rel_type, const float* __restrict__ rel_error,
    const int* __restrict__ edge_pos, const int* __restrict__ rel_row,
    const float* __restrict__ type_tab, const float* __restrict__ pos_tab,
    const _Float16* __restrict__ w1t, const float* __restrict__ b1,
    const _Float16* __restrict__ w2t, const float* __restrict__ b2,
    const _Float16* __restrict__ w3t, const float* __restrict__ b3,
    unsigned* __restrict__ seg, int E) {
  __shared__ __align__(16) char smem[49152];
  __shared__ int rr[32];
  char* h1 = smem;            // [32][256] f16, rowB 512 (16KB)
  char* h2 = smem + 16384;    // [32][512] f16, rowB 1024 (32KB)
  char* e  = smem + 16384;    // [32][128] f16, rowB 256 (8KB, dead before h2 written)

  const int tid = threadIdx.x;
  const int e0 = blockIdx.x * 32;

  // ---- build e tile: 16 threads/row, one half8 each (col split 120/128 is 8-aligned) ----
  {
    int r = tid >> 4, c8 = tid & 15;
    int re = min(e0 + r, E - 1);
    int rt = rel_type[re];
    int ep = edge_pos[re];
    half8 hv;
#pragma unroll
    for (int q = 0; q < 8; ++q) {
      int cc = c8 * 8 + q;
      float v = (cc < 120) ? (rt ? type_tab[rt * 120 + cc] : 0.f)
                           : rel_error[(size_t)re * 8 + (cc - 120)];
      v += pos_tab[ep * 128 + cc];
      hv[q] = (_Float16)v;
    }
    int byte = (r * 256 + c8 * 16) ^ ((r & 7) << 4);
    *(half8*)(e + byte) = hv;
    if (tid < 32) rr[tid] = rel_row[min(e0 + tid, E - 1)];
  }
  __syncthreads();

  {  // layer 1: [32x128]@[128x256] + relu -> h1
    f32x4 acc[2][2];
    init_accn<2, 2>(b1, 0, acc, tid);
    do_slice<2, 128, 0, 4, 256, 2>(w1t, e, 0, acc, tid);
    store_hn<2, 2, true>(h1, 512, 0, acc, tid);
  }
  __syncthreads();
  {  // layer 2: [32x256]@[256x512] + relu -> h2 (overwrites e region, reads drained)
    f32x4 acc[2][4];
    init_accn<2, 4>(b2, 0, acc, tid);
    do_slice<2, 256, 0, 8, 512, 4>(w2t, h1, 0, acc, tid);
    store_hn<2, 4, true>(h2, 1024, 0, acc, tid);
  }
  __syncthreads();
  {  // layer 3: [32x512]@[512x512] -> scatter-max
    f32x4 acc[2][4];
    init_accn<2, 4>(b3, 0, acc, tid);
    do_slice<2, 512, 0, 16, 512, 4>(w3t, h2, 0, acc, tid);

    const int w = tid >> 6, lane = tid & 63, ln15 = lane & 15, kg = lane >> 4;
#pragma unroll
    for (int mt = 0; mt < 2; ++mt) {
      int rbase = mt * 16 + kg * 4;
      float m[4];
      int cur = rr[rbase];
#pragma unroll
      for (int nt = 0; nt < 4; ++nt) m[nt] = acc[mt][nt][0];
#pragma unroll
      for (int j = 1; j < 4; ++j) {
        int rj = rr[rbase + j];
        if (rj == cur) {
#pragma unroll
          for (int nt = 0; nt < 4; ++nt) m[nt] = fmaxf(m[nt], acc[mt][nt][j]);
        } else {
          unsigned* dst = seg + (size_t)cur * 512;
#pragma unroll
          for (int nt = 0; nt < 4; ++nt)
            atomicMax(dst + (w * 4 + nt) * 16 + ln15, flipf(m[nt]));
          cur = rj;
#pragma unroll
          for (int nt = 0; nt < 4; ++nt) m[nt] = acc[mt][nt][j];
        }
      }
      unsigned* dst = seg + (size_t)cur * 512;
#pragma unroll
      for (int nt = 0; nt < 4; ++nt)
        atomicMax(dst + (w * 4 + nt) * 16 + ln15, flipf(m[nt]));
    }
  }
}

// ---- in-register epilogue: relu -> LN (shfl + 2-stage LDS) -> store f16 ----
__device__ __forceinline__ void epi_ln_store(f32x4 (&acc)[4][4], char* dst,
                                             float* st1, float* st2,
                                             float* stM, float* stR,
                                             const float* __restrict__ g,
                                             const float* __restrict__ be, int tid) {
  const int w = tid >> 6, lane = tid & 63, ln15 = lane & 15, kg = lane >> 4;
#pragma unroll
  for (int mt = 0; mt < 4; ++mt)
#pragma unroll
    for (int nt = 0; nt < 4; ++nt)
#pragma unroll
      for (int j = 0; j < 4; ++j) acc[mt][nt][j] = fmaxf(acc[mt][nt][j], 0.f);
#pragma unroll
  for (int mt = 0; mt < 4; ++mt)
#pragma unroll
    for (int j = 0; j < 4; ++j) {
      float a = 0.f, b = 0.f;
#pragma unroll
      for (int nt = 0; nt < 4; ++nt) { float v = acc[mt][nt][j]; a += v; b += v * v; }
#pragma unroll
      for (int m = 1; m < 16; m <<= 1) { a += __shfl_xor(a, m); b += __shfl_xor(b, m); }
      if (ln15 == 0) {
        int r = mt * 16 + kg * 4 + j;
        st1[w * 64 + r] = a;
        st2[w * 64 + r] = b;
      }
    }
  __syncthreads();
  if (tid < 64) {
    float a = 0.f, b = 0.f;
#pragma unroll
    for (int ww = 0; ww < 8; ++ww) { a += st1[ww * 64 + tid]; b += st2[ww * 64 + tid]; }
    float mean = a * (1.f / 512.f);
    float var = b * (1.f / 512.f) - mean * mean;
    stM[tid] = mean;
    stR[tid] = rsqrtf(var + 1e-5f);
  }
  __syncthreads();
  float gv[4], bv[4];
#pragma unroll
  for (int nt = 0; nt < 4; ++nt) {
    int n = (w * 4 + nt) * 16 + ln15;
    gv[nt] = g[n]; bv[nt] = be[n];
  }
#pragma unroll
  for (int mt = 0; mt < 4; ++mt)
#pragma unroll
    for (int j = 0; j < 4; ++j) {
      int r = mt * 16 + kg * 4 + j;
      float mean = stM[r], rs = stR[r];
#pragma unroll
      for (int nt = 0; nt < 4; ++nt) {
        int n = (w * 4 + nt) * 16 + ln15;
        float v = (acc[mt][nt][j] - mean) * rs * gv[nt] + bv[nt];
        *(_Float16*)(dst + ((r * 1024 + n * 2) ^ ((r & 7) << 4))) = (_Float16)v;
      }
    }
  __syncthreads();
}

// ---------------- fused FC: seg+dist -> LN -> fc1 -> LN -> fc2 -> LN -> fc3 ----------------
// launch_bounds(512, 2): 2 blocks/CU -> 128-VGPR budget (r4: (512,4) => 64 VGPR, spilled).
__global__ __launch_bounds__(512, 2) void k_fc(
    const unsigned* __restrict__ segin, const int* __restrict__ dist,
    const float* __restrict__ dist_tab,
    const float* __restrict__ g1, const float* __restrict__ be1,
    const _Float16* __restrict__ wf1t, const float* __restrict__ bf1,
    const float* __restrict__ g2, const float* __restrict__ be2,
    const _Float16* __restrict__ wf2t, const float* __restrict__ bf2,
    const float* __restrict__ g3, const float* __restrict__ be3,
    const _Float16* __restrict__ wf3t, const float* __restrict__ bf3,
    float* __restrict__ x3) {
  __shared__ __align__(16) char bufA[65536];  // [64][512] f16, rowB 1024
  __shared__ float st1[512], st2[512];
  __shared__ float stM[64], stR[64];

  const int tid = threadIdx.x;
  const int r0 = blockIdx.x * 64;

  // ---- prologue: seg + dist emb -> relu -> LN1 -> bufA (f16, swizzled) ----
  {
    const int r = tid >> 3, cp = tid & 7;
    const int gr = r0 + r;
    int di = dist[gr];
    const float* dt = dist_tab + (size_t)di * 512;
    float s1 = 0.f, s2 = 0.f;
#pragma unroll
    for (int i = 0; i < 16; ++i) {
      int c = cp * 64 + i * 4;
      uint4 sv = *(const uint4*)(segin + (size_t)gr * 512 + c);
      float v0 = (sv.x == NEG_FLIP) ? 0.f : unflipf(sv.x);
      float v1 = (sv.y == NEG_FLIP) ? 0.f : unflipf(sv.y);
      float v2 = (sv.z == NEG_FLIP) ? 0.f : unflipf(sv.z);
      float v3 = (sv.w == NEG_FLIP) ? 0.f : unflipf(sv.w);
      if (di) { v0 += dt[c]; v1 += dt[c + 1]; v2 += dt[c + 2]; v3 += dt[c + 3]; }
      v0 = fmaxf(v0, 0.f); v1 = fmaxf(v1, 0.f); v2 = fmaxf(v2, 0.f); v3 = fmaxf(v3, 0.f);
      s1 += v0 + v1 + v2 + v3;
      s2 += v0 * v0 + v1 * v1 + v2 * v2 + v3 * v3;
      half4 hv = {(_Float16)v0, (_Float16)v1, (_Float16)v2, (_Float16)v3};
      *(half4*)(bufA + ((r * 1024 + c * 2) ^ ((r & 7) << 4))) = hv;
    }
#pragma unroll
    for (int o = 4; o > 0; o >>= 1) { s1 += __shfl_down(s1, o); s2 += __shfl_down(s2, o); }
    if (cp == 0) {
      float mean = s1 * (1.f / 512.f);
      float var = s2 * (1.f / 512.f) - mean * mean;
      stM[r] = mean;
      stR[r] = rsqrtf(var + 1e-5f);
    }
    __syncthreads();
    float mean = stM[r], rs = stR[r];
#pragma unroll
    for (int i = 0; i < 16; ++i) {
      int c = cp * 64 + i * 4;
      int byte = (r * 1024 + c * 2) ^ ((r & 7) << 4);
      half4 hv = *(half4*)(bufA + byte);
      float4 g4 = *(const float4*)(g1 + c);
      float4 b4 = *(const float4*)(be1 + c);
      half4 ov = {(_Float16)(((float)hv[0] - mean) * rs * g4.x + b4.x),
                  (_Float16)(((float)hv[1] - mean) * rs * g4.y + b4.y),
                  (_Float16)(((float)hv[2] - mean) * rs * g4.z + b4.z),
                  (_Float16)(((float)hv[3] - mean) * rs * g4.w + b4.w)};
      *(half4*)(bufA + byte) = ov;
    }
  }
  __syncthreads();

  {  // fc1: bufA @ wf1 -> LN2 -> bufA (in-place)
    f32x4 acc[4][4];
    init_accn<4, 4>(bf1, 0, acc, tid);
    do_slice<4, 512, 0, 16, 512, 4>(wf1t, bufA, 0, acc, tid);
    epi_ln_store(acc, bufA, st1, st2, stM, stR, g2, be2, tid);
  }
  {  // fc2: bufA @ wf2 -> LN3 -> bufA (in-place)
    f32x4 acc[4][4];
    init_accn<4, 4>(bf2, 0, acc, tid);
    do_slice<4, 512, 0, 16, 512, 4>(wf2t, bufA, 0, acc, tid);
    epi_ln_store(acc, bufA, st1, st2, stM, stR, g3, be3, tid);
  }
  {  // fc3: bufA @ wf3 [64x512]@[512x16], 4-wave M-split, direct store
    const int w = tid >> 6, lane = tid & 63, ln15 = lane & 15, kg = lane >> 4;
    if (w < 4) {
      f32x4 acc3 = {0.f, 0.f, 0.f, 0.f};
#pragma unroll
      for (int c = 0; c < 16; ++c) {
        half8 b = *(const half8*)((const char*)wf3t + ln15 * 1024 + c * 64 + kg * 16);
        int row = w * 16 + ln15;
        half8 a = *(const half8*)(bufA + ((row * 1024 + c * 64 + kg * 16) ^ ((row & 7) << 4)));
        acc3 = __builtin_amdgcn_mfma_f32_16x16x32_f16(a, b, acc3, 0, 0, 0);
      }
#pragma unroll
      for (int j = 0; j < 4; ++j)
        x3[(size_t)(r0 + w * 16 + kg * 4 + j) * 16 + ln15] = acc3[j] + bf3[ln15];
    }
  }
}

// ---------------- triu mask + symmetrize ----------------
__global__ void k_sym(const float* __restrict__ x3, float* __restrict__ out) {
  int t = blockIdx.x * 256 + threadIdx.x;
  if (t >= SEGN * 4) return;
  int q = t & 3;
  int cell = t >> 2;
  int j = cell % Nn;
  int tmp = cell / Nn;
  int i = tmp % Nn;
  int b = tmp / Nn;
  float4 v = make_float4(0.f, 0.f, 0.f, 0.f);
  if (i <= j) v = *(const float4*)&x3[(size_t)cell * 16 + q * 4];
  if (j <= i) {
    int cell2 = (b * Nn + j) * Nn + i;
    float4 u = *(const float4*)&x3[(size_t)cell2 * 16 + q * 4];
    v.x += u.x; v.y += u.y; v.z += u.z; v.w += u.w;
  }
  *(float4*)&out[(size_t)t * 4] = v;
}

extern "C" void kernel_launch(void* const* d_in, const int* in_sizes, int n_in,
                              void* d_out, int out_size, void* d_ws, size_t ws_size,
                              hipStream_t stream) {
  const int*   rel_type  = (const int*)d_in[0];
  const float* rel_error = (const float*)d_in[1];
  const int*   edge_pos  = (const int*)d_in[2];
  const int*   dist      = (const int*)d_in[3];
  const int*   rel_row   = (const int*)d_in[4];
  const float* type_tab = (const float*)d_in[8];
  const float* pos_tab  = (const float*)d_in[9];
  const float* dist_tab = (const float*)d_in[10];
  const float* w1 = (const float*)d_in[11]; const float* b1 = (const float*)d_in[12];
  const float* w2 = (const float*)d_in[13]; const float* b2 = (const float*)d_in[14];
  const float* w3 = (const float*)d_in[15]; const float* b3 = (const float*)d_in[16];
  const float* g1 = (const float*)d_in[17]; const float* be1 = (const float*)d_in[18];
  const float* wf1 = (const float*)d_in[19]; const float* bf1 = (const float*)d_in[20];
  const float* g2 = (const float*)d_in[21]; const float* be2 = (const float*)d_in[22];
  const float* wf2 = (const float*)d_in[23]; const float* bf2 = (const float*)d_in[24];
  const float* g3 = (const float*)d_in[25]; const float* be3 = (const float*)d_in[26];
  const float* wf3 = (const float*)d_in[27]; const float* bf3 = (const float*)d_in[28];

  const int E = in_sizes[0];
  const size_t seg_bytes = (size_t)SEGN * 512 * 4;     // 209.7 MB
  const size_t x3_bytes  = (size_t)SEGN * 16 * 4;      // 6.55 MB
  const size_t wt_elems  = 32768 + 131072 + 262144 * 3 + 8192;
  if (ws_size < seg_bytes + x3_bytes + wt_elems * 2) return;

  unsigned*  seg = (unsigned*)d_ws;
  float*     x3  = (float*)((char*)d_ws + seg_bytes);
  _Float16*  w1t = (_Float16*)((char*)d_ws + seg_bytes + x3_bytes);
  _Float16*  w2t = w1t + 32768;
  _Float16*  w3t = w2t + 131072;
  _Float16*  wf1t = w3t + 262144;
  _Float16*  wf2t = wf1t + 262144;
  _Float16*  wf3t = wf2t + 262144;
  float*     out = (float*)d_out;

  k_prep<<<3744, 256, 0, stream>>>(w1, w2, w3, wf1, wf2, wf3,
                                   w1t, w2t, w3t, wf1t, wf2t, wf3t);
  k_init<<<2048, 256, 0, stream>>>((uint4*)seg, SEGN * 512 / 4);
  k_edge<<<(E + 31) / 32, 512, 0, stream>>>(rel_type, rel_error, edge_pos, rel_row,
                                            type_tab, pos_tab, w1t, b1, w2t, b2, w3t, b3,
                                            seg, E);
  k_fc<<<SEGN / 64, 512, 0, stream>>>(seg, dist, dist_tab,
                                      g1, be1, wf1t, bf1,
                                      g2, be2, wf2t, bf2,
                                      g3, be3, wf3t, bf3, x3);
  k_sym<<<(SEGN * 4 + 255) / 256, 256, 0, stream>>>(x3, out);
}

// Round 9
// 730.195 us; speedup vs baseline: 1.1081x; 1.1081x over previous
//
#include <hip/hip_runtime.h>

typedef __attribute__((ext_vector_type(8))) _Float16 half8;
typedef __attribute__((ext_vector_type(4))) _Float16 half4;
typedef __attribute__((ext_vector_type(4))) float f32x4;

constexpr int Bn = 4;
constexpr int Nn = 160;
constexpr int SEGN = Bn * Nn * Nn;        // 102400 segments
constexpr unsigned NEG_FLIP = 0x007FFFFFu; // flip(-inf)

__device__ __forceinline__ unsigned flipf(float f) {
  unsigned u = __float_as_uint(f);
  return (u & 0x80000000u) ? ~u : (u | 0x80000000u);
}
__device__ __forceinline__ float unflipf(unsigned s) {
  return __uint_as_float((s & 0x80000000u) ? (s ^ 0x80000000u) : ~s);
}

// ---------------- init segment buffer to flip(-inf) ----------------
__global__ void k_init(uint4* __restrict__ seg, int n4) {
  int i = blockIdx.x * blockDim.x + threadIdx.x;
  int stride = gridDim.x * blockDim.x;
  uint4 v = make_uint4(NEG_FLIP, NEG_FLIP, NEG_FLIP, NEG_FLIP);
  for (; i < n4; i += stride) seg[i] = v;
}

// ------- weight prepass: f32 [K][N] -> f16 chunk-blocked [k/32][N][32] -------
// (wf3: [512][16] -> [16][512] plain transpose)
__global__ void k_prep(const float* __restrict__ w1, const float* __restrict__ w2,
                       const float* __restrict__ w3, const float* __restrict__ wf1,
                       const float* __restrict__ wf2, const float* __restrict__ wf3,
                       _Float16* __restrict__ o1, _Float16* __restrict__ o2,
                       _Float16* __restrict__ o3, _Float16* __restrict__ of1,
                       _Float16* __restrict__ of2, _Float16* __restrict__ of3) {
  int t = blockIdx.x * 256 + threadIdx.x;
  const float* src; _Float16* dst; int N, local; bool is3 = false;
  if (t < 32768)       { src = w1;  dst = o1;  N = 256; local = t; }
  else if (t < 163840) { src = w2;  dst = o2;  N = 512; local = t - 32768; }
  else if (t < 425984) { src = w3;  dst = o3;  N = 512; local = t - 163840; }
  else if (t < 688128) { src = wf1; dst = of1; N = 512; local = t - 425984; }
  else if (t < 950272) { src = wf2; dst = of2; N = 512; local = t - 688128; }
  else if (t < 958464) { src = wf3; dst = of3; N = 16;  local = t - 950272; is3 = true; }
  else return;
  int k = local / N;
  int n = local - k * N;
  if (is3) dst[n * 512 + k] = (_Float16)src[local];
  else dst[(size_t)((k >> 5) * N + n) * 32 + (k & 31)] = (_Float16)src[local];
}

// ---------------- MFMA slice, B direct from global (L2-resident) ----------------
// A in LDS: f16 [M][K], rowB = 2K bytes, byte ^= ((row&7)<<4).
// W chunk-blocked global [c][NSTRIDE][32] f16.
template <int MT, int K, int C0, int CN, int NSTRIDE, int NT>
__device__ __forceinline__ void do_slice(const _Float16* __restrict__ wt,
                                         const char* a_base, int nbase,
                                         f32x4 (&acc)[MT][NT], int tid) {
  constexpr int rowB = K * 2;
  const int w = tid >> 6, lane = tid & 63, ln15 = lane & 15, kg = lane >> 4;
  const char* wb = (const char*)wt;
#pragma unroll
  for (int c = 0; c < CN; ++c) {
    half8 a[MT], b[NT];
#pragma unroll
    for (int nt = 0; nt < NT; ++nt) {
      int n = nbase + (w * NT + nt) * 16 + ln15;
      b[nt] = *(const half8*)(wb + (size_t)(C0 + c) * (NSTRIDE * 64) + n * 64 + kg * 16);
    }
#pragma unroll
    for (int mt = 0; mt < MT; ++mt) {
      int row = mt * 16 + ln15;
      int byte = (row * rowB + c * 64 + kg * 16) ^ ((row & 7) << 4);
      a[mt] = *(const half8*)(a_base + byte);
    }
#pragma unroll
    for (int mt = 0; mt < MT; ++mt)
#pragma unroll
      for (int nt = 0; nt < NT; ++nt)
        acc[mt][nt] = __builtin_amdgcn_mfma_f32_16x16x32_f16(a[mt], b[nt], acc[mt][nt], 0, 0, 0);
  }
}

template <int MT, int NT>
__device__ __forceinline__ void init_accn(const float* __restrict__ bias, int nbase,
                                          f32x4 (&acc)[MT][NT], int tid) {
  const int w = tid >> 6, ln15 = tid & 15;
#pragma unroll
  for (int nt = 0; nt < NT; ++nt) {
    float bv = bias[nbase + (w * NT + nt) * 16 + ln15];
    f32x4 s = {bv, bv, bv, bv};
#pragma unroll
    for (int mt = 0; mt < MT; ++mt) acc[mt][nt] = s;
  }
}

// C layout: col = lane&15, row = (lane>>4)*4 + j  [m89 verified]
template <int MT, int NT, bool RELU>
__device__ __forceinline__ void store_hn(char* h, int rowB, int nbase,
                                         const f32x4 (&acc)[MT][NT], int tid) {
  const int w = tid >> 6, lane = tid & 63, ln15 = lane & 15, kg = lane >> 4;
#pragma unroll
  for (int mt = 0; mt < MT; ++mt)
#pragma unroll
    for (int nt = 0; nt < NT; ++nt)
#pragma unroll
      for (int j = 0; j < 4; ++j) {
        int row = mt * 16 + kg * 4 + j;
        int n = nbase + (w * NT + nt) * 16 + ln15;
        float v = acc[mt][nt][j];
        if (RELU) v = fmaxf(v, 0.f);
        *(_Float16*)(h + ((row * rowB + n * 2) ^ ((row & 7) << 4))) = (_Float16)v;
      }
}

// ---------------- fused edge MLP (MFMA) + scatter-max ----------------
// M=64 edges/block, 1024 threads (16 waves). LDS 96.5KB -> 1 block/CU but
// 4 waves/SIMD (vs 2 at 512t): doubles latency-hiding contexts; per-wave
// acc halves (NT 4->2) so VGPR ~80-100 fits the 128 cap (16 waves x 128 = pool).
__global__ __launch_bounds__(1024, 1) void k_edge(
    const int* __restrict__ rel_type, const float* __restrict__ rel_error,
    const int* __restrict__ edge_pos, const int* __restrict__ rel_row,
    const float* __restrict__ type_tab, const float* __restrict__ pos_tab,
    const _Float16* __restrict__ w1t, const float* __restrict__ b1,
    const _Float16* __restrict__ w2t, const float* __restrict__ b2,
    const _Float16* __restrict__ w3t, const float* __restrict__ b3,
    unsigned* __restrict__ seg, int E) {
  __shared__ __align__(16) char smem[98304];
  __shared__ int rr[64];
  char* h1 = smem;            // [64][256] f16, rowB 512
  char* h2 = smem + 32768;    // [64][512] f16, rowB 1024
  char* e  = smem + 32768;    // [64][128] f16, rowB 256 (dead before h2 written)

  const int tid = threadIdx.x;
  const int e0 = blockIdx.x * 64;

  // ---- build e tile: 64 rows x 16 half8-cols = 1024 threads exactly ----
  {
    int r = tid >> 4, c8 = tid & 15;
    int re = min(e0 + r, E - 1);
    int rt = rel_type[re];
    int ep = edge_pos[re];
    half8 hv;
#pragma unroll
    for (int q = 0; q < 8; ++q) {
      int cc = c8 * 8 + q;
      float v = (cc < 120) ? (rt ? type_tab[rt * 120 + cc] : 0.f)
                           : rel_error[(size_t)re * 8 + (cc - 120)];
      v += pos_tab[ep * 128 + cc];
      hv[q] = (_Float16)v;
    }
    int byte = (r * 256 + c8 * 16) ^ ((r & 7) << 4);
    *(half8*)(e + byte) = hv;
    if (tid < 64) rr[tid] = rel_row[min(e0 + tid, E - 1)];
  }
  __syncthreads();

  {  // layer 1: [64x128]@[128x256] + relu -> h1 (wave owns 64x16, NT=1)
    f32x4 acc[4][1];
    init_accn<4, 1>(b1, 0, acc, tid);
    do_slice<4, 128, 0, 4, 256, 1>(w1t, e, 0, acc, tid);
    store_hn<4, 1, true>(h1, 512, 0, acc, tid);
  }
  __syncthreads();
  {  // layer 2: [64x256]@[256x512] + relu -> h2 (wave owns 64x32, NT=2)
    f32x4 acc[4][2];
    init_accn<4, 2>(b2, 0, acc, tid);
    do_slice<4, 256, 0, 8, 512, 2>(w2t, h1, 0, acc, tid);
    store_hn<4, 2, true>(h2, 1024, 0, acc, tid);
  }
  __syncthreads();
  {  // layer 3: [64x512]@[512x512] -> scatter-max
    f32x4 acc[4][2];
    init_accn<4, 2>(b3, 0, acc, tid);
    do_slice<4, 512, 0, 16, 512, 2>(w3t, h2, 0, acc, tid);

    const int w = tid >> 6, lane = tid & 63, ln15 = lane & 15, kg = lane >> 4;
#pragma unroll
    for (int mt = 0; mt < 4; ++mt) {
      int rbase = mt * 16 + kg * 4;
      float m[2];
      int cur = rr[rbase];
#pragma unroll
      for (int nt = 0; nt < 2; ++nt) m[nt] = acc[mt][nt][0];
#pragma unroll
      for (int j = 1; j < 4; ++j) {
        int rj = rr[rbase + j];
        if (rj == cur) {
#pragma unroll
          for (int nt = 0; nt < 2; ++nt) m[nt] = fmaxf(m[nt], acc[mt][nt][j]);
        } else {
          unsigned* dst = seg + (size_t)cur * 512;
#pragma unroll
          for (int nt = 0; nt < 2; ++nt)
            atomicMax(dst + (w * 2 + nt) * 16 + ln15, flipf(m[nt]));
          cur = rj;
#pragma unroll
          for (int nt = 0; nt < 2; ++nt) m[nt] = acc[mt][nt][j];
        }
      }
      unsigned* dst = seg + (size_t)cur * 512;
#pragma unroll
      for (int nt = 0; nt < 2; ++nt)
        atomicMax(dst + (w * 2 + nt) * 16 + ln15, flipf(m[nt]));
    }
  }
}

// ---- in-register epilogue: relu -> LN (shfl + 2-stage LDS) -> store f16 ----
__device__ __forceinline__ void epi_ln_store(f32x4 (&acc)[4][4], char* dst,
                                             float* st1, float* st2,
                                             float* stM, float* stR,
                                             const float* __restrict__ g,
                                             const float* __restrict__ be, int tid) {
  const int w = tid >> 6, lane = tid & 63, ln15 = lane & 15, kg = lane >> 4;
#pragma unroll
  for (int mt = 0; mt < 4; ++mt)
#pragma unroll
    for (int nt = 0; nt < 4; ++nt)
#pragma unroll
      for (int j = 0; j < 4; ++j) acc[mt][nt][j] = fmaxf(acc[mt][nt][j], 0.f);
#pragma unroll
  for (int mt = 0; mt < 4; ++mt)
#pragma unroll
    for (int j = 0; j < 4; ++j) {
      float a = 0.f, b = 0.f;
#pragma unroll
      for (int nt = 0; nt < 4; ++nt) { float v = acc[mt][nt][j]; a += v; b += v * v; }
#pragma unroll
      for (int m = 1; m < 16; m <<= 1) { a += __shfl_xor(a, m); b += __shfl_xor(b, m); }
      if (ln15 == 0) {
        int r = mt * 16 + kg * 4 + j;
        st1[w * 64 + r] = a;
        st2[w * 64 + r] = b;
      }
    }
  __syncthreads();
  if (tid < 64) {
    float a = 0.f, b = 0.f;
#pragma unroll
    for (int ww = 0; ww < 8; ++ww) { a += st1[ww * 64 + tid]; b += st2[ww * 64 + tid]; }
    float mean = a * (1.f / 512.f);
    float var = b * (1.f / 512.f) - mean * mean;
    stM[tid] = mean;
    stR[tid] = rsqrtf(var + 1e-5f);
  }
  __syncthreads();
  float gv[4], bv[4];
#pragma unroll
  for (int nt = 0; nt < 4; ++nt) {
    int n = (w * 4 + nt) * 16 + ln15;
    gv[nt] = g[n]; bv[nt] = be[n];
  }
#pragma unroll
  for (int mt = 0; mt < 4; ++mt)
#pragma unroll
    for (int j = 0; j < 4; ++j) {
      int r = mt * 16 + kg * 4 + j;
      float mean = stM[r], rs = stR[r];
#pragma unroll
      for (int nt = 0; nt < 4; ++nt) {
        int n = (w * 4 + nt) * 16 + ln15;
        float v = (acc[mt][nt][j] - mean) * rs * gv[nt] + bv[nt];
        *(_Float16*)(dst + ((r * 1024 + n * 2) ^ ((r & 7) << 4))) = (_Float16)v;
      }
    }
  __syncthreads();
}

// ---------------- fused FC: seg+dist -> LN -> fc1 -> LN -> fc2 -> LN -> fc3 ----------------
// launch_bounds(512, 2): 2 blocks/CU -> 128-VGPR budget (r4: (512,4) => 64 VGPR, spilled).
__global__ __launch_bounds__(512, 2) void k_fc(
    const unsigned* __restrict__ segin, const int* __restrict__ dist,
    const float* __restrict__ dist_tab,
    const float* __restrict__ g1, const float* __restrict__ be1,
    const _Float16* __restrict__ wf1t, const float* __restrict__ bf1,
    const float* __restrict__ g2, const float* __restrict__ be2,
    const _Float16* __restrict__ wf2t, const float* __restrict__ bf2,
    const float* __restrict__ g3, const float* __restrict__ be3,
    const _Float16* __restrict__ wf3t, const float* __restrict__ bf3,
    float* __restrict__ x3) {
  __shared__ __align__(16) char bufA[65536];  // [64][512] f16, rowB 1024
  __shared__ float st1[512], st2[512];
  __shared__ float stM[64], stR[64];

  const int tid = threadIdx.x;
  const int r0 = blockIdx.x * 64;

  // ---- prologue: seg + dist emb -> relu -> LN1 -> bufA (f16, swizzled) ----
  {
    const int r = tid >> 3, cp = tid & 7;
    const int gr = r0 + r;
    int di = dist[gr];
    const float* dt = dist_tab + (size_t)di * 512;
    float s1 = 0.f, s2 = 0.f;
#pragma unroll
    for (int i = 0; i < 16; ++i) {
      int c = cp * 64 + i * 4;
      uint4 sv = *(const uint4*)(segin + (size_t)gr * 512 + c);
      float v0 = (sv.x == NEG_FLIP) ? 0.f : unflipf(sv.x);
      float v1 = (sv.y == NEG_FLIP) ? 0.f : unflipf(sv.y);
      float v2 = (sv.z == NEG_FLIP) ? 0.f : unflipf(sv.z);
      float v3 = (sv.w == NEG_FLIP) ? 0.f : unflipf(sv.w);
      if (di) { v0 += dt[c]; v1 += dt[c + 1]; v2 += dt[c + 2]; v3 += dt[c + 3]; }
      v0 = fmaxf(v0, 0.f); v1 = fmaxf(v1, 0.f); v2 = fmaxf(v2, 0.f); v3 = fmaxf(v3, 0.f);
      s1 += v0 + v1 + v2 + v3;
      s2 += v0 * v0 + v1 * v1 + v2 * v2 + v3 * v3;
      half4 hv = {(_Float16)v0, (_Float16)v1, (_Float16)v2, (_Float16)v3};
      *(half4*)(bufA + ((r * 1024 + c * 2) ^ ((r & 7) << 4))) = hv;
    }
#pragma unroll
    for (int o = 4; o > 0; o >>= 1) { s1 += __shfl_down(s1, o); s2 += __shfl_down(s2, o); }
    if (cp == 0) {
      float mean = s1 * (1.f / 512.f);
      float var = s2 * (1.f / 512.f) - mean * mean;
      stM[r] = mean;
      stR[r] = rsqrtf(var + 1e-5f);
    }
    __syncthreads();
    float mean = stM[r], rs = stR[r];
#pragma unroll
    for (int i = 0; i < 16; ++i) {
      int c = cp * 64 + i * 4;
      int byte = (r * 1024 + c * 2) ^ ((r & 7) << 4);
      half4 hv = *(half4*)(bufA + byte);
      float4 g4 = *(const float4*)(g1 + c);
      float4 b4 = *(const float4*)(be1 + c);
      half4 ov = {(_Float16)(((float)hv[0] - mean) * rs * g4.x + b4.x),
                  (_Float16)(((float)hv[1] - mean) * rs * g4.y + b4.y),
                  (_Float16)(((float)hv[2] - mean) * rs * g4.z + b4.z),
                  (_Float16)(((float)hv[3] - mean) * rs * g4.w + b4.w)};
      *(half4*)(bufA + byte) = ov;
    }
  }
  __syncthreads();

  {  // fc1: bufA @ wf1 -> LN2 -> bufA (in-place)
    f32x4 acc[4][4];
    init_accn<4, 4>(bf1, 0, acc, tid);
    do_slice<4, 512, 0, 16, 512, 4>(wf1t, bufA, 0, acc, tid);
    epi_ln_store(acc, bufA, st1, st2, stM, stR, g2, be2, tid);
  }
  {  // fc2: bufA @ wf2 -> LN3 -> bufA (in-place)
    f32x4 acc[4][4];
    init_accn<4, 4>(bf2, 0, acc, tid);
    do_slice<4, 512, 0, 16, 512, 4>(wf2t, bufA, 0, acc, tid);
    epi_ln_store(acc, bufA, st1, st2, stM, stR, g3, be3, tid);
  }
  {  // fc3: bufA @ wf3 [64x512]@[512x16], 4-wave M-split, direct store
    const int w = tid >> 6, lane = tid & 63, ln15 = lane & 15, kg = lane >> 4;
    if (w < 4) {
      f32x4 acc3 = {0.f, 0.f, 0.f, 0.f};
#pragma unroll
      for (int c = 0; c < 16; ++c) {
        half8 b = *(const half8*)((const char*)wf3t + ln15 * 1024 + c * 64 + kg * 16);
        int row = w * 16 + ln15;
        half8 a = *(const half8*)(bufA + ((row * 1024 + c * 64 + kg * 16) ^ ((row & 7) << 4)));
        acc3 = __builtin_amdgcn_mfma_f32_16x16x32_f16(a, b, acc3, 0, 0, 0);
      }
#pragma unroll
      for (int j = 0; j < 4; ++j)
        x3[(size_t)(r0 + w * 16 + kg * 4 + j) * 16 + ln15] = acc3[j] + bf3[ln15];
    }
  }
}

// ---------------- triu mask + symmetrize ----------------
__global__ void k_sym(const float* __restrict__ x3, float* __restrict__ out) {
  int t = blockIdx.x * 256 + threadIdx.x;
  if (t >= SEGN * 4) return;
  int q = t & 3;
  int cell = t >> 2;
  int j = cell % Nn;
  int tmp = cell / Nn;
  int i = tmp % Nn;
  int b = tmp / Nn;
  float4 v = make_float4(0.f, 0.f, 0.f, 0.f);
  if (i <= j) v = *(const float4*)&x3[(size_t)cell * 16 + q * 4];
  if (j <= i) {
    int cell2 = (b * Nn + j) * Nn + i;
    float4 u = *(const float4*)&x3[(size_t)cell2 * 16 + q * 4];
    v.x += u.x; v.y += u.y; v.z += u.z; v.w += u.w;
  }
  *(float4*)&out[(size_t)t * 4] = v;
}

extern "C" void kernel_launch(void* const* d_in, const int* in_sizes, int n_in,
                              void* d_out, int out_size, void* d_ws, size_t ws_size,
                              hipStream_t stream) {
  const int*   rel_type  = (const int*)d_in[0];
  const float* rel_error = (const float*)d_in[1];
  const int*   edge_pos  = (const int*)d_in[2];
  const int*   dist      = (const int*)d_in[3];
  const int*   rel_row   = (const int*)d_in[4];
  const float* type_tab = (const float*)d_in[8];
  const float* pos_tab  = (const float*)d_in[9];
  const float* dist_tab = (const float*)d_in[10];
  const float* w1 = (const float*)d_in[11]; const float* b1 = (const float*)d_in[12];
  const float* w2 = (const float*)d_in[13]; const float* b2 = (const float*)d_in[14];
  const float* w3 = (const float*)d_in[15]; const float* b3 = (const float*)d_in[16];
  const float* g1 = (const float*)d_in[17]; const float* be1 = (const float*)d_in[18];
  const float* wf1 = (const float*)d_in[19]; const float* bf1 = (const float*)d_in[20];
  const float* g2 = (const float*)d_in[21]; const float* be2 = (const float*)d_in[22];
  const float* wf2 = (const float*)d_in[23]; const float* bf2 = (const float*)d_in[24];
  const float* g3 = (const float*)d_in[25]; const float* be3 = (const float*)d_in[26];
  const float* wf3 = (const float*)d_in[27]; const float* bf3 = (const float*)d_in[28];

  const int E = in_sizes[0];
  const size_t seg_bytes = (size_t)SEGN * 512 * 4;     // 209.7 MB
  const size_t x3_bytes  = (size_t)SEGN * 16 * 4;      // 6.55 MB
  const size_t wt_elems  = 32768 + 131072 + 262144 * 3 + 8192;
  if (ws_size < seg_bytes + x3_bytes + wt_elems * 2) return;

  unsigned*  seg = (unsigned*)d_ws;
  float*     x3  = (float*)((char*)d_ws + seg_bytes);
  _Float16*  w1t = (_Float16*)((char*)d_ws + seg_bytes + x3_bytes);
  _Float16*  w2t = w1t + 32768;
  _Float16*  w3t = w2t + 131072;
  _Float16*  wf1t = w3t + 262144;
  _Float16*  wf2t = wf1t + 262144;
  _Float16*  wf3t = wf2t + 262144;
  float*     out = (float*)d_out;

  k_prep<<<3744, 256, 0, stream>>>(w1, w2, w3, wf1, wf2, wf3,
                                   w1t, w2t, w3t, wf1t, wf2t, wf3t);
  k_init<<<2048, 256, 0, stream>>>((uint4*)seg, SEGN * 512 / 4);
  k_edge<<<(E + 63) / 64, 1024, 0, stream>>>(rel_type, rel_error, edge_pos, rel_row,
                                             type_tab, pos_tab, w1t, b1, w2t, b2, w3t, b3,
                                             seg, E);
  k_fc<<<SEGN / 64, 512, 0, stream>>>(seg, dist, dist_tab,
                                      g1, be1, wf1t, bf1,
                                      g2, be2, wf2t, bf2,
                                      g3, be3, wf3t, bf3, x3);
  k_sym<<<(SEGN * 4 + 255) / 256, 256, 0, stream>>>(x3, out);
}

// Round 10
// 715.698 us; speedup vs baseline: 1.1305x; 1.0203x over previous
//
#include <hip/hip_runtime.h>

typedef __attribute__((ext_vector_type(8))) _Float16 half8;
typedef __attribute__((ext_vector_type(4))) _Float16 half4;
typedef __attribute__((ext_vector_type(4))) float f32x4;

constexpr int Bn = 4;
constexpr int Nn = 160;
constexpr int SEGN = Bn * Nn * Nn;        // 102400 segments

// ------- weight prepass: f32 [K][N] -> f16 chunk-blocked [k/32][N][32] -------
// (wf3: [512][16] -> [16][512] plain transpose)
__global__ void k_prep(const float* __restrict__ w1, const float* __restrict__ w2,
                       const float* __restrict__ w3, const float* __restrict__ wf1,
                       const float* __restrict__ wf2, const float* __restrict__ wf3,
                       _Float16* __restrict__ o1, _Float16* __restrict__ o2,
                       _Float16* __restrict__ o3, _Float16* __restrict__ of1,
                       _Float16* __restrict__ of2, _Float16* __restrict__ of3) {
  int t = blockIdx.x * 256 + threadIdx.x;
  const float* src; _Float16* dst; int N, local; bool is3 = false;
  if (t < 32768)       { src = w1;  dst = o1;  N = 256; local = t; }
  else if (t < 163840) { src = w2;  dst = o2;  N = 512; local = t - 32768; }
  else if (t < 425984) { src = w3;  dst = o3;  N = 512; local = t - 163840; }
  else if (t < 688128) { src = wf1; dst = of1; N = 512; local = t - 425984; }
  else if (t < 950272) { src = wf2; dst = of2; N = 512; local = t - 688128; }
  else if (t < 958464) { src = wf3; dst = of3; N = 16;  local = t - 950272; is3 = true; }
  else return;
  int k = local / N;
  int n = local - k * N;
  if (is3) dst[n * 512 + k] = (_Float16)src[local];
  else dst[(size_t)((k >> 5) * N + n) * 32 + (k & 31)] = (_Float16)src[local];
}

// ------- CSR row pointers from sorted rel_row: row_ptr[r] = lower_bound(r) -------
__global__ void k_ptr(const int* __restrict__ rel_row, int* __restrict__ row_ptr, int E) {
  int r = blockIdx.x * 256 + threadIdx.x;
  if (r > SEGN) return;
  if (r == SEGN) { row_ptr[r] = E; return; }
  int lo = 0, hi = E;
  while (lo < hi) { int mid = (lo + hi) >> 1; if (rel_row[mid] < r) lo = mid + 1; else hi = mid; }
  row_ptr[r] = lo;
}

// ---------------- MFMA slice, B direct from global (L2-resident) ----------------
// A in LDS: f16 [M][K], rowB = 2K bytes, byte ^= ((row&7)<<4).
// W chunk-blocked global [c][NSTRIDE][32] f16.
template <int MT, int K, int C0, int CN, int NSTRIDE, int NT>
__device__ __forceinline__ void do_slice(const _Float16* __restrict__ wt,
                                         const char* a_base, int nbase,
                                         f32x4 (&acc)[MT][NT], int tid) {
  constexpr int rowB = K * 2;
  const int w = tid >> 6, lane = tid & 63, ln15 = lane & 15, kg = lane >> 4;
  const char* wb = (const char*)wt;
#pragma unroll
  for (int c = 0; c < CN; ++c) {
    half8 a[MT], b[NT];
#pragma unroll
    for (int nt = 0; nt < NT; ++nt) {
      int n = nbase + (w * NT + nt) * 16 + ln15;
      b[nt] = *(const half8*)(wb + (size_t)(C0 + c) * (NSTRIDE * 64) + n * 64 + kg * 16);
    }
#pragma unroll
    for (int mt = 0; mt < MT; ++mt) {
      int row = mt * 16 + ln15;
      int byte = (row * rowB + c * 64 + kg * 16) ^ ((row & 7) << 4);
      a[mt] = *(const half8*)(a_base + byte);
    }
#pragma unroll
    for (int mt = 0; mt < MT; ++mt)
#pragma unroll
      for (int nt = 0; nt < NT; ++nt)
        acc[mt][nt] = __builtin_amdgcn_mfma_f32_16x16x32_f16(a[mt], b[nt], acc[mt][nt], 0, 0, 0);
  }
}

template <int MT, int NT>
__device__ __forceinline__ void init_accn(const float* __restrict__ bias, int nbase,
                                          f32x4 (&acc)[MT][NT], int tid) {
  const int w = tid >> 6, ln15 = tid & 15;
#pragma unroll
  for (int nt = 0; nt < NT; ++nt) {
    float bv = bias[nbase + (w * NT + nt) * 16 + ln15];
    f32x4 s = {bv, bv, bv, bv};
#pragma unroll
    for (int mt = 0; mt < MT; ++mt) acc[mt][nt] = s;
  }
}

// C layout: col = lane&15, row = (lane>>4)*4 + j  [m89 verified]
template <int MT, int NT, bool RELU>
__device__ __forceinline__ void store_hn(char* h, int rowB, int nbase,
                                         const f32x4 (&acc)[MT][NT], int tid) {
  const int w = tid >> 6, lane = tid & 63, ln15 = lane & 15, kg = lane >> 4;
#pragma unroll
  for (int mt = 0; mt < MT; ++mt)
#pragma unroll
    for (int nt = 0; nt < NT; ++nt)
#pragma unroll
      for (int j = 0; j < 4; ++j) {
        int row = mt * 16 + kg * 4 + j;
        int n = nbase + (w * NT + nt) * 16 + ln15;
        float v = acc[mt][nt][j];
        if (RELU) v = fmaxf(v, 0.f);
        *(_Float16*)(h + ((row * rowB + n * 2) ^ ((row & 7) << 4))) = (_Float16)v;
      }
}

// ---------------- fused edge MLP (MFMA) -> plain f16 stores (no atomics) ----------------
__global__ __launch_bounds__(512) void k_edge(
    const int* __restrict__ rel_type, const float* __restrict__ rel_error,
    const int* __restrict__ edge_pos,
    const float* __restrict__ type_tab, const float* __restrict__ pos_tab,
    const _Float16* __restrict__ w1t, const float* __restrict__ b1,
    const _Float16* __restrict__ w2t, const float* __restrict__ b2,
    const _Float16* __restrict__ w3t, const float* __restrict__ b3,
    _Float16* __restrict__ h3, int E) {
  __shared__ __align__(16) char smem[98304];
  char* h1 = smem;            // [64][256] f16, rowB 512
  char* h2 = smem + 32768;    // [64][512] f16, rowB 1024
  char* e  = smem + 32768;    // [64][128] f16, rowB 256 (dead before h2 written)

  const int tid = threadIdx.x;
  const int e0 = blockIdx.x * 64;

  // ---- build e tile ----
  {
    int r = tid >> 3, c0 = (tid & 7) * 16;
    int re = min(e0 + r, E - 1);
    int rt = rel_type[re];
    int ep = edge_pos[re];
#pragma unroll
    for (int s = 0; s < 2; ++s) {
      half8 hv;
#pragma unroll
      for (int q = 0; q < 8; ++q) {
        int cc = c0 + s * 8 + q;
        float v = (cc < 120) ? (rt ? type_tab[rt * 120 + cc] : 0.f)
                             : rel_error[(size_t)re * 8 + (cc - 120)];
        v += pos_tab[ep * 128 + cc];
        hv[q] = (_Float16)v;
      }
      int byte = (r * 256 + (c0 + s * 8) * 2) ^ ((r & 7) << 4);
      *(half8*)(e + byte) = hv;
    }
  }
  __syncthreads();

  {  // layer 1: [64x128]@[128x256] + relu -> h1
    f32x4 acc[4][2];
    init_accn<4, 2>(b1, 0, acc, tid);
    do_slice<4, 128, 0, 4, 256, 2>(w1t, e, 0, acc, tid);
    store_hn<4, 2, true>(h1, 512, 0, acc, tid);
  }
  __syncthreads();
  {  // layer 2: [64x256]@[256x512] + relu -> h2 (overwrites e region, reads drained)
    f32x4 acc[4][4];
    init_accn<4, 4>(b2, 0, acc, tid);
    do_slice<4, 256, 0, 8, 512, 4>(w2t, h1, 0, acc, tid);
    store_hn<4, 4, true>(h2, 1024, 0, acc, tid);
  }
  __syncthreads();
  {  // layer 3: [64x512]@[512x512] -> h2 (LDS) -> coalesced global f16 stream
    f32x4 acc[4][4];
    init_accn<4, 4>(b3, 0, acc, tid);
    do_slice<4, 512, 0, 16, 512, 4>(w3t, h2, 0, acc, tid);
    __syncthreads();                       // all h2 reads complete
    store_hn<4, 4, false>(h2, 1024, 0, acc, tid);
    __syncthreads();
    uint4* dst = (uint4*)(h3 + (size_t)e0 * 512);
#pragma unroll
    for (int i = 0; i < 8; ++i) {
      int cidx = tid + i * 512;            // 16B chunk index, 4096 total
      int byteoff = cidx * 16;
      int row = byteoff >> 10;
      uint4 v = *(const uint4*)(h2 + (byteoff ^ ((row & 7) << 4)));
      if (e0 + row < E) dst[cidx] = v;
    }
  }
}

// ---- in-register epilogue: relu -> LN (shfl + 2-stage LDS) -> store f16 ----
__device__ __forceinline__ void epi_ln_store(f32x4 (&acc)[4][4], char* dst,
                                             float* st1, float* st2,
                                             float* stM, float* stR,
                                             const float* __restrict__ g,
                                             const float* __restrict__ be, int tid) {
  const int w = tid >> 6, lane = tid & 63, ln15 = lane & 15, kg = lane >> 4;
#pragma unroll
  for (int mt = 0; mt < 4; ++mt)
#pragma unroll
    for (int nt = 0; nt < 4; ++nt)
#pragma unroll
      for (int j = 0; j < 4; ++j) acc[mt][nt][j] = fmaxf(acc[mt][nt][j], 0.f);
#pragma unroll
  for (int mt = 0; mt < 4; ++mt)
#pragma unroll
    for (int j = 0; j < 4; ++j) {
      float a = 0.f, b = 0.f;
#pragma unroll
      for (int nt = 0; nt < 4; ++nt) { float v = acc[mt][nt][j]; a += v; b += v * v; }
#pragma unroll
      for (int m = 1; m < 16; m <<= 1) { a += __shfl_xor(a, m); b += __shfl_xor(b, m); }
      if (ln15 == 0) {
        int r = mt * 16 + kg * 4 + j;
        st1[w * 64 + r] = a;
        st2[w * 64 + r] = b;
      }
    }
  __syncthreads();
  if (tid < 64) {
    float a = 0.f, b = 0.f;
#pragma unroll
    for (int ww = 0; ww < 8; ++ww) { a += st1[ww * 64 + tid]; b += st2[ww * 64 + tid]; }
    float mean = a * (1.f / 512.f);
    float var = b * (1.f / 512.f) - mean * mean;
    stM[tid] = mean;
    stR[tid] = rsqrtf(var + 1e-5f);
  }
  __syncthreads();
  float gv[4], bv[4];
#pragma unroll
  for (int nt = 0; nt < 4; ++nt) {
    int n = (w * 4 + nt) * 16 + ln15;
    gv[nt] = g[n]; bv[nt] = be[n];
  }
#pragma unroll
  for (int mt = 0; mt < 4; ++mt)
#pragma unroll
    for (int j = 0; j < 4; ++j) {
      int r = mt * 16 + kg * 4 + j;
      float mean = stM[r], rs = stR[r];
#pragma unroll
      for (int nt = 0; nt < 4; ++nt) {
        int n = (w * 4 + nt) * 16 + ln15;
        float v = (acc[mt][nt][j] - mean) * rs * gv[nt] + bv[nt];
        *(_Float16*)(dst + ((r * 1024 + n * 2) ^ ((r & 7) << 4))) = (_Float16)v;
      }
    }
  __syncthreads();
}

// -------- fused FC: gather-max(h3 CSR) + dist -> LN -> fc1 -> LN -> fc2 -> LN -> fc3 --------
__global__ __launch_bounds__(512, 2) void k_fc(
    const _Float16* __restrict__ h3, const int* __restrict__ row_ptr,
    const int* __restrict__ dist, const float* __restrict__ dist_tab,
    const float* __restrict__ g1, const float* __restrict__ be1,
    const _Float16* __restrict__ wf1t, const float* __restrict__ bf1,
    const float* __restrict__ g2, const float* __restrict__ be2,
    const _Float16* __restrict__ wf2t, const float* __restrict__ bf2,
    const float* __restrict__ g3, const float* __restrict__ be3,
    const _Float16* __restrict__ wf3t, const float* __restrict__ bf3,
    float* __restrict__ x3) {
  __shared__ __align__(16) char bufA[65536];  // [64][512] f16, rowB 1024
  __shared__ float st1[512], st2[512];
  __shared__ float stM[64], stR[64];

  const int tid = threadIdx.x;
  const int r0 = blockIdx.x * 64;

  // ---- prologue: segment-max gather + dist emb -> relu -> LN1 -> bufA ----
  {
    const int r = tid >> 3, cp = tid & 7;
    const int gr = r0 + r;
    const int s = row_ptr[gr], en = row_ptr[gr + 1];
    const int di = dist[gr];
    const float* dt = dist_tab + (size_t)di * 512;

    half8 mx[8];
    const _Float16 NEGH = (_Float16)(-65504.f);
#pragma unroll
    for (int i = 0; i < 8; ++i)
#pragma unroll
      for (int q = 0; q < 8; ++q) mx[i][q] = NEGH;
    for (int idx = s; idx < en; ++idx) {
      const half8* src = (const half8*)(h3 + (size_t)idx * 512 + cp * 64);
#pragma unroll
      for (int i = 0; i < 8; ++i) {
        half8 b = src[i];
#pragma unroll
        for (int q = 0; q < 8; ++q) if (b[q] > mx[i][q]) mx[i][q] = b[q];
      }
    }
    const bool empty = (s == en);
    float s1 = 0.f, s2 = 0.f;
#pragma unroll
    for (int i = 0; i < 8; ++i) {
      int c0 = cp * 64 + i * 8;
      half8 hv;
#pragma unroll
      for (int q = 0; q < 8; ++q) {
        float v = empty ? 0.f : (float)mx[i][q];
        if (di) v += dt[c0 + q];
        v = fmaxf(v, 0.f);
        s1 += v; s2 += v * v;
        hv[q] = (_Float16)v;
      }
      *(half8*)(bufA + ((r * 1024 + c0 * 2) ^ ((r & 7) << 4))) = hv;
    }
#pragma unroll
    for (int o = 4; o > 0; o >>= 1) { s1 += __shfl_down(s1, o); s2 += __shfl_down(s2, o); }
    if (cp == 0) {
      float mean = s1 * (1.f / 512.f);
      float var = s2 * (1.f / 512.f) - mean * mean;
      stM[r] = mean;
      stR[r] = rsqrtf(var + 1e-5f);
    }
    __syncthreads();
    float mean = stM[r], rs = stR[r];
#pragma unroll
    for (int i = 0; i < 16; ++i) {
      int c = cp * 64 + i * 4;
      int byte = (r * 1024 + c * 2) ^ ((r & 7) << 4);
      half4 hv = *(half4*)(bufA + byte);
      float4 g4 = *(const float4*)(g1 + c);
      float4 b4 = *(const float4*)(be1 + c);
      half4 ov = {(_Float16)(((float)hv[0] - mean) * rs * g4.x + b4.x),
                  (_Float16)(((float)hv[1] - mean) * rs * g4.y + b4.y),
                  (_Float16)(((float)hv[2] - mean) * rs * g4.z + b4.z),
                  (_Float16)(((float)hv[3] - mean) * rs * g4.w + b4.w)};
      *(half4*)(bufA + byte) = ov;
    }
  }
  __syncthreads();

  {  // fc1: bufA @ wf1 -> LN2 -> bufA (in-place)
    f32x4 acc[4][4];
    init_accn<4, 4>(bf1, 0, acc, tid);
    do_slice<4, 512, 0, 16, 512, 4>(wf1t, bufA, 0, acc, tid);
    epi_ln_store(acc, bufA, st1, st2, stM, stR, g2, be2, tid);
  }
  {  // fc2: bufA @ wf2 -> LN3 -> bufA (in-place)
    f32x4 acc[4][4];
    init_accn<4, 4>(bf2, 0, acc, tid);
    do_slice<4, 512, 0, 16, 512, 4>(wf2t, bufA, 0, acc, tid);
    epi_ln_store(acc, bufA, st1, st2, stM, stR, g3, be3, tid);
  }
  {  // fc3: bufA @ wf3 [64x512]@[512x16], 4-wave M-split, direct store
    const int w = tid >> 6, lane = tid & 63, ln15 = lane & 15, kg = lane >> 4;
    if (w < 4) {
      f32x4 acc3 = {0.f, 0.f, 0.f, 0.f};
#pragma unroll
      for (int c = 0; c < 16; ++c) {
        half8 b = *(const half8*)((const char*)wf3t + ln15 * 1024 + c * 64 + kg * 16);
        int row = w * 16 + ln15;
        half8 a = *(const half8*)(bufA + ((row * 1024 + c * 64 + kg * 16) ^ ((row & 7) << 4)));
        acc3 = __builtin_amdgcn_mfma_f32_16x16x32_f16(a, b, acc3, 0, 0, 0);
      }
#pragma unroll
      for (int j = 0; j < 4; ++j)
        x3[(size_t)(r0 + w * 16 + kg * 4 + j) * 16 + ln15] = acc3[j] + bf3[ln15];
    }
  }
}

// ---------------- triu mask + symmetrize ----------------
__global__ void k_sym(const float* __restrict__ x3, float* __restrict__ out) {
  int t = blockIdx.x * 256 + threadIdx.x;
  if (t >= SEGN * 4) return;
  int q = t & 3;
  int cell = t >> 2;
  int j = cell % Nn;
  int tmp = cell / Nn;
  int i = tmp % Nn;
  int b = tmp / Nn;
  float4 v = make_float4(0.f, 0.f, 0.f, 0.f);
  if (i <= j) v = *(const float4*)&x3[(size_t)cell * 16 + q * 4];
  if (j <= i) {
    int cell2 = (b * Nn + j) * Nn + i;
    float4 u = *(const float4*)&x3[(size_t)cell2 * 16 + q * 4];
    v.x += u.x; v.y += u.y; v.z += u.z; v.w += u.w;
  }
  *(float4*)&out[(size_t)t * 4] = v;
}

extern "C" void kernel_launch(void* const* d_in, const int* in_sizes, int n_in,
                              void* d_out, int out_size, void* d_ws, size_t ws_size,
                              hipStream_t stream) {
  const int*   rel_type  = (const int*)d_in[0];
  const float* rel_error = (const float*)d_in[1];
  const int*   edge_pos  = (const int*)d_in[2];
  const int*   dist      = (const int*)d_in[3];
  const int*   rel_row   = (const int*)d_in[4];
  const float* type_tab = (const float*)d_in[8];
  const float* pos_tab  = (const float*)d_in[9];
  const float* dist_tab = (const float*)d_in[10];
  const float* w1 = (const float*)d_in[11]; const float* b1 = (const float*)d_in[12];
  const float* w2 = (const float*)d_in[13]; const float* b2 = (const float*)d_in[14];
  const float* w3 = (const float*)d_in[15]; const float* b3 = (const float*)d_in[16];
  const float* g1 = (const float*)d_in[17]; const float* be1 = (const float*)d_in[18];
  const float* wf1 = (const float*)d_in[19]; const float* bf1 = (const float*)d_in[20];
  const float* g2 = (const float*)d_in[21]; const float* be2 = (const float*)d_in[22];
  const float* wf2 = (const float*)d_in[23]; const float* bf2 = (const float*)d_in[24];
  const float* g3 = (const float*)d_in[25]; const float* be3 = (const float*)d_in[26];
  const float* wf3 = (const float*)d_in[27]; const float* bf3 = (const float*)d_in[28];

  const int E = in_sizes[0];
  const size_t h3_bytes  = (size_t)E * 512 * 2;        // 204.8 MB (f16)
  const size_t x3_bytes  = (size_t)SEGN * 16 * 4;      // 6.55 MB
  const size_t ptr_bytes = (size_t)(SEGN + 1) * 4;     // 410 KB
  const size_t wt_elems  = 32768 + 131072 + 262144 * 3 + 8192;
  if (ws_size < h3_bytes + x3_bytes + ptr_bytes + wt_elems * 2) return;

  _Float16* h3      = (_Float16*)d_ws;
  float*    x3      = (float*)((char*)d_ws + h3_bytes);
  int*      row_ptr = (int*)((char*)d_ws + h3_bytes + x3_bytes);
  _Float16* w1t     = (_Float16*)((char*)d_ws + h3_bytes + x3_bytes + ptr_bytes);
  _Float16* w2t  = w1t + 32768;
  _Float16* w3t  = w2t + 131072;
  _Float16* wf1t = w3t + 262144;
  _Float16* wf2t = wf1t + 262144;
  _Float16* wf3t = wf2t + 262144;
  float*    out  = (float*)d_out;

  k_prep<<<3744, 256, 0, stream>>>(w1, w2, w3, wf1, wf2, wf3,
                                   w1t, w2t, w3t, wf1t, wf2t, wf3t);
  k_ptr<<<(SEGN + 256) / 256, 256, 0, stream>>>(rel_row, row_ptr, E);
  k_edge<<<(E + 63) / 64, 512, 0, stream>>>(rel_type, rel_error, edge_pos,
                                            type_tab, pos_tab, w1t, b1, w2t, b2, w3t, b3,
                                            h3, E);
  k_fc<<<SEGN / 64, 512, 0, stream>>>(h3, row_ptr, dist, dist_tab,
                                      g1, be1, wf1t, bf1,
                                      g2, be2, wf2t, bf2,
                                      g3, be3, wf3t, bf3, x3);
  k_sym<<<(SEGN * 4 + 255) / 256, 256, 0, stream>>>(x3, out);
}

// Round 11
// 690.805 us; speedup vs baseline: 1.1712x; 1.0360x over previous
//
#include <hip/hip_runtime.h>

typedef __attribute__((ext_vector_type(8))) _Float16 half8;
typedef __attribute__((ext_vector_type(4))) _Float16 half4;
typedef __attribute__((ext_vector_type(4))) float f32x4;

constexpr int Bn = 4;
constexpr int Nn = 160;
constexpr int SEGN = Bn * Nn * Nn;        // 102400 segments

// ------- weight prepass: f32 [K][N] -> f16 chunk-blocked [k/32][N][32] -------
// (wf3: [512][16] -> [16][512] plain transpose)
__global__ void k_prep(const float* __restrict__ w1, const float* __restrict__ w2,
                       const float* __restrict__ w3, const float* __restrict__ wf1,
                       const float* __restrict__ wf2, const float* __restrict__ wf3,
                       _Float16* __restrict__ o1, _Float16* __restrict__ o2,
                       _Float16* __restrict__ o3, _Float16* __restrict__ of1,
                       _Float16* __restrict__ of2, _Float16* __restrict__ of3) {
  int t = blockIdx.x * 256 + threadIdx.x;
  const float* src; _Float16* dst; int N, local; bool is3 = false;
  if (t < 32768)       { src = w1;  dst = o1;  N = 256; local = t; }
  else if (t < 163840) { src = w2;  dst = o2;  N = 512; local = t - 32768; }
  else if (t < 425984) { src = w3;  dst = o3;  N = 512; local = t - 163840; }
  else if (t < 688128) { src = wf1; dst = of1; N = 512; local = t - 425984; }
  else if (t < 950272) { src = wf2; dst = of2; N = 512; local = t - 688128; }
  else if (t < 958464) { src = wf3; dst = of3; N = 16;  local = t - 950272; is3 = true; }
  else return;
  int k = local / N;
  int n = local - k * N;
  if (is3) dst[n * 512 + k] = (_Float16)src[local];
  else dst[(size_t)((k >> 5) * N + n) * 32 + (k & 31)] = (_Float16)src[local];
}

// ------- CSR row pointers from sorted rel_row: row_ptr[r] = lower_bound(r) -------
__global__ void k_ptr(const int* __restrict__ rel_row, int* __restrict__ row_ptr, int E) {
  int r = blockIdx.x * 256 + threadIdx.x;
  if (r > SEGN) return;
  if (r == SEGN) { row_ptr[r] = E; return; }
  int lo = 0, hi = E;
  while (lo < hi) { int mid = (lo + hi) >> 1; if (rel_row[mid] < r) lo = mid + 1; else hi = mid; }
  row_ptr[r] = lo;
}

// ---------------- MFMA slice, B direct from global (L2-resident) ----------------
// A in LDS: f16 [M][K], rowB = 2K bytes, byte ^= ((row&7)<<4).
// W chunk-blocked global [c][NSTRIDE][32] f16.
template <int MT, int K, int C0, int CN, int NSTRIDE, int NT>
__device__ __forceinline__ void do_slice(const _Float16* __restrict__ wt,
                                         const char* a_base, int nbase,
                                         f32x4 (&acc)[MT][NT], int tid) {
  constexpr int rowB = K * 2;
  const int w = tid >> 6, lane = tid & 63, ln15 = lane & 15, kg = lane >> 4;
  const char* wb = (const char*)wt;
#pragma unroll
  for (int c = 0; c < CN; ++c) {
    half8 a[MT], b[NT];
#pragma unroll
    for (int nt = 0; nt < NT; ++nt) {
      int n = nbase + (w * NT + nt) * 16 + ln15;
      b[nt] = *(const half8*)(wb + (size_t)(C0 + c) * (NSTRIDE * 64) + n * 64 + kg * 16);
    }
#pragma unroll
    for (int mt = 0; mt < MT; ++mt) {
      int row = mt * 16 + ln15;
      int byte = (row * rowB + c * 64 + kg * 16) ^ ((row & 7) << 4);
      a[mt] = *(const half8*)(a_base + byte);
    }
#pragma unroll
    for (int mt = 0; mt < MT; ++mt)
#pragma unroll
      for (int nt = 0; nt < NT; ++nt)
        acc[mt][nt] = __builtin_amdgcn_mfma_f32_16x16x32_f16(a[mt], b[nt], acc[mt][nt], 0, 0, 0);
  }
}

template <int MT, int NT>
__device__ __forceinline__ void init_accn(const float* __restrict__ bias, int nbase,
                                          f32x4 (&acc)[MT][NT], int tid) {
  const int w = tid >> 6, ln15 = tid & 15;
#pragma unroll
  for (int nt = 0; nt < NT; ++nt) {
    float bv = bias[nbase + (w * NT + nt) * 16 + ln15];
    f32x4 s = {bv, bv, bv, bv};
#pragma unroll
    for (int mt = 0; mt < MT; ++mt) acc[mt][nt] = s;
  }
}

// C layout: col = lane&15, row = (lane>>4)*4 + j  [m89 verified]
template <int MT, int NT, bool RELU>
__device__ __forceinline__ void store_hn(char* h, int rowB, int nbase,
                                         const f32x4 (&acc)[MT][NT], int tid) {
  const int w = tid >> 6, lane = tid & 63, ln15 = lane & 15, kg = lane >> 4;
#pragma unroll
  for (int mt = 0; mt < MT; ++mt)
#pragma unroll
    for (int nt = 0; nt < NT; ++nt)
#pragma unroll
      for (int j = 0; j < 4; ++j) {
        int row = mt * 16 + kg * 4 + j;
        int n = nbase + (w * NT + nt) * 16 + ln15;
        float v = acc[mt][nt][j];
        if (RELU) v = fmaxf(v, 0.f);
        *(_Float16*)(h + ((row * rowB + n * 2) ^ ((row & 7) << 4))) = (_Float16)v;
      }
}

// ---------------- fused edge MLP (MFMA) -> plain f16 stores (no atomics) ----------------
__global__ __launch_bounds__(512) void k_edge(
    const int* __restrict__ rel_type, const float* __restrict__ rel_error,
    const int* __restrict__ edge_pos,
    const float* __restrict__ type_tab, const float* __restrict__ pos_tab,
    const _Float16* __restrict__ w1t, const float* __restrict__ b1,
    const _Float16* __restrict__ w2t, const float* __restrict__ b2,
    const _Float16* __restrict__ w3t, const float* __restrict__ b3,
    _Float16* __restrict__ h3, int E) {
  __shared__ __align__(16) char smem[98304];
  char* h1 = smem;            // [64][256] f16, rowB 512
  char* h2 = smem + 32768;    // [64][512] f16, rowB 1024
  char* e  = smem + 32768;    // [64][128] f16, rowB 256 (dead before h2 written)

  const int tid = threadIdx.x;
  const int e0 = blockIdx.x * 64;

  // ---- build e tile ----
  {
    int r = tid >> 3, c0 = (tid & 7) * 16;
    int re = min(e0 + r, E - 1);
    int rt = rel_type[re];
    int ep = edge_pos[re];
#pragma unroll
    for (int s = 0; s < 2; ++s) {
      half8 hv;
#pragma unroll
      for (int q = 0; q < 8; ++q) {
        int cc = c0 + s * 8 + q;
        float v = (cc < 120) ? (rt ? type_tab[rt * 120 + cc] : 0.f)
                             : rel_error[(size_t)re * 8 + (cc - 120)];
        v += pos_tab[ep * 128 + cc];
        hv[q] = (_Float16)v;
      }
      int byte = (r * 256 + (c0 + s * 8) * 2) ^ ((r & 7) << 4);
      *(half8*)(e + byte) = hv;
    }
  }
  __syncthreads();

  {  // layer 1: [64x128]@[128x256] + relu -> h1
    f32x4 acc[4][2];
    init_accn<4, 2>(b1, 0, acc, tid);
    do_slice<4, 128, 0, 4, 256, 2>(w1t, e, 0, acc, tid);
    store_hn<4, 2, true>(h1, 512, 0, acc, tid);
  }
  __syncthreads();
  {  // layer 2: [64x256]@[256x512] + relu -> h2 (overwrites e region, reads drained)
    f32x4 acc[4][4];
    init_accn<4, 4>(b2, 0, acc, tid);
    do_slice<4, 256, 0, 8, 512, 4>(w2t, h1, 0, acc, tid);
    store_hn<4, 4, true>(h2, 1024, 0, acc, tid);
  }
  __syncthreads();
  {  // layer 3: [64x512]@[512x512] -> h2 (LDS) -> coalesced global f16 stream
    f32x4 acc[4][4];
    init_accn<4, 4>(b3, 0, acc, tid);
    do_slice<4, 512, 0, 16, 512, 4>(w3t, h2, 0, acc, tid);
    __syncthreads();                       // all h2 reads complete
    store_hn<4, 4, false>(h2, 1024, 0, acc, tid);
    __syncthreads();
    uint4* dst = (uint4*)(h3 + (size_t)e0 * 512);
#pragma unroll
    for (int i = 0; i < 8; ++i) {
      int cidx = tid + i * 512;            // 16B chunk index, 4096 total
      int byteoff = cidx * 16;
      int row = byteoff >> 10;
      uint4 v = *(const uint4*)(h2 + (byteoff ^ ((row & 7) << 4)));
      if (e0 + row < E) dst[cidx] = v;
    }
  }
}

// ---- in-register epilogue: relu -> LN (shfl + 2-stage LDS) -> store f16 ----
__device__ __forceinline__ void epi_ln_store(f32x4 (&acc)[4][4], char* dst,
                                             float* st1, float* st2,
                                             float* stM, float* stR,
                                             const float* __restrict__ g,
                                             const float* __restrict__ be, int tid) {
  const int w = tid >> 6, lane = tid & 63, ln15 = lane & 15, kg = lane >> 4;
#pragma unroll
  for (int mt = 0; mt < 4; ++mt)
#pragma unroll
    for (int nt = 0; nt < 4; ++nt)
#pragma unroll
      for (int j = 0; j < 4; ++j) acc[mt][nt][j] = fmaxf(acc[mt][nt][j], 0.f);
#pragma unroll
  for (int mt = 0; mt < 4; ++mt)
#pragma unroll
    for (int j = 0; j < 4; ++j) {
      float a = 0.f, b = 0.f;
#pragma unroll
      for (int nt = 0; nt < 4; ++nt) { float v = acc[mt][nt][j]; a += v; b += v * v; }
#pragma unroll
      for (int m = 1; m < 16; m <<= 1) { a += __shfl_xor(a, m); b += __shfl_xor(b, m); }
      if (ln15 == 0) {
        int r = mt * 16 + kg * 4 + j;
        st1[w * 64 + r] = a;
        st2[w * 64 + r] = b;
      }
    }
  __syncthreads();
  if (tid < 64) {
    float a = 0.f, b = 0.f;
#pragma unroll
    for (int ww = 0; ww < 8; ++ww) { a += st1[ww * 64 + tid]; b += st2[ww * 64 + tid]; }
    float mean = a * (1.f / 512.f);
    float var = b * (1.f / 512.f) - mean * mean;
    stM[tid] = mean;
    stR[tid] = rsqrtf(var + 1e-5f);
  }
  __syncthreads();
  float gv[4], bv[4];
#pragma unroll
  for (int nt = 0; nt < 4; ++nt) {
    int n = (w * 4 + nt) * 16 + ln15;
    gv[nt] = g[n]; bv[nt] = be[n];
  }
#pragma unroll
  for (int mt = 0; mt < 4; ++mt)
#pragma unroll
    for (int j = 0; j < 4; ++j) {
      int r = mt * 16 + kg * 4 + j;
      float mean = stM[r], rs = stR[r];
#pragma unroll
      for (int nt = 0; nt < 4; ++nt) {
        int n = (w * 4 + nt) * 16 + ln15;
        float v = (acc[mt][nt][j] - mean) * rs * gv[nt] + bv[nt];
        *(_Float16*)(dst + ((r * 1024 + n * 2) ^ ((r & 7) << 4))) = (_Float16)v;
      }
    }
  __syncthreads();
}

// -------- fused FC: gather-max(h3 CSR) + dist -> LN -> fc1 -> LN -> fc2 -> LN -> fc3 --------
__global__ __launch_bounds__(512, 2) void k_fc(
    const _Float16* __restrict__ h3, const int* __restrict__ row_ptr,
    const int* __restrict__ dist, const float* __restrict__ dist_tab,
    const float* __restrict__ g1, const float* __restrict__ be1,
    const _Float16* __restrict__ wf1t, const float* __restrict__ bf1,
    const float* __restrict__ g2, const float* __restrict__ be2,
    const _Float16* __restrict__ wf2t, const float* __restrict__ bf2,
    const float* __restrict__ g3, const float* __restrict__ be3,
    const _Float16* __restrict__ wf3t, const float* __restrict__ bf3,
    float* __restrict__ x3) {
  __shared__ __align__(16) char bufA[65536];  // [64][512] f16, rowB 1024
  __shared__ float st1[512], st2[512];
  __shared__ float stM[64], stR[64];

  const int tid = threadIdx.x;
  const int r0 = blockIdx.x * 64;

  // ---- prologue: segment-max gather (2-deep pipelined, packed f16 max) ----
  {
    const int r = tid >> 3, cp = tid & 7;
    const int gr = r0 + r;
    const int s = row_ptr[gr], en = row_ptr[gr + 1];
    const int di = dist[gr];
    const float* dt = dist_tab + (size_t)di * 512;

    half8 mx[8];
    const _Float16 NEGH = (_Float16)(-65504.f);
#pragma unroll
    for (int i = 0; i < 8; ++i)
#pragma unroll
      for (int q = 0; q < 8; ++q) mx[i][q] = NEGH;

    if (s < en) {
      half8 cur[8];
      const half8* src = (const half8*)(h3 + (size_t)s * 512 + cp * 64);
#pragma unroll
      for (int i = 0; i < 8; ++i) cur[i] = src[i];
      for (int idx = s + 1; idx < en; ++idx) {
        const half8* nsrc = (const half8*)(h3 + (size_t)idx * 512 + cp * 64);
        half8 nxt[8];
#pragma unroll
        for (int i = 0; i < 8; ++i) nxt[i] = nsrc[i];       // issue before consuming cur
#pragma unroll
        for (int i = 0; i < 8; ++i) mx[i] = __builtin_elementwise_max(mx[i], cur[i]);
#pragma unroll
        for (int i = 0; i < 8; ++i) cur[i] = nxt[i];
      }
#pragma unroll
      for (int i = 0; i < 8; ++i) mx[i] = __builtin_elementwise_max(mx[i], cur[i]);
    }

    const bool empty = (s == en);
    float s1 = 0.f, s2 = 0.f;
#pragma unroll
    for (int i = 0; i < 8; ++i) {
      int c0 = cp * 64 + i * 8;
      half8 hv;
#pragma unroll
      for (int q = 0; q < 8; ++q) {
        float v = empty ? 0.f : (float)mx[i][q];
        if (di) v += dt[c0 + q];
        v = fmaxf(v, 0.f);
        s1 += v; s2 += v * v;
        hv[q] = (_Float16)v;
      }
      *(half8*)(bufA + ((r * 1024 + c0 * 2) ^ ((r & 7) << 4))) = hv;
    }
#pragma unroll
    for (int o = 4; o > 0; o >>= 1) { s1 += __shfl_down(s1, o); s2 += __shfl_down(s2, o); }
    if (cp == 0) {
      float mean = s1 * (1.f / 512.f);
      float var = s2 * (1.f / 512.f) - mean * mean;
      stM[r] = mean;
      stR[r] = rsqrtf(var + 1e-5f);
    }
    __syncthreads();
    float mean = stM[r], rs = stR[r];
#pragma unroll
    for (int i = 0; i < 16; ++i) {
      int c = cp * 64 + i * 4;
      int byte = (r * 1024 + c * 2) ^ ((r & 7) << 4);
      half4 hv = *(half4*)(bufA + byte);
      float4 g4 = *(const float4*)(g1 + c);
      float4 b4 = *(const float4*)(be1 + c);
      half4 ov = {(_Float16)(((float)hv[0] - mean) * rs * g4.x + b4.x),
                  (_Float16)(((float)hv[1] - mean) * rs * g4.y + b4.y),
                  (_Float16)(((float)hv[2] - mean) * rs * g4.z + b4.z),
                  (_Float16)(((float)hv[3] - mean) * rs * g4.w + b4.w)};
      *(half4*)(bufA + byte) = ov;
    }
  }
  __syncthreads();

  {  // fc1: bufA @ wf1 -> LN2 -> bufA (in-place)
    f32x4 acc[4][4];
    init_accn<4, 4>(bf1, 0, acc, tid);
    do_slice<4, 512, 0, 16, 512, 4>(wf1t, bufA, 0, acc, tid);
    epi_ln_store(acc, bufA, st1, st2, stM, stR, g2, be2, tid);
  }
  {  // fc2: bufA @ wf2 -> LN3 -> bufA (in-place)
    f32x4 acc[4][4];
    init_accn<4, 4>(bf2, 0, acc, tid);
    do_slice<4, 512, 0, 16, 512, 4>(wf2t, bufA, 0, acc, tid);
    epi_ln_store(acc, bufA, st1, st2, stM, stR, g3, be3, tid);
  }
  {  // fc3: bufA @ wf3 [64x512]@[512x16], 4-wave M-split, direct store
    const int w = tid >> 6, lane = tid & 63, ln15 = lane & 15, kg = lane >> 4;
    if (w < 4) {
      f32x4 acc3 = {0.f, 0.f, 0.f, 0.f};
#pragma unroll
      for (int c = 0; c < 16; ++c) {
        half8 b = *(const half8*)((const char*)wf3t + ln15 * 1024 + c * 64 + kg * 16);
        int row = w * 16 + ln15;
        half8 a = *(const half8*)(bufA + ((row * 1024 + c * 64 + kg * 16) ^ ((row & 7) << 4)));
        acc3 = __builtin_amdgcn_mfma_f32_16x16x32_f16(a, b, acc3, 0, 0, 0);
      }
#pragma unroll
      for (int j = 0; j < 4; ++j)
        x3[(size_t)(r0 + w * 16 + kg * 4 + j) * 16 + ln15] = acc3[j] + bf3[ln15];
    }
  }
}

// ---------------- triu mask + symmetrize ----------------
__global__ void k_sym(const float* __restrict__ x3, float* __restrict__ out) {
  int t = blockIdx.x * 256 + threadIdx.x;
  if (t >= SEGN * 4) return;
  int q = t & 3;
  int cell = t >> 2;
  int j = cell % Nn;
  int tmp = cell / Nn;
  int i = tmp % Nn;
  int b = tmp / Nn;
  float4 v = make_float4(0.f, 0.f, 0.f, 0.f);
  if (i <= j) v = *(const float4*)&x3[(size_t)cell * 16 + q * 4];
  if (j <= i) {
    int cell2 = (b * Nn + j) * Nn + i;
    float4 u = *(const float4*)&x3[(size_t)cell2 * 16 + q * 4];
    v.x += u.x; v.y += u.y; v.z += u.z; v.w += u.w;
  }
  *(float4*)&out[(size_t)t * 4] = v;
}

extern "C" void kernel_launch(void* const* d_in, const int* in_sizes, int n_in,
                              void* d_out, int out_size, void* d_ws, size_t ws_size,
                              hipStream_t stream) {
  const int*   rel_type  = (const int*)d_in[0];
  const float* rel_error = (const float*)d_in[1];
  const int*   edge_pos  = (const int*)d_in[2];
  const int*   dist      = (const int*)d_in[3];
  const int*   rel_row   = (const int*)d_in[4];
  const float* type_tab = (const float*)d_in[8];
  const float* pos_tab  = (const float*)d_in[9];
  const float* dist_tab = (const float*)d_in[10];
  const float* w1 = (const float*)d_in[11]; const float* b1 = (const float*)d_in[12];
  const float* w2 = (const float*)d_in[13]; const float* b2 = (const float*)d_in[14];
  const float* w3 = (const float*)d_in[15]; const float* b3 = (const float*)d_in[16];
  const float* g1 = (const float*)d_in[17]; const float* be1 = (const float*)d_in[18];
  const float* wf1 = (const float*)d_in[19]; const float* bf1 = (const float*)d_in[20];
  const float* g2 = (const float*)d_in[21]; const float* be2 = (const float*)d_in[22];
  const float* wf2 = (const float*)d_in[23]; const float* bf2 = (const float*)d_in[24];
  const float* g3 = (const float*)d_in[25]; const float* be3 = (const float*)d_in[26];
  const float* wf3 = (const float*)d_in[27]; const float* bf3 = (const float*)d_in[28];

  const int E = in_sizes[0];
  const size_t h3_bytes  = (size_t)E * 512 * 2;        // 204.8 MB (f16)
  const size_t x3_bytes  = (size_t)SEGN * 16 * 4;      // 6.55 MB
  const size_t ptr_bytes = (size_t)(SEGN + 1) * 4;     // 410 KB
  const size_t wt_elems  = 32768 + 131072 + 262144 * 3 + 8192;
  if (ws_size < h3_bytes + x3_bytes + ptr_bytes + wt_elems * 2) return;

  _Float16* h3      = (_Float16*)d_ws;
  float*    x3      = (float*)((char*)d_ws + h3_bytes);
  int*      row_ptr = (int*)((char*)d_ws + h3_bytes + x3_bytes);
  _Float16* w1t     = (_Float16*)((char*)d_ws + h3_bytes + x3_bytes + ptr_bytes);
  _Float16* w2t  = w1t + 32768;
  _Float16* w3t  = w2t + 131072;
  _Float16* wf1t = w3t + 262144;
  _Float16* wf2t = wf1t + 262144;
  _Float16* wf3t = wf2t + 262144;
  float*    out  = (float*)d_out;

  k_prep<<<3744, 256, 0, stream>>>(w1, w2, w3, wf1, wf2, wf3,
                                   w1t, w2t, w3t, wf1t, wf2t, wf3t);
  k_ptr<<<(SEGN + 256) / 256, 256, 0, stream>>>(rel_row, row_ptr, E);
  k_edge<<<(E + 63) / 64, 512, 0, stream>>>(rel_type, rel_error, edge_pos,
                                            type_tab, pos_tab, w1t, b1, w2t, b2, w3t, b3,
                                            h3, E);
  k_fc<<<SEGN / 64, 512, 0, stream>>>(h3, row_ptr, dist, dist_tab,
                                      g1, be1, wf1t, bf1,
                                      g2, be2, wf2t, bf2,
                                      g3, be3, wf3t, bf3, x3);
  k_sym<<<(SEGN * 4 + 255) / 256, 256, 0, stream>>>(x3, out);
}

// Round 12
// 653.386 us; speedup vs baseline: 1.2383x; 1.0573x over previous
//
#include <hip/hip_runtime.h>

typedef __attribute__((ext_vector_type(8))) _Float16 half8;
typedef __attribute__((ext_vector_type(4))) _Float16 half4;
typedef __attribute__((ext_vector_type(4))) float f32x4;

constexpr int Bn = 4;
constexpr int Nn = 160;
constexpr int SEGN = Bn * Nn * Nn;        // 102400 segments

// ------- weight prepass: f32 [K][N] -> f16 chunk-blocked [k/32][N][32] -------
// (wf3: [512][16] -> [16][512] plain transpose)
__global__ void k_prep(const float* __restrict__ w1, const float* __restrict__ w2,
                       const float* __restrict__ w3, const float* __restrict__ wf1,
                       const float* __restrict__ wf2, const float* __restrict__ wf3,
                       _Float16* __restrict__ o1, _Float16* __restrict__ o2,
                       _Float16* __restrict__ o3, _Float16* __restrict__ of1,
                       _Float16* __restrict__ of2, _Float16* __restrict__ of3) {
  int t = blockIdx.x * 256 + threadIdx.x;
  const float* src; _Float16* dst; int N, local; bool is3 = false;
  if (t < 32768)       { src = w1;  dst = o1;  N = 256; local = t; }
  else if (t < 163840) { src = w2;  dst = o2;  N = 512; local = t - 32768; }
  else if (t < 425984) { src = w3;  dst = o3;  N = 512; local = t - 163840; }
  else if (t < 688128) { src = wf1; dst = of1; N = 512; local = t - 425984; }
  else if (t < 950272) { src = wf2; dst = of2; N = 512; local = t - 688128; }
  else if (t < 958464) { src = wf3; dst = of3; N = 16;  local = t - 950272; is3 = true; }
  else return;
  int k = local / N;
  int n = local - k * N;
  if (is3) dst[n * 512 + k] = (_Float16)src[local];
  else dst[(size_t)((k >> 5) * N + n) * 32 + (k & 31)] = (_Float16)src[local];
}

// ------- CSR row pointers from sorted rel_row: row_ptr[r] = lower_bound(r) -------
__global__ void k_ptr(const int* __restrict__ rel_row, int* __restrict__ row_ptr, int E) {
  int r = blockIdx.x * 256 + threadIdx.x;
  if (r > SEGN) return;
  if (r == SEGN) { row_ptr[r] = E; return; }
  int lo = 0, hi = E;
  while (lo < hi) { int mid = (lo + hi) >> 1; if (rel_row[mid] < r) lo = mid + 1; else hi = mid; }
  row_ptr[r] = lo;
}

// ---------------- MFMA slice, B direct from global (L2-resident) ----------------
// A in LDS: f16 [M][K], rowB = 2K bytes, byte ^= ((row&7)<<4).
// W chunk-blocked global [c][NSTRIDE][32] f16.
template <int MT, int K, int C0, int CN, int NSTRIDE, int NT>
__device__ __forceinline__ void do_slice(const _Float16* __restrict__ wt,
                                         const char* a_base, int nbase,
                                         f32x4 (&acc)[MT][NT], int tid) {
  constexpr int rowB = K * 2;
  const int w = tid >> 6, lane = tid & 63, ln15 = lane & 15, kg = lane >> 4;
  const char* wb = (const char*)wt;
#pragma unroll
  for (int c = 0; c < CN; ++c) {
    half8 a[MT], b[NT];
#pragma unroll
    for (int nt = 0; nt < NT; ++nt) {
      int n = nbase + (w * NT + nt) * 16 + ln15;
      b[nt] = *(const half8*)(wb + (size_t)(C0 + c) * (NSTRIDE * 64) + n * 64 + kg * 16);
    }
#pragma unroll
    for (int mt = 0; mt < MT; ++mt) {
      int row = mt * 16 + ln15;
      int byte = (row * rowB + c * 64 + kg * 16) ^ ((row & 7) << 4);
      a[mt] = *(const half8*)(a_base + byte);
    }
#pragma unroll
    for (int mt = 0; mt < MT; ++mt)
#pragma unroll
      for (int nt = 0; nt < NT; ++nt)
        acc[mt][nt] = __builtin_amdgcn_mfma_f32_16x16x32_f16(a[mt], b[nt], acc[mt][nt], 0, 0, 0);
  }
}

template <int MT, int NT>
__device__ __forceinline__ void init_accn(const float* __restrict__ bias, int nbase,
                                          f32x4 (&acc)[MT][NT], int tid) {
  const int w = tid >> 6, ln15 = tid & 15;
#pragma unroll
  for (int nt = 0; nt < NT; ++nt) {
    float bv = bias[nbase + (w * NT + nt) * 16 + ln15];
    f32x4 s = {bv, bv, bv, bv};
#pragma unroll
    for (int mt = 0; mt < MT; ++mt) acc[mt][nt] = s;
  }
}

// C layout: col = lane&15, row = (lane>>4)*4 + j  [m89 verified]
template <int MT, int NT, bool RELU>
__device__ __forceinline__ void store_hn(char* h, int rowB, int nbase,
                                         const f32x4 (&acc)[MT][NT], int tid) {
  const int w = tid >> 6, lane = tid & 63, ln15 = lane & 15, kg = lane >> 4;
#pragma unroll
  for (int mt = 0; mt < MT; ++mt)
#pragma unroll
    for (int nt = 0; nt < NT; ++nt)
#pragma unroll
      for (int j = 0; j < 4; ++j) {
        int row = mt * 16 + kg * 4 + j;
        int n = nbase + (w * NT + nt) * 16 + ln15;
        float v = acc[mt][nt][j];
        if (RELU) v = fmaxf(v, 0.f);
        *(_Float16*)(h + ((row * rowB + n * 2) ^ ((row & 7) << 4))) = (_Float16)v;
      }
}

// ---------------- fused edge MLP (MFMA) -> plain f16 stores (no atomics) ----------------
__global__ __launch_bounds__(512) void k_edge(
    const int* __restrict__ rel_type, const float* __restrict__ rel_error,
    const int* __restrict__ edge_pos,
    const float* __restrict__ type_tab, const float* __restrict__ pos_tab,
    const _Float16* __restrict__ w1t, const float* __restrict__ b1,
    const _Float16* __restrict__ w2t, const float* __restrict__ b2,
    const _Float16* __restrict__ w3t, const float* __restrict__ b3,
    _Float16* __restrict__ h3, int E) {
  __shared__ __align__(16) char smem[98304];
  char* h1 = smem;            // [64][256] f16, rowB 512
  char* h2 = smem + 32768;    // [64][512] f16, rowB 1024
  char* e  = smem + 32768;    // [64][128] f16, rowB 256 (dead before h2 written)

  const int tid = threadIdx.x;
  const int e0 = blockIdx.x * 64;

  // ---- build e tile ----
  {
    int r = tid >> 3, c0 = (tid & 7) * 16;
    int re = min(e0 + r, E - 1);
    int rt = rel_type[re];
    int ep = edge_pos[re];
#pragma unroll
    for (int s = 0; s < 2; ++s) {
      half8 hv;
#pragma unroll
      for (int q = 0; q < 8; ++q) {
        int cc = c0 + s * 8 + q;
        float v = (cc < 120) ? (rt ? type_tab[rt * 120 + cc] : 0.f)
                             : rel_error[(size_t)re * 8 + (cc - 120)];
        v += pos_tab[ep * 128 + cc];
        hv[q] = (_Float16)v;
      }
      int byte = (r * 256 + (c0 + s * 8) * 2) ^ ((r & 7) << 4);
      *(half8*)(e + byte) = hv;
    }
  }
  __syncthreads();

  {  // layer 1: [64x128]@[128x256] + relu -> h1
    f32x4 acc[4][2];
    init_accn<4, 2>(b1, 0, acc, tid);
    do_slice<4, 128, 0, 4, 256, 2>(w1t, e, 0, acc, tid);
    store_hn<4, 2, true>(h1, 512, 0, acc, tid);
  }
  __syncthreads();
  {  // layer 2: [64x256]@[256x512] + relu -> h2 (overwrites e region, reads drained)
    f32x4 acc[4][4];
    init_accn<4, 4>(b2, 0, acc, tid);
    do_slice<4, 256, 0, 8, 512, 4>(w2t, h1, 0, acc, tid);
    store_hn<4, 4, true>(h2, 1024, 0, acc, tid);
  }
  __syncthreads();
  {  // layer 3: [64x512]@[512x512] -> h2 (LDS) -> coalesced global f16 stream
    f32x4 acc[4][4];
    init_accn<4, 4>(b3, 0, acc, tid);
    do_slice<4, 512, 0, 16, 512, 4>(w3t, h2, 0, acc, tid);
    __syncthreads();                       // all h2 reads complete
    store_hn<4, 4, false>(h2, 1024, 0, acc, tid);
    __syncthreads();
    uint4* dst = (uint4*)(h3 + (size_t)e0 * 512);
#pragma unroll
    for (int i = 0; i < 8; ++i) {
      int cidx = tid + i * 512;            // 16B chunk index, 4096 total
      int byteoff = cidx * 16;
      int row = byteoff >> 10;
      uint4 v = *(const uint4*)(h2 + (byteoff ^ ((row & 7) << 4)));
      if (e0 + row < E) dst[cidx] = v;
    }
  }
}

// ---- in-register epilogue: relu -> LN (shfl + 2-stage LDS) -> store f16 ----
__device__ __forceinline__ void epi_ln_store(f32x4 (&acc)[4][4], char* dst,
                                             float* st1, float* st2,
                                             float* stM, float* stR,
                                             const float* __restrict__ g,
                                             const float* __restrict__ be, int tid) {
  const int w = tid >> 6, lane = tid & 63, ln15 = lane & 15, kg = lane >> 4;
#pragma unroll
  for (int mt = 0; mt < 4; ++mt)
#pragma unroll
    for (int nt = 0; nt < 4; ++nt)
#pragma unroll
      for (int j = 0; j < 4; ++j) acc[mt][nt][j] = fmaxf(acc[mt][nt][j], 0.f);
#pragma unroll
  for (int mt = 0; mt < 4; ++mt)
#pragma unroll
    for (int j = 0; j < 4; ++j) {
      float a = 0.f, b = 0.f;
#pragma unroll
      for (int nt = 0; nt < 4; ++nt) { float v = acc[mt][nt][j]; a += v; b += v * v; }
#pragma unroll
      for (int m = 1; m < 16; m <<= 1) { a += __shfl_xor(a, m); b += __shfl_xor(b, m); }
      if (ln15 == 0) {
        int r = mt * 16 + kg * 4 + j;
        st1[w * 64 + r] = a;
        st2[w * 64 + r] = b;
      }
    }
  __syncthreads();
  if (tid < 64) {
    float a = 0.f, b = 0.f;
#pragma unroll
    for (int ww = 0; ww < 8; ++ww) { a += st1[ww * 64 + tid]; b += st2[ww * 64 + tid]; }
    float mean = a * (1.f / 512.f);
    float var = b * (1.f / 512.f) - mean * mean;
    stM[tid] = mean;
    stR[tid] = rsqrtf(var + 1e-5f);
  }
  __syncthreads();
  float gv[4], bv[4];
#pragma unroll
  for (int nt = 0; nt < 4; ++nt) {
    int n = (w * 4 + nt) * 16 + ln15;
    gv[nt] = g[n]; bv[nt] = be[n];
  }
#pragma unroll
  for (int mt = 0; mt < 4; ++mt)
#pragma unroll
    for (int j = 0; j < 4; ++j) {
      int r = mt * 16 + kg * 4 + j;
      float mean = stM[r], rs = stR[r];
#pragma unroll
      for (int nt = 0; nt < 4; ++nt) {
        int n = (w * 4 + nt) * 16 + ln15;
        float v = (acc[mt][nt][j] - mean) * rs * gv[nt] + bv[nt];
        *(_Float16*)(dst + ((r * 1024 + n * 2) ^ ((r & 7) << 4))) = (_Float16)v;
      }
    }
  __syncthreads();
}

// -------- fused FC: wave-per-row gather-max(h3) + dist -> LN -> fc1 -> LN -> fc2 -> LN -> fc3 --------
__global__ __launch_bounds__(512, 2) void k_fc(
    const _Float16* __restrict__ h3, const int* __restrict__ row_ptr,
    const int* __restrict__ dist, const float* __restrict__ dist_tab,
    const float* __restrict__ g1, const float* __restrict__ be1,
    const _Float16* __restrict__ wf1t, const float* __restrict__ bf1,
    const float* __restrict__ g2, const float* __restrict__ be2,
    const _Float16* __restrict__ wf2t, const float* __restrict__ bf2,
    const float* __restrict__ g3, const float* __restrict__ be3,
    const _Float16* __restrict__ wf3t, const float* __restrict__ bf3,
    float* __restrict__ x3) {
  __shared__ __align__(16) char bufA[65536];  // [64][512] f16, rowB 1024
  __shared__ float st1[512], st2[512];
  __shared__ float stM[64], stR[64];

  const int tid = threadIdx.x;
  const int r0 = blockIdx.x * 64;

  // ---- phase 1: wave-per-row gather (lane = col slice, coalesced 1KB/edge) ----
  {
    const int w = tid >> 6, lane = tid & 63;
    const int coff = lane * 8;
    const float* gp = g1 + coff;
    const float* bp = be1 + coff;
    const _Float16 NEGH = (_Float16)(-65504.f);
    for (int rr = 0; rr < 8; ++rr) {
      int rloc = w * 8 + rr;
      int gr = r0 + rloc;
      int s = row_ptr[gr], en = row_ptr[gr + 1];
      int di = dist[gr];
      half8 mx;
#pragma unroll
      for (int q = 0; q < 8; ++q) mx[q] = NEGH;
      int idx = s;
      while (idx + 4 <= en) {   // uniform across wave (same s/en) -> no divergence
        half8 c0 = *(const half8*)(h3 + (size_t)(idx + 0) * 512 + coff);
        half8 c1 = *(const half8*)(h3 + (size_t)(idx + 1) * 512 + coff);
        half8 c2 = *(const half8*)(h3 + (size_t)(idx + 2) * 512 + coff);
        half8 c3 = *(const half8*)(h3 + (size_t)(idx + 3) * 512 + coff);
        mx = __builtin_elementwise_max(mx, __builtin_elementwise_max(
                 __builtin_elementwise_max(c0, c1), __builtin_elementwise_max(c2, c3)));
        idx += 4;
      }
      if (idx + 2 <= en) {
        half8 c0 = *(const half8*)(h3 + (size_t)(idx + 0) * 512 + coff);
        half8 c1 = *(const half8*)(h3 + (size_t)(idx + 1) * 512 + coff);
        mx = __builtin_elementwise_max(mx, __builtin_elementwise_max(c0, c1));
        idx += 2;
      }
      if (idx < en) {
        half8 c0 = *(const half8*)(h3 + (size_t)idx * 512 + coff);
        mx = __builtin_elementwise_max(mx, c0);
      }
      const float* dt = dist_tab + (size_t)di * 512 + coff;
      float v[8]; float s1 = 0.f, s2 = 0.f;
#pragma unroll
      for (int q = 0; q < 8; ++q) {
        float vv = (s == en) ? 0.f : (float)mx[q];
        if (di) vv += dt[q];
        vv = fmaxf(vv, 0.f);
        v[q] = vv; s1 += vv; s2 += vv * vv;
      }
#pragma unroll
      for (int o = 32; o > 0; o >>= 1) { s1 += __shfl_xor(s1, o); s2 += __shfl_xor(s2, o); }
      float mean = s1 * (1.f / 512.f);
      float rs = rsqrtf(s2 * (1.f / 512.f) - mean * mean + 1e-5f);
      half8 ov;
#pragma unroll
      for (int q = 0; q < 8; ++q) ov[q] = (_Float16)((v[q] - mean) * rs * gp[q] + bp[q]);
      *(half8*)(bufA + ((rloc * 1024 + coff * 2) ^ ((rloc & 7) << 4))) = ov;
    }
  }
  __syncthreads();

  {  // fc1: bufA @ wf1 -> LN2 -> bufA (in-place)
    f32x4 acc[4][4];
    init_accn<4, 4>(bf1, 0, acc, tid);
    do_slice<4, 512, 0, 16, 512, 4>(wf1t, bufA, 0, acc, tid);
    epi_ln_store(acc, bufA, st1, st2, stM, stR, g2, be2, tid);
  }
  {  // fc2: bufA @ wf2 -> LN3 -> bufA (in-place)
    f32x4 acc[4][4];
    init_accn<4, 4>(bf2, 0, acc, tid);
    do_slice<4, 512, 0, 16, 512, 4>(wf2t, bufA, 0, acc, tid);
    epi_ln_store(acc, bufA, st1, st2, stM, stR, g3, be3, tid);
  }
  {  // fc3: bufA @ wf3 [64x512]@[512x16], 4-wave M-split, direct store
    const int w = tid >> 6, lane = tid & 63, ln15 = lane & 15, kg = lane >> 4;
    if (w < 4) {
      f32x4 acc3 = {0.f, 0.f, 0.f, 0.f};
#pragma unroll
      for (int c = 0; c < 16; ++c) {
        half8 b = *(const half8*)((const char*)wf3t + ln15 * 1024 + c * 64 + kg * 16);
        int row = w * 16 + ln15;
        half8 a = *(const half8*)(bufA + ((row * 1024 + c * 64 + kg * 16) ^ ((row & 7) << 4)));
        acc3 = __builtin_amdgcn_mfma_f32_16x16x32_f16(a, b, acc3, 0, 0, 0);
      }
#pragma unroll
      for (int j = 0; j < 4; ++j)
        x3[(size_t)(r0 + w * 16 + kg * 4 + j) * 16 + ln15] = acc3[j] + bf3[ln15];
    }
  }
}

// ---------------- triu mask + symmetrize ----------------
__global__ void k_sym(const float* __restrict__ x3, float* __restrict__ out) {
  int t = blockIdx.x * 256 + threadIdx.x;
  if (t >= SEGN * 4) return;
  int q = t & 3;
  int cell = t >> 2;
  int j = cell % Nn;
  int tmp = cell / Nn;
  int i = tmp % Nn;
  int b = tmp / Nn;
  float4 v = make_float4(0.f, 0.f, 0.f, 0.f);
  if (i <= j) v = *(const float4*)&x3[(size_t)cell * 16 + q * 4];
  if (j <= i) {
    int cell2 = (b * Nn + j) * Nn + i;
    float4 u = *(const float4*)&x3[(size_t)cell2 * 16 + q * 4];
    v.x += u.x; v.y += u.y; v.z += u.z; v.w += u.w;
  }
  *(float4*)&out[(size_t)t * 4] = v;
}

extern "C" void kernel_launch(void* const* d_in, const int* in_sizes, int n_in,
                              void* d_out, int out_size, void* d_ws, size_t ws_size,
                              hipStream_t stream) {
  const int*   rel_type  = (const int*)d_in[0];
  const float* rel_error = (const float*)d_in[1];
  const int*   edge_pos  = (const int*)d_in[2];
  const int*   dist      = (const int*)d_in[3];
  const int*   rel_row   = (const int*)d_in[4];
  const float* type_tab = (const float*)d_in[8];
  const float* pos_tab  = (const float*)d_in[9];
  const float* dist_tab = (const float*)d_in[10];
  const float* w1 = (const float*)d_in[11]; const float* b1 = (const float*)d_in[12];
  const float* w2 = (const float*)d_in[13]; const float* b2 = (const float*)d_in[14];
  const float* w3 = (const float*)d_in[15]; const float* b3 = (const float*)d_in[16];
  const float* g1 = (const float*)d_in[17]; const float* be1 = (const float*)d_in[18];
  const float* wf1 = (const float*)d_in[19]; const float* bf1 = (const float*)d_in[20];
  const float* g2 = (const float*)d_in[21]; const float* be2 = (const float*)d_in[22];
  const float* wf2 = (const float*)d_in[23]; const float* bf2 = (const float*)d_in[24];
  const float* g3 = (const float*)d_in[25]; const float* be3 = (const float*)d_in[26];
  const float* wf3 = (const float*)d_in[27]; const float* bf3 = (const float*)d_in[28];

  const int E = in_sizes[0];
  const size_t h3_bytes  = (size_t)E * 512 * 2;        // 204.8 MB (f16)
  const size_t x3_bytes  = (size_t)SEGN * 16 * 4;      // 6.55 MB
  const size_t ptr_bytes = (size_t)(SEGN + 1) * 4;     // 410 KB
  const size_t wt_elems  = 32768 + 131072 + 262144 * 3 + 8192;
  if (ws_size < h3_bytes + x3_bytes + ptr_bytes + wt_elems * 2) return;

  _Float16* h3      = (_Float16*)d_ws;
  float*    x3      = (float*)((char*)d_ws + h3_bytes);
  int*      row_ptr = (int*)((char*)d_ws + h3_bytes + x3_bytes);
  _Float16* w1t     = (_Float16*)((char*)d_ws + h3_bytes + x3_bytes + ptr_bytes);
  _Float16* w2t  = w1t + 32768;
  _Float16* w3t  = w2t + 131072;
  _Float16* wf1t = w3t + 262144;
  _Float16* wf2t = wf1t + 262144;
  _Float16* wf3t = wf2t + 262144;
  float*    out  = (float*)d_out;

  k_prep<<<3744, 256, 0, stream>>>(w1, w2, w3, wf1, wf2, wf3,
                                   w1t, w2t, w3t, wf1t, wf2t, wf3t);
  k_ptr<<<(SEGN + 256) / 256, 256, 0, stream>>>(rel_row, row_ptr, E);
  k_edge<<<(E + 63) / 64, 512, 0, stream>>>(rel_type, rel_error, edge_pos,
                                            type_tab, pos_tab, w1t, b1, w2t, b2, w3t, b3,
                                            h3, E);
  k_fc<<<SEGN / 64, 512, 0, stream>>>(h3, row_ptr, dist, dist_tab,
                                      g1, be1, wf1t, bf1,
                                      g2, be2, wf2t, bf2,
                                      g3, be3, wf3t, bf3, x3);
  k_sym<<<(SEGN * 4 + 255) / 256, 256, 0, stream>>>(x3, out);
}

// Round 13
// 506.235 us; speedup vs baseline: 1.5983x; 1.2907x over previous
//
#include <hip/hip_runtime.h>

typedef __attribute__((ext_vector_type(8))) _Float16 half8;
typedef __attribute__((ext_vector_type(4))) _Float16 half4;
typedef __attribute__((ext_vector_type(4))) float f32x4;

constexpr int Bn = 4;
constexpr int Nn = 160;
constexpr int SEGN = Bn * Nn * Nn;        // 102400 segments
constexpr int TRIN = Nn * (Nn + 1) / 2;   // 12880 upper-tri cells per batch
constexpr int CMPN = Bn * TRIN;           // 51520 compact rows (= 805 * 64)

__device__ __forceinline__ int tri_base(int i) { return i * Nn - (i * (i - 1)) / 2; }

// ------- weight prepass: f32 [K][N] -> f16 chunk-blocked [k/32][N][32] -------
// (wf3: [512][16] -> [16][512] plain transpose)
__global__ void k_prep(const float* __restrict__ w1, const float* __restrict__ w2,
                       const float* __restrict__ w3, const float* __restrict__ wf1,
                       const float* __restrict__ wf2, const float* __restrict__ wf3,
                       _Float16* __restrict__ o1, _Float16* __restrict__ o2,
                       _Float16* __restrict__ o3, _Float16* __restrict__ of1,
                       _Float16* __restrict__ of2, _Float16* __restrict__ of3) {
  int t = blockIdx.x * 256 + threadIdx.x;
  const float* src; _Float16* dst; int N, local; bool is3 = false;
  if (t < 32768)       { src = w1;  dst = o1;  N = 256; local = t; }
  else if (t < 163840) { src = w2;  dst = o2;  N = 512; local = t - 32768; }
  else if (t < 425984) { src = w3;  dst = o3;  N = 512; local = t - 163840; }
  else if (t < 688128) { src = wf1; dst = of1; N = 512; local = t - 425984; }
  else if (t < 950272) { src = wf2; dst = of2; N = 512; local = t - 688128; }
  else if (t < 958464) { src = wf3; dst = of3; N = 16;  local = t - 950272; is3 = true; }
  else return;
  int k = local / N;
  int n = local - k * N;
  if (is3) dst[n * 512 + k] = (_Float16)src[local];
  else dst[(size_t)((k >> 5) * N + n) * 32 + (k & 31)] = (_Float16)src[local];
}

// ------- CSR row pointers (sorted rel_row) + tri2ij lookup -------
__global__ void k_ptr(const int* __restrict__ rel_row, int* __restrict__ row_ptr,
                      int* __restrict__ tri2ij, int E) {
  int r = blockIdx.x * 256 + threadIdx.x;
  if (r < TRIN) {
    // largest i with tri_base(i) <= r
    int lo = 0, hi = Nn - 1;
    while (lo < hi) { int mid = (lo + hi + 1) >> 1; if (tri_base(mid) <= r) lo = mid; else hi = mid - 1; }
    int j = lo + (r - tri_base(lo));
    tri2ij[r] = (lo << 16) | j;
  }
  if (r > SEGN) return;
  if (r == SEGN) { row_ptr[r] = E; return; }
  int lo = 0, hi = E;
  while (lo < hi) { int mid = (lo + hi) >> 1; if (rel_row[mid] < r) lo = mid + 1; else hi = mid; }
  row_ptr[r] = lo;
}

// ---------------- MFMA slice, B direct from global (L2-resident) ----------------
// A in LDS: f16 [M][K], rowB = 2K bytes, byte ^= ((row&7)<<4).
// W chunk-blocked global [c][NSTRIDE][32] f16.
template <int MT, int K, int C0, int CN, int NSTRIDE, int NT>
__device__ __forceinline__ void do_slice(const _Float16* __restrict__ wt,
                                         const char* a_base, int nbase,
                                         f32x4 (&acc)[MT][NT], int tid) {
  constexpr int rowB = K * 2;
  const int w = tid >> 6, lane = tid & 63, ln15 = lane & 15, kg = lane >> 4;
  const char* wb = (const char*)wt;
#pragma unroll
  for (int c = 0; c < CN; ++c) {
    half8 a[MT], b[NT];
#pragma unroll
    for (int nt = 0; nt < NT; ++nt) {
      int n = nbase + (w * NT + nt) * 16 + ln15;
      b[nt] = *(const half8*)(wb + (size_t)(C0 + c) * (NSTRIDE * 64) + n * 64 + kg * 16);
    }
#pragma unroll
    for (int mt = 0; mt < MT; ++mt) {
      int row = mt * 16 + ln15;
      int byte = (row * rowB + c * 64 + kg * 16) ^ ((row & 7) << 4);
      a[mt] = *(const half8*)(a_base + byte);
    }
#pragma unroll
    for (int mt = 0; mt < MT; ++mt)
#pragma unroll
      for (int nt = 0; nt < NT; ++nt)
        acc[mt][nt] = __builtin_amdgcn_mfma_f32_16x16x32_f16(a[mt], b[nt], acc[mt][nt], 0, 0, 0);
  }
}

template <int MT, int NT>
__device__ __forceinline__ void init_accn(const float* __restrict__ bias, int nbase,
                                          f32x4 (&acc)[MT][NT], int tid) {
  const int w = tid >> 6, ln15 = tid & 15;
#pragma unroll
  for (int nt = 0; nt < NT; ++nt) {
    float bv = bias[nbase + (w * NT + nt) * 16 + ln15];
    f32x4 s = {bv, bv, bv, bv};
#pragma unroll
    for (int mt = 0; mt < MT; ++mt) acc[mt][nt] = s;
  }
}

// C layout: col = lane&15, row = (lane>>4)*4 + j  [m89 verified]
template <int MT, int NT, bool RELU>
__device__ __forceinline__ void store_hn(char* h, int rowB, int nbase,
                                         const f32x4 (&acc)[MT][NT], int tid) {
  const int w = tid >> 6, lane = tid & 63, ln15 = lane & 15, kg = lane >> 4;
#pragma unroll
  for (int mt = 0; mt < MT; ++mt)
#pragma unroll
    for (int nt = 0; nt < NT; ++nt)
#pragma unroll
      for (int j = 0; j < 4; ++j) {
        int row = mt * 16 + kg * 4 + j;
        int n = nbase + (w * NT + nt) * 16 + ln15;
        float v = acc[mt][nt][j];
        if (RELU) v = fmaxf(v, 0.f);
        *(_Float16*)(h + ((row * rowB + n * 2) ^ ((row & 7) << 4))) = (_Float16)v;
      }
}

// ---------------- fused edge MLP (MFMA) -> f16 stores (kept cells only) ----------------
__global__ __launch_bounds__(512) void k_edge(
    const int* __restrict__ rel_type, const float* __restrict__ rel_error,
    const int* __restrict__ edge_pos, const int* __restrict__ rel_row,
    const float* __restrict__ type_tab, const float* __restrict__ pos_tab,
    const _Float16* __restrict__ w1t, const float* __restrict__ b1,
    const _Float16* __restrict__ w2t, const float* __restrict__ b2,
    const _Float16* __restrict__ w3t, const float* __restrict__ b3,
    _Float16* __restrict__ h3, int E) {
  __shared__ __align__(16) char smem[98304];
  __shared__ int keepA[64];
  char* h1 = smem;            // [64][256] f16, rowB 512
  char* h2 = smem + 32768;    // [64][512] f16, rowB 1024
  char* e  = smem + 32768;    // [64][128] f16, rowB 256 (dead before h2 written)

  const int tid = threadIdx.x;
  const int e0 = blockIdx.x * 64;

  // ---- build e tile ----
  {
    int r = tid >> 3, c0 = (tid & 7) * 16;
    int re = min(e0 + r, E - 1);
    int rt = rel_type[re];
    int ep = edge_pos[re];
#pragma unroll
    for (int s = 0; s < 2; ++s) {
      half8 hv;
#pragma unroll
      for (int q = 0; q < 8; ++q) {
        int cc = c0 + s * 8 + q;
        float v = (cc < 120) ? (rt ? type_tab[rt * 120 + cc] : 0.f)
                             : rel_error[(size_t)re * 8 + (cc - 120)];
        v += pos_tab[ep * 128 + cc];
        hv[q] = (_Float16)v;
      }
      int byte = (r * 256 + (c0 + s * 8) * 2) ^ ((r & 7) << 4);
      *(half8*)(e + byte) = hv;
    }
    if (tid < 64) {
      int cell = rel_row[min(e0 + tid, E - 1)];
      int jj = cell % Nn;
      int ii = (cell / Nn) % Nn;
      keepA[tid] = (ii <= jj);
    }
  }
  __syncthreads();

  {  // layer 1: [64x128]@[128x256] + relu -> h1
    f32x4 acc[4][2];
    init_accn<4, 2>(b1, 0, acc, tid);
    do_slice<4, 128, 0, 4, 256, 2>(w1t, e, 0, acc, tid);
    store_hn<4, 2, true>(h1, 512, 0, acc, tid);
  }
  __syncthreads();
  {  // layer 2: [64x256]@[256x512] + relu -> h2 (overwrites e region, reads drained)
    f32x4 acc[4][4];
    init_accn<4, 4>(b2, 0, acc, tid);
    do_slice<4, 256, 0, 8, 512, 4>(w2t, h1, 0, acc, tid);
    store_hn<4, 4, true>(h2, 1024, 0, acc, tid);
  }
  __syncthreads();
  {  // layer 3: [64x512]@[512x512] -> h2 (LDS) -> coalesced f16 stream (kept rows)
    f32x4 acc[4][4];
    init_accn<4, 4>(b3, 0, acc, tid);
    do_slice<4, 512, 0, 16, 512, 4>(w3t, h2, 0, acc, tid);
    __syncthreads();                       // all h2 reads complete
    store_hn<4, 4, false>(h2, 1024, 0, acc, tid);
    __syncthreads();
    uint4* dst = (uint4*)(h3 + (size_t)e0 * 512);
#pragma unroll
    for (int i = 0; i < 8; ++i) {
      int cidx = tid + i * 512;            // 16B chunk index, 4096 total
      int byteoff = cidx * 16;
      int row = byteoff >> 10;
      uint4 v = *(const uint4*)(h2 + (byteoff ^ ((row & 7) << 4)));
      if (e0 + row < E && keepA[row]) dst[cidx] = v;
    }
  }
}

// ---- in-register epilogue: relu -> LN (shfl + 2-stage LDS) -> store f16 ----
__device__ __forceinline__ void epi_ln_store(f32x4 (&acc)[4][4], char* dst,
                                             float* st1, float* st2,
                                             float* stM, float* stR,
                                             const float* __restrict__ g,
                                             const float* __restrict__ be, int tid) {
  const int w = tid >> 6, lane = tid & 63, ln15 = lane & 15, kg = lane >> 4;
#pragma unroll
  for (int mt = 0; mt < 4; ++mt)
#pragma unroll
    for (int nt = 0; nt < 4; ++nt)
#pragma unroll
      for (int j = 0; j < 4; ++j) acc[mt][nt][j] = fmaxf(acc[mt][nt][j], 0.f);
#pragma unroll
  for (int mt = 0; mt < 4; ++mt)
#pragma unroll
    for (int j = 0; j < 4; ++j) {
      float a = 0.f, b = 0.f;
#pragma unroll
      for (int nt = 0; nt < 4; ++nt) { float v = acc[mt][nt][j]; a += v; b += v * v; }
#pragma unroll
      for (int m = 1; m < 16; m <<= 1) { a += __shfl_xor(a, m); b += __shfl_xor(b, m); }
      if (ln15 == 0) {
        int r = mt * 16 + kg * 4 + j;
        st1[w * 64 + r] = a;
        st2[w * 64 + r] = b;
      }
    }
  __syncthreads();
  if (tid < 64) {
    float a = 0.f, b = 0.f;
#pragma unroll
    for (int ww = 0; ww < 8; ++ww) { a += st1[ww * 64 + tid]; b += st2[ww * 64 + tid]; }
    float mean = a * (1.f / 512.f);
    float var = b * (1.f / 512.f) - mean * mean;
    stM[tid] = mean;
    stR[tid] = rsqrtf(var + 1e-5f);
  }
  __syncthreads();
  float gv[4], bv[4];
#pragma unroll
  for (int nt = 0; nt < 4; ++nt) {
    int n = (w * 4 + nt) * 16 + ln15;
    gv[nt] = g[n]; bv[nt] = be[n];
  }
#pragma unroll
  for (int mt = 0; mt < 4; ++mt)
#pragma unroll
    for (int j = 0; j < 4; ++j) {
      int r = mt * 16 + kg * 4 + j;
      float mean = stM[r], rs = stR[r];
#pragma unroll
      for (int nt = 0; nt < 4; ++nt) {
        int n = (w * 4 + nt) * 16 + ln15;
        float v = (acc[mt][nt][j] - mean) * rs * gv[nt] + bv[nt];
        *(_Float16*)(dst + ((r * 1024 + n * 2) ^ ((r & 7) << 4))) = (_Float16)v;
      }
    }
  __syncthreads();
}

// -------- fused FC on UPPER-TRI cells only: gather-max -> LN -> fc1 -> LN -> fc2 -> LN -> fc3 --------
__global__ __launch_bounds__(512, 2) void k_fc(
    const _Float16* __restrict__ h3, const int* __restrict__ row_ptr,
    const int* __restrict__ tri2ij,
    const int* __restrict__ dist, const float* __restrict__ dist_tab,
    const float* __restrict__ g1, const float* __restrict__ be1,
    const _Float16* __restrict__ wf1t, const float* __restrict__ bf1,
    const float* __restrict__ g2, const float* __restrict__ be2,
    const _Float16* __restrict__ wf2t, const float* __restrict__ bf2,
    const float* __restrict__ g3, const float* __restrict__ be3,
    const _Float16* __restrict__ wf3t, const float* __restrict__ bf3,
    float* __restrict__ x3c) {
  __shared__ __align__(16) char bufA[65536];  // [64][512] f16, rowB 1024
  __shared__ float st1[512], st2[512];
  __shared__ float stM[64], stR[64];

  const int tid = threadIdx.x;
  const int p0 = blockIdx.x * 64;             // compact row base

  // ---- phase 1: wave-per-row gather (lane = col slice, coalesced 1KB/edge) ----
  {
    const int w = tid >> 6, lane = tid & 63;
    const int coff = lane * 8;
    const float* gp = g1 + coff;
    const float* bp = be1 + coff;
    const _Float16 NEGH = (_Float16)(-65504.f);
    for (int rr = 0; rr < 8; ++rr) {
      int rloc = w * 8 + rr;
      int p = p0 + rloc;
      int b = p / TRIN;
      int ij = tri2ij[p - b * TRIN];
      int gr = (b * Nn + (ij >> 16)) * Nn + (ij & 0xffff);
      int s = row_ptr[gr], en = row_ptr[gr + 1];
      int di = dist[gr];
      half8 mx;
#pragma unroll
      for (int q = 0; q < 8; ++q) mx[q] = NEGH;
      int idx = s;
      while (idx + 4 <= en) {   // uniform across wave (same s/en) -> no divergence
        half8 c0 = *(const half8*)(h3 + (size_t)(idx + 0) * 512 + coff);
        half8 c1 = *(const half8*)(h3 + (size_t)(idx + 1) * 512 + coff);
        half8 c2 = *(const half8*)(h3 + (size_t)(idx + 2) * 512 + coff);
        half8 c3 = *(const half8*)(h3 + (size_t)(idx + 3) * 512 + coff);
        mx = __builtin_elementwise_max(mx, __builtin_elementwise_max(
                 __builtin_elementwise_max(c0, c1), __builtin_elementwise_max(c2, c3)));
        idx += 4;
      }
      if (idx + 2 <= en) {
        half8 c0 = *(const half8*)(h3 + (size_t)(idx + 0) * 512 + coff);
        half8 c1 = *(const half8*)(h3 + (size_t)(idx + 1) * 512 + coff);
        mx = __builtin_elementwise_max(mx, __builtin_elementwise_max(c0, c1));
        idx += 2;
      }
      if (idx < en) {
        half8 c0 = *(const half8*)(h3 + (size_t)idx * 512 + coff);
        mx = __builtin_elementwise_max(mx, c0);
      }
      const float* dt = dist_tab + (size_t)di * 512 + coff;
      float v[8]; float s1 = 0.f, s2 = 0.f;
#pragma unroll
      for (int q = 0; q < 8; ++q) {
        float vv = (s == en) ? 0.f : (float)mx[q];
        if (di) vv += dt[q];
        vv = fmaxf(vv, 0.f);
        v[q] = vv; s1 += vv; s2 += vv * vv;
      }
#pragma unroll
      for (int o = 32; o > 0; o >>= 1) { s1 += __shfl_xor(s1, o); s2 += __shfl_xor(s2, o); }
      float mean = s1 * (1.f / 512.f);
      float rs = rsqrtf(s2 * (1.f / 512.f) - mean * mean + 1e-5f);
      half8 ov;
#pragma unroll
      for (int q = 0; q < 8; ++q) ov[q] = (_Float16)((v[q] - mean) * rs * gp[q] + bp[q]);
      *(half8*)(bufA + ((rloc * 1024 + coff * 2) ^ ((rloc & 7) << 4))) = ov;
    }
  }
  __syncthreads();

  {  // fc1: bufA @ wf1 -> LN2 -> bufA (in-place)
    f32x4 acc[4][4];
    init_accn<4, 4>(bf1, 0, acc, tid);
    do_slice<4, 512, 0, 16, 512, 4>(wf1t, bufA, 0, acc, tid);
    epi_ln_store(acc, bufA, st1, st2, stM, stR, g2, be2, tid);
  }
  {  // fc2: bufA @ wf2 -> LN3 -> bufA (in-place)
    f32x4 acc[4][4];
    init_accn<4, 4>(bf2, 0, acc, tid);
    do_slice<4, 512, 0, 16, 512, 4>(wf2t, bufA, 0, acc, tid);
    epi_ln_store(acc, bufA, st1, st2, stM, stR, g3, be3, tid);
  }
  {  // fc3: bufA @ wf3 [64x512]@[512x16], 4-wave M-split, direct store (compact)
    const int w = tid >> 6, lane = tid & 63, ln15 = lane & 15, kg = lane >> 4;
    if (w < 4) {
      f32x4 acc3 = {0.f, 0.f, 0.f, 0.f};
#pragma unroll
      for (int c = 0; c < 16; ++c) {
        half8 b = *(const half8*)((const char*)wf3t + ln15 * 1024 + c * 64 + kg * 16);
        int row = w * 16 + ln15;
        half8 a = *(const half8*)(bufA + ((row * 1024 + c * 64 + kg * 16) ^ ((row & 7) << 4)));
        acc3 = __builtin_amdgcn_mfma_f32_16x16x32_f16(a, b, acc3, 0, 0, 0);
      }
#pragma unroll
      for (int j = 0; j < 4; ++j)
        x3c[(size_t)(p0 + w * 16 + kg * 4 + j) * 16 + ln15] = acc3[j] + bf3[ln15];
    }
  }
}

// ---------------- symmetrize from compact upper-tri x3c ----------------
__global__ void k_sym(const float* __restrict__ x3c, float* __restrict__ out) {
  int t = blockIdx.x * 256 + threadIdx.x;
  if (t >= SEGN * 4) return;
  int q = t & 3;
  int cell = t >> 2;
  int j = cell % Nn;
  int tmp = cell / Nn;
  int i = tmp % Nn;
  int b = tmp / Nn;
  int lo = min(i, j), hi = i ^ j ^ lo;
  int p = b * TRIN + tri_base(lo) + (hi - lo);
  float4 v = *(const float4*)&x3c[(size_t)p * 16 + q * 4];
  if (i == j) { v.x *= 2.f; v.y *= 2.f; v.z *= 2.f; v.w *= 2.f; }
  *(float4*)&out[(size_t)t * 4] = v;
}

extern "C" void kernel_launch(void* const* d_in, const int* in_sizes, int n_in,
                              void* d_out, int out_size, void* d_ws, size_t ws_size,
                              hipStream_t stream) {
  const int*   rel_type  = (const int*)d_in[0];
  const float* rel_error = (const float*)d_in[1];
  const int*   edge_pos  = (const int*)d_in[2];
  const int*   dist      = (const int*)d_in[3];
  const int*   rel_row   = (const int*)d_in[4];
  const float* type_tab = (const float*)d_in[8];
  const float* pos_tab  = (const float*)d_in[9];
  const float* dist_tab = (const float*)d_in[10];
  const float* w1 = (const float*)d_in[11]; const float* b1 = (const float*)d_in[12];
  const float* w2 = (const float*)d_in[13]; const float* b2 = (const float*)d_in[14];
  const float* w3 = (const float*)d_in[15]; const float* b3 = (const float*)d_in[16];
  const float* g1 = (const float*)d_in[17]; const float* be1 = (const float*)d_in[18];
  const float* wf1 = (const float*)d_in[19]; const float* bf1 = (const float*)d_in[20];
  const float* g2 = (const float*)d_in[21]; const float* be2 = (const float*)d_in[22];
  const float* wf2 = (const float*)d_in[23]; const float* bf2 = (const float*)d_in[24];
  const float* g3 = (const float*)d_in[25]; const float* be3 = (const float*)d_in[26];
  const float* wf3 = (const float*)d_in[27]; const float* bf3 = (const float*)d_in[28];

  const int E = in_sizes[0];
  const size_t h3_bytes  = (size_t)E * 512 * 2;        // 204.8 MB (f16)
  const size_t x3_bytes  = (size_t)CMPN * 16 * 4;      // 3.3 MB (compact)
  const size_t ptr_bytes = (size_t)(SEGN + 1) * 4;     // 410 KB
  const size_t tri_bytes = (size_t)TRIN * 4;           // 51.5 KB
  const size_t wt_elems  = 32768 + 131072 + 262144 * 3 + 8192;
  if (ws_size < h3_bytes + x3_bytes + ptr_bytes + tri_bytes + wt_elems * 2) return;

  _Float16* h3      = (_Float16*)d_ws;
  float*    x3c     = (float*)((char*)d_ws + h3_bytes);
  int*      row_ptr = (int*)((char*)d_ws + h3_bytes + x3_bytes);
  int*      tri2ij  = (int*)((char*)d_ws + h3_bytes + x3_bytes + ptr_bytes);
  _Float16* w1t     = (_Float16*)((char*)d_ws + h3_bytes + x3_bytes + ptr_bytes + tri_bytes);
  _Float16* w2t  = w1t + 32768;
  _Float16* w3t  = w2t + 131072;
  _Float16* wf1t = w3t + 262144;
  _Float16* wf2t = wf1t + 262144;
  _Float16* wf3t = wf2t + 262144;
  float*    out  = (float*)d_out;

  k_prep<<<3744, 256, 0, stream>>>(w1, w2, w3, wf1, wf2, wf3,
                                   w1t, w2t, w3t, wf1t, wf2t, wf3t);
  k_ptr<<<(SEGN + 256) / 256, 256, 0, stream>>>(rel_row, row_ptr, tri2ij, E);
  k_edge<<<(E + 63) / 64, 512, 0, stream>>>(rel_type, rel_error, edge_pos, rel_row,
                                            type_tab, pos_tab, w1t, b1, w2t, b2, w3t, b3,
                                            h3, E);
  k_fc<<<CMPN / 64, 512, 0, stream>>>(h3, row_ptr, tri2ij, dist, dist_tab,
                                      g1, be1, wf1t, bf1,
                                      g2, be2, wf2t, bf2,
                                      g3, be3, wf3t, bf3, x3c);
  k_sym<<<(SEGN * 4 + 255) / 256, 256, 0, stream>>>(x3c, out);
}

// Round 14
// 391.691 us; speedup vs baseline: 2.0656x; 1.2924x over previous
//
#include <hip/hip_runtime.h>

typedef __attribute__((ext_vector_type(8))) _Float16 half8;
typedef __attribute__((ext_vector_type(4))) _Float16 half4;
typedef __attribute__((ext_vector_type(4))) float f32x4;

constexpr int Bn = 4;
constexpr int Nn = 160;
constexpr int SEGN = Bn * Nn * Nn;        // 102400 segments
constexpr int TRIN = Nn * (Nn + 1) / 2;   // 12880 upper-tri cells per batch
constexpr int CMPN = Bn * TRIN;           // 51520 compact rows (= 805 * 64)
constexpr int SCAN_NB = (SEGN + 511) / 512; // 200 scan blocks

__device__ __forceinline__ int tri_base(int i) { return i * Nn - (i * (i - 1)) / 2; }

// ------- weight prepass: f32 [K][N] -> f16 chunk-blocked [k/32][N][32] -------
__global__ void k_prep(const float* __restrict__ w1, const float* __restrict__ w2,
                       const float* __restrict__ w3, const float* __restrict__ wf1,
                       const float* __restrict__ wf2, const float* __restrict__ wf3,
                       _Float16* __restrict__ o1, _Float16* __restrict__ o2,
                       _Float16* __restrict__ o3, _Float16* __restrict__ of1,
                       _Float16* __restrict__ of2, _Float16* __restrict__ of3) {
  int t = blockIdx.x * 256 + threadIdx.x;
  const float* src; _Float16* dst; int N, local; bool is3 = false;
  if (t < 32768)       { src = w1;  dst = o1;  N = 256; local = t; }
  else if (t < 163840) { src = w2;  dst = o2;  N = 512; local = t - 32768; }
  else if (t < 425984) { src = w3;  dst = o3;  N = 512; local = t - 163840; }
  else if (t < 688128) { src = wf1; dst = of1; N = 512; local = t - 425984; }
  else if (t < 950272) { src = wf2; dst = of2; N = 512; local = t - 688128; }
  else if (t < 958464) { src = wf3; dst = of3; N = 16;  local = t - 950272; is3 = true; }
  else return;
  int k = local / N;
  int n = local - k * N;
  if (is3) dst[n * 512 + k] = (_Float16)src[local];
  else dst[(size_t)((k >> 5) * N + n) * 32 + (k & 31)] = (_Float16)src[local];
}

__device__ __forceinline__ int lower_bound_rr(const int* __restrict__ rel_row, int E, int key) {
  int lo = 0, hi = E;
  while (lo < hi) { int mid = (lo + hi) >> 1; if (rel_row[mid] < key) lo = mid + 1; else hi = mid; }
  return lo;
}

// ------- CSR row pointers + per-cell kept-edge count + tri2ij lookup -------
__global__ void k_cnt(const int* __restrict__ rel_row, int* __restrict__ row_ptr,
                      int* __restrict__ cnt, int* __restrict__ tri2ij, int E) {
  int r = blockIdx.x * 256 + threadIdx.x;
  if (r < TRIN) {
    int lo = 0, hi = Nn - 1;
    while (lo < hi) { int mid = (lo + hi + 1) >> 1; if (tri_base(mid) <= r) lo = mid; else hi = mid - 1; }
    int j = lo + (r - tri_base(lo));
    tri2ij[r] = (lo << 16) | j;
  }
  if (r > SEGN) return;
  int lo = lower_bound_rr(rel_row, E, r);
  row_ptr[r] = lo;
  if (r < SEGN) {
    int hi2 = lower_bound_rr(rel_row, E, r + 1);
    int jj = r % Nn;
    int ii = (r / Nn) % Nn;
    cnt[r] = (ii <= jj) ? (hi2 - lo) : 0;
  }
}

// ------- scan pass 1: per-512-block exclusive prefix + block sums -------
__global__ void k_scan1(const int* __restrict__ cnt, int* __restrict__ pre,
                        int* __restrict__ bsum) {
  __shared__ int tmp[512];
  int t = threadIdx.x, b = blockIdx.x;
  int idx = b * 512 + t;
  int v = (idx < SEGN) ? cnt[idx] : 0;
  tmp[t] = v;
  __syncthreads();
  for (int o = 1; o < 512; o <<= 1) {
    int add = (t >= o) ? tmp[t - o] : 0;
    __syncthreads();
    tmp[t] += add;
    __syncthreads();
  }
  if (idx < SEGN) pre[idx] = tmp[t] - v;
  if (t == 511) bsum[b] = tmp[511];
}

// ------- scan pass 2: scan the 200 block sums (1 block), emit EK -------
__global__ void k_scan2(int* __restrict__ bsum, int* __restrict__ ek) {
  __shared__ int tmp[256];
  int t = threadIdx.x;
  int v = (t < SCAN_NB) ? bsum[t] : 0;
  tmp[t] = v;
  __syncthreads();
  for (int o = 1; o < 256; o <<= 1) {
    int add = (t >= o) ? tmp[t - o] : 0;
    __syncthreads();
    tmp[t] += add;
    __syncthreads();
  }
  if (t < SCAN_NB) bsum[t] = tmp[t] - v;
  if (t == 255) ek[0] = tmp[255];
}

// ------- build cstart[cell] and edge_map[compact] -> original edge -------
__global__ void k_map(const int* __restrict__ row_ptr, const int* __restrict__ cnt,
                      const int* __restrict__ pre, const int* __restrict__ bsum,
                      int* __restrict__ cstart, int* __restrict__ edge_map) {
  int r = blockIdx.x * 512 + threadIdx.x;
  if (r >= SEGN) return;
  int cs = pre[r] + bsum[r >> 9];
  cstart[r] = cs;
  int c = cnt[r];
  int rp = row_ptr[r];
  for (int k = 0; k < c; ++k) edge_map[cs + k] = rp + k;
}

// ---------------- MFMA slice, B direct from global (L2-resident) ----------------
template <int MT, int K, int C0, int CN, int NSTRIDE, int NT>
__device__ __forceinline__ void do_slice(const _Float16* __restrict__ wt,
                                         const char* a_base, int nbase,
                                         f32x4 (&acc)[MT][NT], int tid) {
  constexpr int rowB = K * 2;
  const int w = tid >> 6, lane = tid & 63, ln15 = lane & 15, kg = lane >> 4;
  const char* wb = (const char*)wt;
#pragma unroll
  for (int c = 0; c < CN; ++c) {
    half8 a[MT], b[NT];
#pragma unroll
    for (int nt = 0; nt < NT; ++nt) {
      int n = nbase + (w * NT + nt) * 16 + ln15;
      b[nt] = *(const half8*)(wb + (size_t)(C0 + c) * (NSTRIDE * 64) + n * 64 + kg * 16);
    }
#pragma unroll
    for (int mt = 0; mt < MT; ++mt) {
      int row = mt * 16 + ln15;
      int byte = (row * rowB + c * 64 + kg * 16) ^ ((row & 7) << 4);
      a[mt] = *(const half8*)(a_base + byte);
    }
#pragma unroll
    for (int mt = 0; mt < MT; ++mt)
#pragma unroll
      for (int nt = 0; nt < NT; ++nt)
        acc[mt][nt] = __builtin_amdgcn_mfma_f32_16x16x32_f16(a[mt], b[nt], acc[mt][nt], 0, 0, 0);
  }
}

template <int MT, int NT>
__device__ __forceinline__ void init_accn(const float* __restrict__ bias, int nbase,
                                          f32x4 (&acc)[MT][NT], int tid) {
  const int w = tid >> 6, ln15 = tid & 15;
#pragma unroll
  for (int nt = 0; nt < NT; ++nt) {
    float bv = bias[nbase + (w * NT + nt) * 16 + ln15];
    f32x4 s = {bv, bv, bv, bv};
#pragma unroll
    for (int mt = 0; mt < MT; ++mt) acc[mt][nt] = s;
  }
}

// C layout: col = lane&15, row = (lane>>4)*4 + j  [m89 verified]
template <int MT, int NT, bool RELU>
__device__ __forceinline__ void store_hn(char* h, int rowB, int nbase,
                                         const f32x4 (&acc)[MT][NT], int tid) {
  const int w = tid >> 6, lane = tid & 63, ln15 = lane & 15, kg = lane >> 4;
#pragma unroll
  for (int mt = 0; mt < MT; ++mt)
#pragma unroll
    for (int nt = 0; nt < NT; ++nt)
#pragma unroll
      for (int j = 0; j < 4; ++j) {
        int row = mt * 16 + kg * 4 + j;
        int n = nbase + (w * NT + nt) * 16 + ln15;
        float v = acc[mt][nt][j];
        if (RELU) v = fmaxf(v, 0.f);
        *(_Float16*)(h + ((row * rowB + n * 2) ^ ((row & 7) << 4))) = (_Float16)v;
      }
}

// -------- fused edge MLP (MFMA) over COMPACTED kept edges -> compact h3 --------
__global__ __launch_bounds__(512) void k_edge(
    const int* __restrict__ rel_type, const float* __restrict__ rel_error,
    const int* __restrict__ edge_pos, const int* __restrict__ edge_map,
    const int* __restrict__ ekp,
    const float* __restrict__ type_tab, const float* __restrict__ pos_tab,
    const _Float16* __restrict__ w1t, const float* __restrict__ b1,
    const _Float16* __restrict__ w2t, const float* __restrict__ b2,
    const _Float16* __restrict__ w3t, const float* __restrict__ b3,
    _Float16* __restrict__ h3) {
  __shared__ __align__(16) char smem[98304];
  char* h1 = smem;            // [64][256] f16, rowB 512
  char* h2 = smem + 32768;    // [64][512] f16, rowB 1024
  char* e  = smem + 32768;    // [64][128] f16, rowB 256 (dead before h2 written)

  const int tid = threadIdx.x;
  const int e0 = blockIdx.x * 64;
  const int EK = ekp[0];
  if (e0 >= EK) return;

  // ---- build e tile (compact slot -> original edge via edge_map) ----
  {
    int r = tid >> 3, c0 = (tid & 7) * 16;
    int re = edge_map[min(e0 + r, EK - 1)];
    int rt = rel_type[re];
    int ep = edge_pos[re];
#pragma unroll
    for (int s = 0; s < 2; ++s) {
      half8 hv;
#pragma unroll
      for (int q = 0; q < 8; ++q) {
        int cc = c0 + s * 8 + q;
        float v = (cc < 120) ? (rt ? type_tab[rt * 120 + cc] : 0.f)
                             : rel_error[(size_t)re * 8 + (cc - 120)];
        v += pos_tab[ep * 128 + cc];
        hv[q] = (_Float16)v;
      }
      int byte = (r * 256 + (c0 + s * 8) * 2) ^ ((r & 7) << 4);
      *(half8*)(e + byte) = hv;
    }
  }
  __syncthreads();

  {  // layer 1: [64x128]@[128x256] + relu -> h1
    f32x4 acc[4][2];
    init_accn<4, 2>(b1, 0, acc, tid);
    do_slice<4, 128, 0, 4, 256, 2>(w1t, e, 0, acc, tid);
    store_hn<4, 2, true>(h1, 512, 0, acc, tid);
  }
  __syncthreads();
  {  // layer 2: [64x256]@[256x512] + relu -> h2
    f32x4 acc[4][4];
    init_accn<4, 4>(b2, 0, acc, tid);
    do_slice<4, 256, 0, 8, 512, 4>(w2t, h1, 0, acc, tid);
    store_hn<4, 4, true>(h2, 1024, 0, acc, tid);
  }
  __syncthreads();
  {  // layer 3: [64x512]@[512x512] -> h2 (LDS) -> coalesced compact f16 stream
    f32x4 acc[4][4];
    init_accn<4, 4>(b3, 0, acc, tid);
    do_slice<4, 512, 0, 16, 512, 4>(w3t, h2, 0, acc, tid);
    __syncthreads();                       // all h2 reads complete
    store_hn<4, 4, false>(h2, 1024, 0, acc, tid);
    __syncthreads();
    uint4* dst = (uint4*)(h3 + (size_t)e0 * 512);
#pragma unroll
    for (int i = 0; i < 8; ++i) {
      int cidx = tid + i * 512;            // 16B chunk index, 4096 total
      int byteoff = cidx * 16;
      int row = byteoff >> 10;
      uint4 v = *(const uint4*)(h2 + (byteoff ^ ((row & 7) << 4)));
      if (e0 + row < EK) dst[cidx] = v;
    }
  }
}

// ---- in-register epilogue: relu -> LN (shfl + 2-stage LDS) -> store f16 ----
__device__ __forceinline__ void epi_ln_store(f32x4 (&acc)[4][4], char* dst,
                                             float* st1, float* st2,
                                             float* stM, float* stR,
                                             const float* __restrict__ g,
                                             const float* __restrict__ be, int tid) {
  const int w = tid >> 6, lane = tid & 63, ln15 = lane & 15, kg = lane >> 4;
#pragma unroll
  for (int mt = 0; mt < 4; ++mt)
#pragma unroll
    for (int nt = 0; nt < 4; ++nt)
#pragma unroll
      for (int j = 0; j < 4; ++j) acc[mt][nt][j] = fmaxf(acc[mt][nt][j], 0.f);
#pragma unroll
  for (int mt = 0; mt < 4; ++mt)
#pragma unroll
    for (int j = 0; j < 4; ++j) {
      float a = 0.f, b = 0.f;
#pragma unroll
      for (int nt = 0; nt < 4; ++nt) { float v = acc[mt][nt][j]; a += v; b += v * v; }
#pragma unroll
      for (int m = 1; m < 16; m <<= 1) { a += __shfl_xor(a, m); b += __shfl_xor(b, m); }
      if (ln15 == 0) {
        int r = mt * 16 + kg * 4 + j;
        st1[w * 64 + r] = a;
        st2[w * 64 + r] = b;
      }
    }
  __syncthreads();
  if (tid < 64) {
    float a = 0.f, b = 0.f;
#pragma unroll
    for (int ww = 0; ww < 8; ++ww) { a += st1[ww * 64 + tid]; b += st2[ww * 64 + tid]; }
    float mean = a * (1.f / 512.f);
    float var = b * (1.f / 512.f) - mean * mean;
    stM[tid] = mean;
    stR[tid] = rsqrtf(var + 1e-5f);
  }
  __syncthreads();
  float gv[4], bv[4];
#pragma unroll
  for (int nt = 0; nt < 4; ++nt) {
    int n = (w * 4 + nt) * 16 + ln15;
    gv[nt] = g[n]; bv[nt] = be[n];
  }
#pragma unroll
  for (int mt = 0; mt < 4; ++mt)
#pragma unroll
    for (int j = 0; j < 4; ++j) {
      int r = mt * 16 + kg * 4 + j;
      float mean = stM[r], rs = stR[r];
#pragma unroll
      for (int nt = 0; nt < 4; ++nt) {
        int n = (w * 4 + nt) * 16 + ln15;
        float v = (acc[mt][nt][j] - mean) * rs * gv[nt] + bv[nt];
        *(_Float16*)(dst + ((r * 1024 + n * 2) ^ ((r & 7) << 4))) = (_Float16)v;
      }
    }
  __syncthreads();
}

// -------- fused FC on UPPER-TRI cells: gather-max(compact h3) -> LN -> fc1/2/3 --------
__global__ __launch_bounds__(512, 2) void k_fc(
    const _Float16* __restrict__ h3, const int* __restrict__ cstart,
    const int* __restrict__ cnt, const int* __restrict__ tri2ij,
    const int* __restrict__ dist, const float* __restrict__ dist_tab,
    const float* __restrict__ g1, const float* __restrict__ be1,
    const _Float16* __restrict__ wf1t, const float* __restrict__ bf1,
    const float* __restrict__ g2, const float* __restrict__ be2,
    const _Float16* __restrict__ wf2t, const float* __restrict__ bf2,
    const float* __restrict__ g3, const float* __restrict__ be3,
    const _Float16* __restrict__ wf3t, const float* __restrict__ bf3,
    float* __restrict__ x3c) {
  __shared__ __align__(16) char bufA[65536];  // [64][512] f16, rowB 1024
  __shared__ float st1[512], st2[512];
  __shared__ float stM[64], stR[64];

  const int tid = threadIdx.x;
  const int p0 = blockIdx.x * 64;             // compact row base

  // ---- phase 1: wave-per-row gather (lane = col slice, coalesced 1KB/edge) ----
  {
    const int w = tid >> 6, lane = tid & 63;
    const int coff = lane * 8;
    const float* gp = g1 + coff;
    const float* bp = be1 + coff;
    const _Float16 NEGH = (_Float16)(-65504.f);
    for (int rr = 0; rr < 8; ++rr) {
      int rloc = w * 8 + rr;
      int p = p0 + rloc;
      int b = p / TRIN;
      int ij = tri2ij[p - b * TRIN];
      int gr = (b * Nn + (ij >> 16)) * Nn + (ij & 0xffff);
      int s = cstart[gr], en = s + cnt[gr];
      int di = dist[gr];
      half8 mx;
#pragma unroll
      for (int q = 0; q < 8; ++q) mx[q] = NEGH;
      int idx = s;
      while (idx + 4 <= en) {
        half8 c0 = *(const half8*)(h3 + (size_t)(idx + 0) * 512 + coff);
        half8 c1 = *(const half8*)(h3 + (size_t)(idx + 1) * 512 + coff);
        half8 c2 = *(const half8*)(h3 + (size_t)(idx + 2) * 512 + coff);
        half8 c3 = *(const half8*)(h3 + (size_t)(idx + 3) * 512 + coff);
        mx = __builtin_elementwise_max(mx, __builtin_elementwise_max(
                 __builtin_elementwise_max(c0, c1), __builtin_elementwise_max(c2, c3)));
        idx += 4;
      }
      if (idx + 2 <= en) {
        half8 c0 = *(const half8*)(h3 + (size_t)(idx + 0) * 512 + coff);
        half8 c1 = *(const half8*)(h3 + (size_t)(idx + 1) * 512 + coff);
        mx = __builtin_elementwise_max(mx, __builtin_elementwise_max(c0, c1));
        idx += 2;
      }
      if (idx < en) {
        half8 c0 = *(const half8*)(h3 + (size_t)idx * 512 + coff);
        mx = __builtin_elementwise_max(mx, c0);
      }
      const float* dt = dist_tab + (size_t)di * 512 + coff;
      float v[8]; float s1 = 0.f, s2 = 0.f;
#pragma unroll
      for (int q = 0; q < 8; ++q) {
        float vv = (s == en) ? 0.f : (float)mx[q];
        if (di) vv += dt[q];
        vv = fmaxf(vv, 0.f);
        v[q] = vv; s1 += vv; s2 += vv * vv;
      }
#pragma unroll
      for (int o = 32; o > 0; o >>= 1) { s1 += __shfl_xor(s1, o); s2 += __shfl_xor(s2, o); }
      float mean = s1 * (1.f / 512.f);
      float rs = rsqrtf(s2 * (1.f / 512.f) - mean * mean + 1e-5f);
      half8 ov;
#pragma unroll
      for (int q = 0; q < 8; ++q) ov[q] = (_Float16)((v[q] - mean) * rs * gp[q] + bp[q]);
      *(half8*)(bufA + ((rloc * 1024 + coff * 2) ^ ((rloc & 7) << 4))) = ov;
    }
  }
  __syncthreads();

  {  // fc1: bufA @ wf1 -> LN2 -> bufA (in-place)
    f32x4 acc[4][4];
    init_accn<4, 4>(bf1, 0, acc, tid);
    do_slice<4, 512, 0, 16, 512, 4>(wf1t, bufA, 0, acc, tid);
    epi_ln_store(acc, bufA, st1, st2, stM, stR, g2, be2, tid);
  }
  {  // fc2: bufA @ wf2 -> LN3 -> bufA (in-place)
    f32x4 acc[4][4];
    init_accn<4, 4>(bf2, 0, acc, tid);
    do_slice<4, 512, 0, 16, 512, 4>(wf2t, bufA, 0, acc, tid);
    epi_ln_store(acc, bufA, st1, st2, stM, stR, g3, be3, tid);
  }
  {  // fc3: bufA @ wf3 [64x512]@[512x16], 4-wave M-split, direct store (compact)
    const int w = tid >> 6, lane = tid & 63, ln15 = lane & 15, kg = lane >> 4;
    if (w < 4) {
      f32x4 acc3 = {0.f, 0.f, 0.f, 0.f};
#pragma unroll
      for (int c = 0; c < 16; ++c) {
        half8 b = *(const half8*)((const char*)wf3t + ln15 * 1024 + c * 64 + kg * 16);
        int row = w * 16 + ln15;
        half8 a = *(const half8*)(bufA + ((row * 1024 + c * 64 + kg * 16) ^ ((row & 7) << 4)));
        acc3 = __builtin_amdgcn_mfma_f32_16x16x32_f16(a, b, acc3, 0, 0, 0);
      }
#pragma unroll
      for (int j = 0; j < 4; ++j)
        x3c[(size_t)(p0 + w * 16 + kg * 4 + j) * 16 + ln15] = acc3[j] + bf3[ln15];
    }
  }
}

// ---------------- symmetrize from compact upper-tri x3c ----------------
__global__ void k_sym(const float* __restrict__ x3c, float* __restrict__ out) {
  int t = blockIdx.x * 256 + threadIdx.x;
  if (t >= SEGN * 4) return;
  int q = t & 3;
  int cell = t >> 2;
  int j = cell % Nn;
  int tmp = cell / Nn;
  int i = tmp % Nn;
  int b = tmp / Nn;
  int lo = min(i, j), hi = i ^ j ^ lo;
  int p = b * TRIN + tri_base(lo) + (hi - lo);
  float4 v = *(const float4*)&x3c[(size_t)p * 16 + q * 4];
  if (i == j) { v.x *= 2.f; v.y *= 2.f; v.z *= 2.f; v.w *= 2.f; }
  *(float4*)&out[(size_t)t * 4] = v;
}

extern "C" void kernel_launch(void* const* d_in, const int* in_sizes, int n_in,
                              void* d_out, int out_size, void* d_ws, size_t ws_size,
                              hipStream_t stream) {
  const int*   rel_type  = (const int*)d_in[0];
  const float* rel_error = (const float*)d_in[1];
  const int*   edge_pos  = (const int*)d_in[2];
  const int*   dist      = (const int*)d_in[3];
  const int*   rel_row   = (const int*)d_in[4];
  const float* type_tab = (const float*)d_in[8];
  const float* pos_tab  = (const float*)d_in[9];
  const float* dist_tab = (const float*)d_in[10];
  const float* w1 = (const float*)d_in[11]; const float* b1 = (const float*)d_in[12];
  const float* w2 = (const float*)d_in[13]; const float* b2 = (const float*)d_in[14];
  const float* w3 = (const float*)d_in[15]; const float* b3 = (const float*)d_in[16];
  const float* g1 = (const float*)d_in[17]; const float* be1 = (const float*)d_in[18];
  const float* wf1 = (const float*)d_in[19]; const float* bf1 = (const float*)d_in[20];
  const float* g2 = (const float*)d_in[21]; const float* be2 = (const float*)d_in[22];
  const float* wf2 = (const float*)d_in[23]; const float* bf2 = (const float*)d_in[24];
  const float* g3 = (const float*)d_in[25]; const float* be3 = (const float*)d_in[26];
  const float* wf3 = (const float*)d_in[27]; const float* bf3 = (const float*)d_in[28];

  const int E = in_sizes[0];
  const size_t h3_bytes   = (size_t)E * 512 * 2;        // 204.8 MB (upper bound)
  const size_t x3_bytes   = (size_t)CMPN * 16 * 4;      // 3.3 MB
  const size_t ptr_bytes  = (size_t)(SEGN + 1) * 4;
  const size_t tri_bytes  = (size_t)TRIN * 4;
  const size_t cell_bytes = (size_t)SEGN * 4;           // cnt / pre / cstart each
  const size_t map_bytes  = (size_t)E * 4;
  const size_t wt_elems   = 32768 + 131072 + 262144 * 3 + 8192;
  const size_t total = h3_bytes + x3_bytes + ptr_bytes + tri_bytes + 3 * cell_bytes +
                       map_bytes + 1024 + 256 * 4 + wt_elems * 2;
  if (ws_size < total) return;

  char* wp = (char*)d_ws;
  _Float16* h3      = (_Float16*)wp;            wp += h3_bytes;
  float*    x3c     = (float*)wp;               wp += x3_bytes;
  int*      row_ptr = (int*)wp;                 wp += ptr_bytes;
  int*      tri2ij  = (int*)wp;                 wp += tri_bytes;
  int*      cnt     = (int*)wp;                 wp += cell_bytes;
  int*      pre     = (int*)wp;                 wp += cell_bytes;
  int*      cstart  = (int*)wp;                 wp += cell_bytes;
  int*      edge_map= (int*)wp;                 wp += map_bytes;
  int*      bsum    = (int*)wp;                 wp += 256 * 4;
  int*      ekp     = (int*)wp;                 wp += 1024;
  _Float16* w1t     = (_Float16*)wp;
  _Float16* w2t  = w1t + 32768;
  _Float16* w3t  = w2t + 131072;
  _Float16* wf1t = w3t + 262144;
  _Float16* wf2t = wf1t + 262144;
  _Float16* wf3t = wf2t + 262144;
  float*    out  = (float*)d_out;

  k_prep<<<3744, 256, 0, stream>>>(w1, w2, w3, wf1, wf2, wf3,
                                   w1t, w2t, w3t, wf1t, wf2t, wf3t);
  k_cnt<<<(SEGN + 256) / 256, 256, 0, stream>>>(rel_row, row_ptr, cnt, tri2ij, E);
  k_scan1<<<SCAN_NB, 512, 0, stream>>>(cnt, pre, bsum);
  k_scan2<<<1, 256, 0, stream>>>(bsum, ekp);
  k_map<<<SCAN_NB, 512, 0, stream>>>(row_ptr, cnt, pre, bsum, cstart, edge_map);
  k_edge<<<(E + 63) / 64, 512, 0, stream>>>(rel_type, rel_error, edge_pos, edge_map, ekp,
                                            type_tab, pos_tab, w1t, b1, w2t, b2, w3t, b3,
                                            h3);
  k_fc<<<CMPN / 64, 512, 0, stream>>>(h3, cstart, cnt, tri2ij, dist, dist_tab,
                                      g1, be1, wf1t, bf1,
                                      g2, be2, wf2t, bf2,
                                      g3, be3, wf3t, bf3, x3c);
  k_sym<<<(SEGN * 4 + 255) / 256, 256, 0, stream>>>(x3c, out);
}

// Round 15
// 389.255 us; speedup vs baseline: 2.0786x; 1.0063x over previous
//
#include <hip/hip_runtime.h>

typedef __attribute__((ext_vector_type(8))) _Float16 half8;
typedef __attribute__((ext_vector_type(4))) _Float16 half4;
typedef __attribute__((ext_vector_type(4))) float f32x4;

constexpr int Bn = 4;
constexpr int Nn = 160;
constexpr int SEGN = Bn * Nn * Nn;        // 102400 segments
constexpr int TRIN = Nn * (Nn + 1) / 2;   // 12880 upper-tri cells per batch
constexpr int CMPN = Bn * TRIN;           // 51520 compact rows (= 805 * 64)
constexpr int SCAN_NB = (SEGN + 511) / 512; // 200 scan blocks

__device__ __forceinline__ int tri_base(int i) { return i * Nn - (i * (i - 1)) / 2; }

// ------- weight prepass: f32 [K][N] -> f16 chunk-blocked [k/32][N][32] -------
__global__ void k_prep(const float* __restrict__ w1, const float* __restrict__ w2,
                       const float* __restrict__ w3, const float* __restrict__ wf1,
                       const float* __restrict__ wf2, const float* __restrict__ wf3,
                       _Float16* __restrict__ o1, _Float16* __restrict__ o2,
                       _Float16* __restrict__ o3, _Float16* __restrict__ of1,
                       _Float16* __restrict__ of2, _Float16* __restrict__ of3) {
  int t = blockIdx.x * 256 + threadIdx.x;
  const float* src; _Float16* dst; int N, local; bool is3 = false;
  if (t < 32768)       { src = w1;  dst = o1;  N = 256; local = t; }
  else if (t < 163840) { src = w2;  dst = o2;  N = 512; local = t - 32768; }
  else if (t < 425984) { src = w3;  dst = o3;  N = 512; local = t - 163840; }
  else if (t < 688128) { src = wf1; dst = of1; N = 512; local = t - 425984; }
  else if (t < 950272) { src = wf2; dst = of2; N = 512; local = t - 688128; }
  else if (t < 958464) { src = wf3; dst = of3; N = 16;  local = t - 950272; is3 = true; }
  else return;
  int k = local / N;
  int n = local - k * N;
  if (is3) dst[n * 512 + k] = (_Float16)src[local];
  else dst[(size_t)((k >> 5) * N + n) * 32 + (k & 31)] = (_Float16)src[local];
}

__device__ __forceinline__ int lower_bound_rr(const int* __restrict__ rel_row, int E, int key) {
  int lo = 0, hi = E;
  while (lo < hi) { int mid = (lo + hi) >> 1; if (rel_row[mid] < key) lo = mid + 1; else hi = mid; }
  return lo;
}

// ------- CSR row pointers + per-cell kept-edge count + tri2ij lookup -------
__global__ void k_cnt(const int* __restrict__ rel_row, int* __restrict__ row_ptr,
                      int* __restrict__ cnt, int* __restrict__ tri2ij, int E) {
  int r = blockIdx.x * 256 + threadIdx.x;
  if (r < TRIN) {
    int lo = 0, hi = Nn - 1;
    while (lo < hi) { int mid = (lo + hi + 1) >> 1; if (tri_base(mid) <= r) lo = mid; else hi = mid - 1; }
    int j = lo + (r - tri_base(lo));
    tri2ij[r] = (lo << 16) | j;
  }
  if (r > SEGN) return;
  int lo = lower_bound_rr(rel_row, E, r);
  row_ptr[r] = lo;
  if (r < SEGN) {
    int hi2 = lower_bound_rr(rel_row, E, r + 1);
    int jj = r % Nn;
    int ii = (r / Nn) % Nn;
    cnt[r] = (ii <= jj) ? (hi2 - lo) : 0;
  }
}

// ------- scan pass 1: per-512-block exclusive prefix + block sums -------
__global__ void k_scan1(const int* __restrict__ cnt, int* __restrict__ pre,
                        int* __restrict__ bsum) {
  __shared__ int tmp[512];
  int t = threadIdx.x, b = blockIdx.x;
  int idx = b * 512 + t;
  int v = (idx < SEGN) ? cnt[idx] : 0;
  tmp[t] = v;
  __syncthreads();
  for (int o = 1; o < 512; o <<= 1) {
    int add = (t >= o) ? tmp[t - o] : 0;
    __syncthreads();
    tmp[t] += add;
    __syncthreads();
  }
  if (idx < SEGN) pre[idx] = tmp[t] - v;
  if (t == 511) bsum[b] = tmp[511];
}

// ------- scan pass 2: scan the 200 block sums (1 block), emit EK -------
__global__ void k_scan2(int* __restrict__ bsum, int* __restrict__ ek) {
  __shared__ int tmp[256];
  int t = threadIdx.x;
  int v = (t < SCAN_NB) ? bsum[t] : 0;
  tmp[t] = v;
  __syncthreads();
  for (int o = 1; o < 256; o <<= 1) {
    int add = (t >= o) ? tmp[t - o] : 0;
    __syncthreads();
    tmp[t] += add;
    __syncthreads();
  }
  if (t < SCAN_NB) bsum[t] = tmp[t] - v;
  if (t == 255) ek[0] = tmp[255];
}

// ------- build cstart[cell] (SEGN+1 entries) and edge_map[compact] -------
__global__ void k_map(const int* __restrict__ row_ptr, const int* __restrict__ cnt,
                      const int* __restrict__ pre, const int* __restrict__ bsum,
                      int* __restrict__ cstart, int* __restrict__ edge_map) {
  int r = blockIdx.x * 512 + threadIdx.x;
  if (r >= SEGN) return;
  int cs = pre[r] + bsum[r >> 9];
  cstart[r] = cs;
  int c = cnt[r];
  int rp = row_ptr[r];
  for (int k = 0; k < c; ++k) edge_map[cs + k] = rp + k;
  if (r == SEGN - 1) cstart[SEGN] = cs + c;
}

// ---------------- MFMA slice, B direct from global (L2-resident) ----------------
// SP: wrap the MFMA burst in s_setprio(1)/(0)  [T5 — pays when waves have role diversity]
template <int MT, int K, int C0, int CN, int NSTRIDE, int NT, bool SP>
__device__ __forceinline__ void do_slice(const _Float16* __restrict__ wt,
                                         const char* a_base, int nbase,
                                         f32x4 (&acc)[MT][NT], int tid) {
  constexpr int rowB = K * 2;
  const int w = tid >> 6, lane = tid & 63, ln15 = lane & 15, kg = lane >> 4;
  const char* wb = (const char*)wt;
#pragma unroll
  for (int c = 0; c < CN; ++c) {
    half8 a[MT], b[NT];
#pragma unroll
    for (int nt = 0; nt < NT; ++nt) {
      int n = nbase + (w * NT + nt) * 16 + ln15;
      b[nt] = *(const half8*)(wb + (size_t)(C0 + c) * (NSTRIDE * 64) + n * 64 + kg * 16);
    }
#pragma unroll
    for (int mt = 0; mt < MT; ++mt) {
      int row = mt * 16 + ln15;
      int byte = (row * rowB + c * 64 + kg * 16) ^ ((row & 7) << 4);
      a[mt] = *(const half8*)(a_base + byte);
    }
    if (SP) __builtin_amdgcn_s_setprio(1);
#pragma unroll
    for (int mt = 0; mt < MT; ++mt)
#pragma unroll
      for (int nt = 0; nt < NT; ++nt)
        acc[mt][nt] = __builtin_amdgcn_mfma_f32_16x16x32_f16(a[mt], b[nt], acc[mt][nt], 0, 0, 0);
    if (SP) __builtin_amdgcn_s_setprio(0);
  }
}

template <int MT, int NT>
__device__ __forceinline__ void init_accn(const float* __restrict__ bias, int nbase,
                                          f32x4 (&acc)[MT][NT], int tid) {
  const int w = tid >> 6, ln15 = tid & 15;
#pragma unroll
  for (int nt = 0; nt < NT; ++nt) {
    float bv = bias[nbase + (w * NT + nt) * 16 + ln15];
    f32x4 s = {bv, bv, bv, bv};
#pragma unroll
    for (int mt = 0; mt < MT; ++mt) acc[mt][nt] = s;
  }
}

// C layout: col = lane&15, row = (lane>>4)*4 + j  [m89 verified]
template <int MT, int NT, bool RELU>
__device__ __forceinline__ void store_hn(char* h, int rowB, int nbase,
                                         const f32x4 (&acc)[MT][NT], int tid) {
  const int w = tid >> 6, lane = tid & 63, ln15 = lane & 15, kg = lane >> 4;
#pragma unroll
  for (int mt = 0; mt < MT; ++mt)
#pragma unroll
    for (int nt = 0; nt < NT; ++nt)
#pragma unroll
      for (int j = 0; j < 4; ++j) {
        int row = mt * 16 + kg * 4 + j;
        int n = nbase + (w * NT + nt) * 16 + ln15;
        float v = acc[mt][nt][j];
        if (RELU) v = fmaxf(v, 0.f);
        *(_Float16*)(h + ((row * rowB + n * 2) ^ ((row & 7) << 4))) = (_Float16)v;
      }
}

// -------- fused edge MLP (MFMA) over COMPACTED kept edges -> compact h3 --------
__global__ __launch_bounds__(512) void k_edge(
    const int* __restrict__ rel_type, const float* __restrict__ rel_error,
    const int* __restrict__ edge_pos, const int* __restrict__ edge_map,
    const int* __restrict__ ekp,
    const float* __restrict__ type_tab, const float* __restrict__ pos_tab,
    const _Float16* __restrict__ w1t, const float* __restrict__ b1,
    const _Float16* __restrict__ w2t, const float* __restrict__ b2,
    const _Float16* __restrict__ w3t, const float* __restrict__ b3,
    _Float16* __restrict__ h3) {
  __shared__ __align__(16) char smem[98304];
  char* h1 = smem;            // [64][256] f16, rowB 512
  char* h2 = smem + 32768;    // [64][512] f16, rowB 1024
  char* e  = smem + 32768;    // [64][128] f16, rowB 256 (dead before h2 written)

  const int tid = threadIdx.x;
  const int e0 = blockIdx.x * 64;
  const int EK = ekp[0];
  if (e0 >= EK) return;

  // ---- build e tile (compact slot -> original edge via edge_map) ----
  {
    int r = tid >> 3, c0 = (tid & 7) * 16;
    int re = edge_map[min(e0 + r, EK - 1)];
    int rt = rel_type[re];
    int ep = edge_pos[re];
#pragma unroll
    for (int s = 0; s < 2; ++s) {
      half8 hv;
#pragma unroll
      for (int q = 0; q < 8; ++q) {
        int cc = c0 + s * 8 + q;
        float v = (cc < 120) ? (rt ? type_tab[rt * 120 + cc] : 0.f)
                             : rel_error[(size_t)re * 8 + (cc - 120)];
        v += pos_tab[ep * 128 + cc];
        hv[q] = (_Float16)v;
      }
      int byte = (r * 256 + (c0 + s * 8) * 2) ^ ((r & 7) << 4);
      *(half8*)(e + byte) = hv;
    }
  }
  __syncthreads();

  {  // layer 1: [64x128]@[128x256] + relu -> h1
    f32x4 acc[4][2];
    init_accn<4, 2>(b1, 0, acc, tid);
    do_slice<4, 128, 0, 4, 256, 2, true>(w1t, e, 0, acc, tid);
    store_hn<4, 2, true>(h1, 512, 0, acc, tid);
  }
  __syncthreads();
  {  // layer 2: [64x256]@[256x512] + relu -> h2
    f32x4 acc[4][4];
    init_accn<4, 4>(b2, 0, acc, tid);
    do_slice<4, 256, 0, 8, 512, 4, true>(w2t, h1, 0, acc, tid);
    store_hn<4, 4, true>(h2, 1024, 0, acc, tid);
  }
  __syncthreads();
  {  // layer 3: [64x512]@[512x512] -> h2 (LDS) -> coalesced compact f16 stream
    f32x4 acc[4][4];
    init_accn<4, 4>(b3, 0, acc, tid);
    do_slice<4, 512, 0, 16, 512, 4, true>(w3t, h2, 0, acc, tid);
    __syncthreads();                       // all h2 reads complete
    store_hn<4, 4, false>(h2, 1024, 0, acc, tid);
    __syncthreads();
    uint4* dst = (uint4*)(h3 + (size_t)e0 * 512);
#pragma unroll
    for (int i = 0; i < 8; ++i) {
      int cidx = tid + i * 512;            // 16B chunk index, 4096 total
      int byteoff = cidx * 16;
      int row = byteoff >> 10;
      uint4 v = *(const uint4*)(h2 + (byteoff ^ ((row & 7) << 4)));
      if (e0 + row < EK) dst[cidx] = v;
    }
  }
}

// ---- in-register epilogue: relu -> LN (shfl + 2-stage LDS) -> store f16 ----
__device__ __forceinline__ void epi_ln_store(f32x4 (&acc)[4][4], char* dst,
                                             float* st1, float* st2,
                                             float* stM, float* stR,
                                             const float* __restrict__ g,
                                             const float* __restrict__ be, int tid) {
  const int w = tid >> 6, lane = tid & 63, ln15 = lane & 15, kg = lane >> 4;
#pragma unroll
  for (int mt = 0; mt < 4; ++mt)
#pragma unroll
    for (int nt = 0; nt < 4; ++nt)
#pragma unroll
      for (int j = 0; j < 4; ++j) acc[mt][nt][j] = fmaxf(acc[mt][nt][j], 0.f);
#pragma unroll
  for (int mt = 0; mt < 4; ++mt)
#pragma unroll
    for (int j = 0; j < 4; ++j) {
      float a = 0.f, b = 0.f;
#pragma unroll
      for (int nt = 0; nt < 4; ++nt) { float v = acc[mt][nt][j]; a += v; b += v * v; }
#pragma unroll
      for (int m = 1; m < 16; m <<= 1) { a += __shfl_xor(a, m); b += __shfl_xor(b, m); }
      if (ln15 == 0) {
        int r = mt * 16 + kg * 4 + j;
        st1[w * 64 + r] = a;
        st2[w * 64 + r] = b;
      }
    }
  __syncthreads();
  if (tid < 64) {
    float a = 0.f, b = 0.f;
#pragma unroll
    for (int ww = 0; ww < 8; ++ww) { a += st1[ww * 64 + tid]; b += st2[ww * 64 + tid]; }
    float mean = a * (1.f / 512.f);
    float var = b * (1.f / 512.f) - mean * mean;
    stM[tid] = mean;
    stR[tid] = rsqrtf(var + 1e-5f);
  }
  __syncthreads();
  float gv[4], bv[4];
#pragma unroll
  for (int nt = 0; nt < 4; ++nt) {
    int n = (w * 4 + nt) * 16 + ln15;
    gv[nt] = g[n]; bv[nt] = be[n];
  }
#pragma unroll
  for (int mt = 0; mt < 4; ++mt)
#pragma unroll
    for (int j = 0; j < 4; ++j) {
      int r = mt * 16 + kg * 4 + j;
      float mean = stM[r], rs = stR[r];
#pragma unroll
      for (int nt = 0; nt < 4; ++nt) {
        int n = (w * 4 + nt) * 16 + ln15;
        float v = (acc[mt][nt][j] - mean) * rs * gv[nt] + bv[nt];
        *(_Float16*)(dst + ((r * 1024 + n * 2) ^ ((r & 7) << 4))) = (_Float16)v;
      }
    }
  __syncthreads();
}

// -------- fused FC on UPPER-TRI cells: gather-max(compact h3) -> LN -> fc1/2/3 --------
__global__ __launch_bounds__(512, 2) void k_fc(
    const _Float16* __restrict__ h3, const int* __restrict__ cstart,
    const int* __restrict__ tri2ij,
    const int* __restrict__ dist, const float* __restrict__ dist_tab,
    const float* __restrict__ g1, const float* __restrict__ be1,
    const _Float16* __restrict__ wf1t, const float* __restrict__ bf1,
    const float* __restrict__ g2, const float* __restrict__ be2,
    const _Float16* __restrict__ wf2t, const float* __restrict__ bf2,
    const float* __restrict__ g3, const float* __restrict__ be3,
    const _Float16* __restrict__ wf3t, const float* __restrict__ bf3,
    float* __restrict__ x3c) {
  __shared__ __align__(16) char bufA[65536];  // [64][512] f16, rowB 1024
  __shared__ float st1[512], st2[512];
  __shared__ float stM[64], stR[64];

  const int tid = threadIdx.x;
  const int p0 = blockIdx.x * 64;             // compact row base

  // ---- phase 1: wave-per-row gather (lane = col slice, coalesced 1KB/edge) ----
  {
    const int w = tid >> 6, lane = tid & 63;
    const int coff = lane * 8;
    const float* gp = g1 + coff;
    const float* bp = be1 + coff;
    const _Float16 NEGH = (_Float16)(-65504.f);
    for (int rr = 0; rr < 8; ++rr) {
      int rloc = w * 8 + rr;
      int p = p0 + rloc;
      int b = p / TRIN;
      int ij = tri2ij[p - b * TRIN];
      int gr = (b * Nn + (ij >> 16)) * Nn + (ij & 0xffff);
      int s = cstart[gr], en = cstart[gr + 1];
      int di = dist[gr];
      half8 mx;
#pragma unroll
      for (int q = 0; q < 8; ++q) mx[q] = NEGH;
      int idx = s;
      while (idx + 4 <= en) {
        half8 c0 = *(const half8*)(h3 + (size_t)(idx + 0) * 512 + coff);
        half8 c1 = *(const half8*)(h3 + (size_t)(idx + 1) * 512 + coff);
        half8 c2 = *(const half8*)(h3 + (size_t)(idx + 2) * 512 + coff);
        half8 c3 = *(const half8*)(h3 + (size_t)(idx + 3) * 512 + coff);
        mx = __builtin_elementwise_max(mx, __builtin_elementwise_max(
                 __builtin_elementwise_max(c0, c1), __builtin_elementwise_max(c2, c3)));
        idx += 4;
      }
      if (idx + 2 <= en) {
        half8 c0 = *(const half8*)(h3 + (size_t)(idx + 0) * 512 + coff);
        half8 c1 = *(const half8*)(h3 + (size_t)(idx + 1) * 512 + coff);
        mx = __builtin_elementwise_max(mx, __builtin_elementwise_max(c0, c1));
        idx += 2;
      }
      if (idx < en) {
        half8 c0 = *(const half8*)(h3 + (size_t)idx * 512 + coff);
        mx = __builtin_elementwise_max(mx, c0);
      }
      const float* dt = dist_tab + (size_t)di * 512 + coff;
      float v[8]; float s1 = 0.f, s2 = 0.f;
#pragma unroll
      for (int q = 0; q < 8; ++q) {
        float vv = (s == en) ? 0.f : (float)mx[q];
        if (di) vv += dt[q];
        vv = fmaxf(vv, 0.f);
        v[q] = vv; s1 += vv; s2 += vv * vv;
      }
#pragma unroll
      for (int o = 32; o > 0; o >>= 1) { s1 += __shfl_xor(s1, o); s2 += __shfl_xor(s2, o); }
      float mean = s1 * (1.f / 512.f);
      float rs = rsqrtf(s2 * (1.f / 512.f) - mean * mean + 1e-5f);
      half8 ov;
#pragma unroll
      for (int q = 0; q < 8; ++q) ov[q] = (_Float16)((v[q] - mean) * rs * gp[q] + bp[q]);
      *(half8*)(bufA + ((rloc * 1024 + coff * 2) ^ ((rloc & 7) << 4))) = ov;
    }
  }
  __syncthreads();

  {  // fc1: bufA @ wf1 -> LN2 -> bufA (in-place)
    f32x4 acc[4][4];
    init_accn<4, 4>(bf1, 0, acc, tid);
    do_slice<4, 512, 0, 16, 512, 4, true>(wf1t, bufA, 0, acc, tid);
    epi_ln_store(acc, bufA, st1, st2, stM, stR, g2, be2, tid);
  }
  {  // fc2: bufA @ wf2 -> LN3 -> bufA (in-place)
    f32x4 acc[4][4];
    init_accn<4, 4>(bf2, 0, acc, tid);
    do_slice<4, 512, 0, 16, 512, 4, true>(wf2t, bufA, 0, acc, tid);
    epi_ln_store(acc, bufA, st1, st2, stM, stR, g3, be3, tid);
  }
  {  // fc3: bufA @ wf3 [64x512]@[512x16], 4-wave M-split, direct store (compact)
    const int w = tid >> 6, lane = tid & 63, ln15 = lane & 15, kg = lane >> 4;
    if (w < 4) {
      f32x4 acc3 = {0.f, 0.f, 0.f, 0.f};
#pragma unroll
      for (int c = 0; c < 16; ++c) {
        half8 b = *(const half8*)((const char*)wf3t + ln15 * 1024 + c * 64 + kg * 16);
        int row = w * 16 + ln15;
        half8 a = *(const half8*)(bufA + ((row * 1024 + c * 64 + kg * 16) ^ ((row & 7) << 4)));
        acc3 = __builtin_amdgcn_mfma_f32_16x16x32_f16(a, b, acc3, 0, 0, 0);
      }
#pragma unroll
      for (int j = 0; j < 4; ++j)
        x3c[(size_t)(p0 + w * 16 + kg * 4 + j) * 16 + ln15] = acc3[j] + bf3[ln15];
    }
  }
}

// ---------------- symmetrize from compact upper-tri x3c ----------------
__global__ void k_sym(const float* __restrict__ x3c, float* __restrict__ out) {
  int t = blockIdx.x * 256 + threadIdx.x;
  if (t >= SEGN * 4) return;
  int q = t & 3;
  int cell = t >> 2;
  int j = cell % Nn;
  int tmp = cell / Nn;
  int i = tmp % Nn;
  int b = tmp / Nn;
  int lo = min(i, j), hi = i ^ j ^ lo;
  int p = b * TRIN + tri_base(lo) + (hi - lo);
  float4 v = *(const float4*)&x3c[(size_t)p * 16 + q * 4];
  if (i == j) { v.x *= 2.f; v.y *= 2.f; v.z *= 2.f; v.w *= 2.f; }
  *(float4*)&out[(size_t)t * 4] = v;
}

extern "C" void kernel_launch(void* const* d_in, const int* in_sizes, int n_in,
                              void* d_out, int out_size, void* d_ws, size_t ws_size,
                              hipStream_t stream) {
  const int*   rel_type  = (const int*)d_in[0];
  const float* rel_error = (const float*)d_in[1];
  const int*   edge_pos  = (const int*)d_in[2];
  const int*   dist      = (const int*)d_in[3];
  const int*   rel_row   = (const int*)d_in[4];
  const float* type_tab = (const float*)d_in[8];
  const float* pos_tab  = (const float*)d_in[9];
  const float* dist_tab = (const float*)d_in[10];
  const float* w1 = (const float*)d_in[11]; const float* b1 = (const float*)d_in[12];
  const float* w2 = (const float*)d_in[13]; const float* b2 = (const float*)d_in[14];
  const float* w3 = (const float*)d_in[15]; const float* b3 = (const float*)d_in[16];
  const float* g1 = (const float*)d_in[17]; const float* be1 = (const float*)d_in[18];
  const float* wf1 = (const float*)d_in[19]; const float* bf1 = (const float*)d_in[20];
  const float* g2 = (const float*)d_in[21]; const float* be2 = (const float*)d_in[22];
  const float* wf2 = (const float*)d_in[23]; const float* bf2 = (const float*)d_in[24];
  const float* g3 = (const float*)d_in[25]; const float* be3 = (const float*)d_in[26];
  const float* wf3 = (const float*)d_in[27]; const float* bf3 = (const float*)d_in[28];

  const int E = in_sizes[0];
  const size_t h3_bytes   = (size_t)E * 512 * 2;        // 204.8 MB (upper bound)
  const size_t x3_bytes   = (size_t)CMPN * 16 * 4;      // 3.3 MB
  const size_t ptr_bytes  = (size_t)(SEGN + 1) * 4;
  const size_t tri_bytes  = (size_t)TRIN * 4;
  const size_t cell_bytes = (size_t)SEGN * 4;
  const size_t cst_bytes  = (size_t)(SEGN + 1) * 4;
  const size_t map_bytes  = (size_t)E * 4;
  const size_t wt_elems   = 32768 + 131072 + 262144 * 3 + 8192;
  const size_t total = h3_bytes + x3_bytes + ptr_bytes + tri_bytes + 2 * cell_bytes +
                       cst_bytes + map_bytes + 1024 + 256 * 4 + wt_elems * 2;
  if (ws_size < total) return;

  char* wp = (char*)d_ws;
  _Float16* h3      = (_Float16*)wp;            wp += h3_bytes;
  float*    x3c     = (float*)wp;               wp += x3_bytes;
  int*      row_ptr = (int*)wp;                 wp += ptr_bytes;
  int*      tri2ij  = (int*)wp;                 wp += tri_bytes;
  int*      cnt     = (int*)wp;                 wp += cell_bytes;
  int*      pre     = (int*)wp;                 wp += cell_bytes;
  int*      cstart  = (int*)wp;                 wp += cst_bytes;
  int*      edge_map= (int*)wp;                 wp += map_bytes;
  int*      bsum    = (int*)wp;                 wp += 256 * 4;
  int*      ekp     = (int*)wp;                 wp += 1024;
  _Float16* w1t     = (_Float16*)wp;
  _Float16* w2t  = w1t + 32768;
  _Float16* w3t  = w2t + 131072;
  _Float16* wf1t = w3t + 262144;
  _Float16* wf2t = wf1t + 262144;
  _Float16* wf3t = wf2t + 262144;
  float*    out  = (float*)d_out;

  k_prep<<<3744, 256, 0, stream>>>(w1, w2, w3, wf1, wf2, wf3,
                                   w1t, w2t, w3t, wf1t, wf2t, wf3t);
  k_cnt<<<(SEGN + 256) / 256, 256, 0, stream>>>(rel_row, row_ptr, cnt, tri2ij, E);
  k_scan1<<<SCAN_NB, 512, 0, stream>>>(cnt, pre, bsum);
  k_scan2<<<1, 256, 0, stream>>>(bsum, ekp);
  k_map<<<SCAN_NB, 512, 0, stream>>>(row_ptr, cnt, pre, bsum, cstart, edge_map);
  k_edge<<<(E + 63) / 64, 512, 0, stream>>>(rel_type, rel_error, edge_pos, edge_map, ekp,
                                            type_tab, pos_tab, w1t, b1, w2t, b2, w3t, b3,
                                            h3);
  k_fc<<<CMPN / 64, 512, 0, stream>>>(h3, cstart, tri2ij, dist, dist_tab,
                                      g1, be1, wf1t, bf1,
                                      g2, be2, wf2t, bf2,
                                      g3, be3, wf3t, bf3, x3c);
  k_sym<<<(SEGN * 4 + 255) / 256, 256, 0, stream>>>(x3c, out);
}

// Round 16
// 375.412 us; speedup vs baseline: 2.1552x; 1.0369x over previous
//
#include <hip/hip_runtime.h>

typedef __attribute__((ext_vector_type(8))) _Float16 half8;
typedef __attribute__((ext_vector_type(4))) _Float16 half4;
typedef __attribute__((ext_vector_type(4))) float f32x4;

constexpr int Bn = 4;
constexpr int Nn = 160;
constexpr int SEGN = Bn * Nn * Nn;        // 102400 segments
constexpr int TRIN = Nn * (Nn + 1) / 2;   // 12880 upper-tri cells per batch
constexpr int CMPN = Bn * TRIN;           // 51520 compact rows (= 805 * 64)
constexpr int SCAN_NB = (SEGN + 511) / 512; // 200 scan blocks

__device__ __forceinline__ int tri_base(int i) { return i * Nn - (i * (i - 1)) / 2; }

// ------- weight prepass: f32 [K][N] -> f16 chunk-blocked [k/32][N][32] -------
__global__ void k_prep(const float* __restrict__ w1, const float* __restrict__ w2,
                       const float* __restrict__ w3, const float* __restrict__ wf1,
                       const float* __restrict__ wf2, const float* __restrict__ wf3,
                       _Float16* __restrict__ o1, _Float16* __restrict__ o2,
                       _Float16* __restrict__ o3, _Float16* __restrict__ of1,
                       _Float16* __restrict__ of2, _Float16* __restrict__ of3) {
  int t = blockIdx.x * 256 + threadIdx.x;
  const float* src; _Float16* dst; int N, local; bool is3 = false;
  if (t < 32768)       { src = w1;  dst = o1;  N = 256; local = t; }
  else if (t < 163840) { src = w2;  dst = o2;  N = 512; local = t - 32768; }
  else if (t < 425984) { src = w3;  dst = o3;  N = 512; local = t - 163840; }
  else if (t < 688128) { src = wf1; dst = of1; N = 512; local = t - 425984; }
  else if (t < 950272) { src = wf2; dst = of2; N = 512; local = t - 688128; }
  else if (t < 958464) { src = wf3; dst = of3; N = 16;  local = t - 950272; is3 = true; }
  else return;
  int k = local / N;
  int n = local - k * N;
  if (is3) dst[n * 512 + k] = (_Float16)src[local];
  else dst[(size_t)((k >> 5) * N + n) * 32 + (k & 31)] = (_Float16)src[local];
}

__device__ __forceinline__ int lower_bound_rr(const int* __restrict__ rel_row, int E, int key) {
  int lo = 0, hi = E;
  while (lo < hi) { int mid = (lo + hi) >> 1; if (rel_row[mid] < key) lo = mid + 1; else hi = mid; }
  return lo;
}

// ------- CSR row pointers + per-cell kept-edge count + tri2ij lookup -------
__global__ void k_cnt(const int* __restrict__ rel_row, int* __restrict__ row_ptr,
                      int* __restrict__ cnt, int* __restrict__ tri2ij, int E) {
  int r = blockIdx.x * 256 + threadIdx.x;
  if (r < TRIN) {
    int lo = 0, hi = Nn - 1;
    while (lo < hi) { int mid = (lo + hi + 1) >> 1; if (tri_base(mid) <= r) lo = mid; else hi = mid - 1; }
    int j = lo + (r - tri_base(lo));
    tri2ij[r] = (lo << 16) | j;
  }
  if (r > SEGN) return;
  int lo = lower_bound_rr(rel_row, E, r);
  row_ptr[r] = lo;
  if (r < SEGN) {
    int hi2 = lower_bound_rr(rel_row, E, r + 1);
    int jj = r % Nn;
    int ii = (r / Nn) % Nn;
    cnt[r] = (ii <= jj) ? (hi2 - lo) : 0;
  }
}

// ------- scan pass 1: per-512-block exclusive prefix + block sums -------
__global__ void k_scan1(const int* __restrict__ cnt, int* __restrict__ pre,
                        int* __restrict__ bsum) {
  __shared__ int tmp[512];
  int t = threadIdx.x, b = blockIdx.x;
  int idx = b * 512 + t;
  int v = (idx < SEGN) ? cnt[idx] : 0;
  tmp[t] = v;
  __syncthreads();
  for (int o = 1; o < 512; o <<= 1) {
    int add = (t >= o) ? tmp[t - o] : 0;
    __syncthreads();
    tmp[t] += add;
    __syncthreads();
  }
  if (idx < SEGN) pre[idx] = tmp[t] - v;
  if (t == 511) bsum[b] = tmp[511];
}

// ------- scan pass 2: scan the 200 block sums (1 block), emit EK -------
__global__ void k_scan2(int* __restrict__ bsum, int* __restrict__ ek) {
  __shared__ int tmp[256];
  int t = threadIdx.x;
  int v = (t < SCAN_NB) ? bsum[t] : 0;
  tmp[t] = v;
  __syncthreads();
  for (int o = 1; o < 256; o <<= 1) {
    int add = (t >= o) ? tmp[t - o] : 0;
    __syncthreads();
    tmp[t] += add;
    __syncthreads();
  }
  if (t < SCAN_NB) bsum[t] = tmp[t] - v;
  if (t == 255) ek[0] = tmp[255];
}

// ------- build cstart[cell] (SEGN+1 entries) and edge_map[compact] -------
__global__ void k_map(const int* __restrict__ row_ptr, const int* __restrict__ cnt,
                      const int* __restrict__ pre, const int* __restrict__ bsum,
                      int* __restrict__ cstart, int* __restrict__ edge_map) {
  int r = blockIdx.x * 512 + threadIdx.x;
  if (r >= SEGN) return;
  int cs = pre[r] + bsum[r >> 9];
  cstart[r] = cs;
  int c = cnt[r];
  int rp = row_ptr[r];
  for (int k = 0; k < c; ++k) edge_map[cs + k] = rp + k;
  if (r == SEGN - 1) cstart[SEGN] = cs + c;
}

// ---------------- MFMA slice, B direct from global (L2-resident) ----------------
template <int MT, int K, int C0, int CN, int NSTRIDE, int NT, bool SP>
__device__ __forceinline__ void do_slice(const _Float16* __restrict__ wt,
                                         const char* a_base, int nbase,
                                         f32x4 (&acc)[MT][NT], int tid) {
  constexpr int rowB = K * 2;
  const int w = tid >> 6, lane = tid & 63, ln15 = lane & 15, kg = lane >> 4;
  const char* wb = (const char*)wt;
#pragma unroll
  for (int c = 0; c < CN; ++c) {
    half8 a[MT], b[NT];
#pragma unroll
    for (int nt = 0; nt < NT; ++nt) {
      int n = nbase + (w * NT + nt) * 16 + ln15;
      b[nt] = *(const half8*)(wb + (size_t)(C0 + c) * (NSTRIDE * 64) + n * 64 + kg * 16);
    }
#pragma unroll
    for (int mt = 0; mt < MT; ++mt) {
      int row = mt * 16 + ln15;
      int byte = (row * rowB + c * 64 + kg * 16) ^ ((row & 7) << 4);
      a[mt] = *(const half8*)(a_base + byte);
    }
    if (SP) __builtin_amdgcn_s_setprio(1);
#pragma unroll
    for (int mt = 0; mt < MT; ++mt)
#pragma unroll
      for (int nt = 0; nt < NT; ++nt)
        acc[mt][nt] = __builtin_amdgcn_mfma_f32_16x16x32_f16(a[mt], b[nt], acc[mt][nt], 0, 0, 0);
    if (SP) __builtin_amdgcn_s_setprio(0);
  }
}

template <int MT, int NT>
__device__ __forceinline__ void init_accn(const float* __restrict__ bias, int nbase,
                                          f32x4 (&acc)[MT][NT], int tid) {
  const int w = tid >> 6, ln15 = tid & 15;
#pragma unroll
  for (int nt = 0; nt < NT; ++nt) {
    float bv = bias[nbase + (w * NT + nt) * 16 + ln15];
    f32x4 s = {bv, bv, bv, bv};
#pragma unroll
    for (int mt = 0; mt < MT; ++mt) acc[mt][nt] = s;
  }
}

// C layout: col = lane&15, row = (lane>>4)*4 + j  [m89 verified]
template <int MT, int NT, bool RELU>
__device__ __forceinline__ void store_hn(char* h, int rowB, int nbase,
                                         const f32x4 (&acc)[MT][NT], int tid) {
  const int w = tid >> 6, lane = tid & 63, ln15 = lane & 15, kg = lane >> 4;
#pragma unroll
  for (int mt = 0; mt < MT; ++mt)
#pragma unroll
    for (int nt = 0; nt < NT; ++nt)
#pragma unroll
      for (int j = 0; j < 4; ++j) {
        int row = mt * 16 + kg * 4 + j;
        int n = nbase + (w * NT + nt) * 16 + ln15;
        float v = acc[mt][nt][j];
        if (RELU) v = fmaxf(v, 0.f);
        *(_Float16*)(h + ((row * rowB + n * 2) ^ ((row & 7) << 4))) = (_Float16)v;
      }
}

// -------- fused edge MLP (MFMA) over COMPACTED kept edges -> compact h3 --------
__global__ __launch_bounds__(512) void k_edge(
    const int* __restrict__ rel_type, const float* __restrict__ rel_error,
    const int* __restrict__ edge_pos, const int* __restrict__ edge_map,
    const int* __restrict__ ekp,
    const float* __restrict__ type_tab, const float* __restrict__ pos_tab,
    const _Float16* __restrict__ w1t, const float* __restrict__ b1,
    const _Float16* __restrict__ w2t, const float* __restrict__ b2,
    const _Float16* __restrict__ w3t, const float* __restrict__ b3,
    _Float16* __restrict__ h3) {
  __shared__ __align__(16) char smem[98304];
  char* h1 = smem;            // [64][256] f16, rowB 512
  char* h2 = smem + 32768;    // [64][512] f16, rowB 1024
  char* e  = smem + 32768;    // [64][128] f16, rowB 256 (dead before h2 written)

  const int tid = threadIdx.x;
  const int e0 = blockIdx.x * 64;
  const int EK = ekp[0];
  if (e0 >= EK) return;

  // ---- build e tile (compact slot -> original edge via edge_map) ----
  {
    int r = tid >> 3, c0 = (tid & 7) * 16;
    int re = edge_map[min(e0 + r, EK - 1)];
    int rt = rel_type[re];
    int ep = edge_pos[re];
#pragma unroll
    for (int s = 0; s < 2; ++s) {
      half8 hv;
#pragma unroll
      for (int q = 0; q < 8; ++q) {
        int cc = c0 + s * 8 + q;
        float v = (cc < 120) ? (rt ? type_tab[rt * 120 + cc] : 0.f)
                             : rel_error[(size_t)re * 8 + (cc - 120)];
        v += pos_tab[ep * 128 + cc];
        hv[q] = (_Float16)v;
      }
      int byte = (r * 256 + (c0 + s * 8) * 2) ^ ((r & 7) << 4);
      *(half8*)(e + byte) = hv;
    }
  }
  __syncthreads();

  {  // layer 1: [64x128]@[128x256] + relu -> h1
    f32x4 acc[4][2];
    init_accn<4, 2>(b1, 0, acc, tid);
    do_slice<4, 128, 0, 4, 256, 2, true>(w1t, e, 0, acc, tid);
    store_hn<4, 2, true>(h1, 512, 0, acc, tid);
  }
  __syncthreads();
  {  // layer 2: [64x256]@[256x512] + relu -> h2
    f32x4 acc[4][4];
    init_accn<4, 4>(b2, 0, acc, tid);
    do_slice<4, 256, 0, 8, 512, 4, true>(w2t, h1, 0, acc, tid);
    store_hn<4, 4, true>(h2, 1024, 0, acc, tid);
  }
  __syncthreads();
  {  // layer 3: [64x512]@[512x512] -> h2 (LDS) -> coalesced compact f16 stream
    f32x4 acc[4][4];
    init_accn<4, 4>(b3, 0, acc, tid);
    do_slice<4, 512, 0, 16, 512, 4, true>(w3t, h2, 0, acc, tid);
    __syncthreads();                       // all h2 reads complete
    store_hn<4, 4, false>(h2, 1024, 0, acc, tid);
    __syncthreads();
    uint4* dst = (uint4*)(h3 + (size_t)e0 * 512);
#pragma unroll
    for (int i = 0; i < 8; ++i) {
      int cidx = tid + i * 512;            // 16B chunk index, 4096 total
      int byteoff = cidx * 16;
      int row = byteoff >> 10;
      uint4 v = *(const uint4*)(h2 + (byteoff ^ ((row & 7) << 4)));
      if (e0 + row < EK) dst[cidx] = v;
    }
  }
}

// -------- gather-max + dist + relu + LN1 -> pre-swizzled f16 rows (rowsA) --------
// wave-per-row; 4 waves/block, 8 rows/wave; ~0 LDS -> high occupancy.
__global__ __launch_bounds__(256) void k_gather(
    const _Float16* __restrict__ h3, const int* __restrict__ cstart,
    const int* __restrict__ tri2ij, const int* __restrict__ dist,
    const float* __restrict__ dist_tab,
    const float* __restrict__ g1, const float* __restrict__ be1,
    _Float16* __restrict__ rowsA) {
  const int w = threadIdx.x >> 6, lane = threadIdx.x & 63;
  const int coff = lane * 8;
  const float* gp = g1 + coff;
  const float* bp = be1 + coff;
  const _Float16 NEGH = (_Float16)(-65504.f);
  const int pbase = blockIdx.x * 32 + w * 8;
  for (int rr = 0; rr < 8; ++rr) {
    int p = pbase + rr;
    if (p >= CMPN) return;
    int b = p / TRIN;
    int ij = tri2ij[p - b * TRIN];
    int gr = (b * Nn + (ij >> 16)) * Nn + (ij & 0xffff);
    int s = cstart[gr], en = cstart[gr + 1];
    int di = dist[gr];
    half8 mx;
#pragma unroll
    for (int q = 0; q < 8; ++q) mx[q] = NEGH;
    int idx = s;
    while (idx + 4 <= en) {
      half8 c0 = *(const half8*)(h3 + (size_t)(idx + 0) * 512 + coff);
      half8 c1 = *(const half8*)(h3 + (size_t)(idx + 1) * 512 + coff);
      half8 c2 = *(const half8*)(h3 + (size_t)(idx + 2) * 512 + coff);
      half8 c3 = *(const half8*)(h3 + (size_t)(idx + 3) * 512 + coff);
      mx = __builtin_elementwise_max(mx, __builtin_elementwise_max(
               __builtin_elementwise_max(c0, c1), __builtin_elementwise_max(c2, c3)));
      idx += 4;
    }
    if (idx + 2 <= en) {
      half8 c0 = *(const half8*)(h3 + (size_t)(idx + 0) * 512 + coff);
      half8 c1 = *(const half8*)(h3 + (size_t)(idx + 1) * 512 + coff);
      mx = __builtin_elementwise_max(mx, __builtin_elementwise_max(c0, c1));
      idx += 2;
    }
    if (idx < en) {
      half8 c0 = *(const half8*)(h3 + (size_t)idx * 512 + coff);
      mx = __builtin_elementwise_max(mx, c0);
    }
    const float* dt = dist_tab + (size_t)di * 512 + coff;
    float v[8]; float s1 = 0.f, s2 = 0.f;
#pragma unroll
    for (int q = 0; q < 8; ++q) {
      float vv = (s == en) ? 0.f : (float)mx[q];
      if (di) vv += dt[q];
      vv = fmaxf(vv, 0.f);
      v[q] = vv; s1 += vv; s2 += vv * vv;
    }
#pragma unroll
    for (int o = 32; o > 0; o >>= 1) { s1 += __shfl_xor(s1, o); s2 += __shfl_xor(s2, o); }
    float mean = s1 * (1.f / 512.f);
    float rs = rsqrtf(s2 * (1.f / 512.f) - mean * mean + 1e-5f);
    half8 ov;
#pragma unroll
    for (int q = 0; q < 8; ++q) ov[q] = (_Float16)((v[q] - mean) * rs * gp[q] + bp[q]);
    // pre-swizzled write: same XOR layout the GEMM kernel's A-reads use
    *(half8*)((char*)rowsA + (size_t)p * 1024 + ((coff * 2) ^ ((p & 7) << 4))) = ov;
  }
}

// ---- in-register epilogue: relu -> LN (shfl + 2-stage LDS) -> store f16 ----
__device__ __forceinline__ void epi_ln_store(f32x4 (&acc)[4][4], char* dst,
                                             float* st1, float* st2,
                                             float* stM, float* stR,
                                             const float* __restrict__ g,
                                             const float* __restrict__ be, int tid) {
  const int w = tid >> 6, lane = tid & 63, ln15 = lane & 15, kg = lane >> 4;
#pragma unroll
  for (int mt = 0; mt < 4; ++mt)
#pragma unroll
    for (int nt = 0; nt < 4; ++nt)
#pragma unroll
      for (int j = 0; j < 4; ++j) acc[mt][nt][j] = fmaxf(acc[mt][nt][j], 0.f);
#pragma unroll
  for (int mt = 0; mt < 4; ++mt)
#pragma unroll
    for (int j = 0; j < 4; ++j) {
      float a = 0.f, b = 0.f;
#pragma unroll
      for (int nt = 0; nt < 4; ++nt) { float v = acc[mt][nt][j]; a += v; b += v * v; }
#pragma unroll
      for (int m = 1; m < 16; m <<= 1) { a += __shfl_xor(a, m); b += __shfl_xor(b, m); }
      if (ln15 == 0) {
        int r = mt * 16 + kg * 4 + j;
        st1[w * 64 + r] = a;
        st2[w * 64 + r] = b;
      }
    }
  __syncthreads();
  if (tid < 64) {
    float a = 0.f, b = 0.f;
#pragma unroll
    for (int ww = 0; ww < 8; ++ww) { a += st1[ww * 64 + tid]; b += st2[ww * 64 + tid]; }
    float mean = a * (1.f / 512.f);
    float var = b * (1.f / 512.f) - mean * mean;
    stM[tid] = mean;
    stR[tid] = rsqrtf(var + 1e-5f);
  }
  __syncthreads();
  float gv[4], bv[4];
#pragma unroll
  for (int nt = 0; nt < 4; ++nt) {
    int n = (w * 4 + nt) * 16 + ln15;
    gv[nt] = g[n]; bv[nt] = be[n];
  }
#pragma unroll
  for (int mt = 0; mt < 4; ++mt)
#pragma unroll
    for (int j = 0; j < 4; ++j) {
      int r = mt * 16 + kg * 4 + j;
      float mean = stM[r], rs = stR[r];
#pragma unroll
      for (int nt = 0; nt < 4; ++nt) {
        int n = (w * 4 + nt) * 16 + ln15;
        float v = (acc[mt][nt][j] - mean) * rs * gv[nt] + bv[nt];
        *(_Float16*)(dst + ((r * 1024 + n * 2) ^ ((r & 7) << 4))) = (_Float16)v;
      }
    }
  __syncthreads();
}

// -------- FC GEMM stack on pre-gathered rows: stage -> fc1 -> LN -> fc2 -> LN -> fc3 --------
__global__ __launch_bounds__(512, 2) void k_fcg(
    const _Float16* __restrict__ rowsA,
    const float* __restrict__ g2, const float* __restrict__ be2,
    const _Float16* __restrict__ wf1t, const float* __restrict__ bf1,
    const float* __restrict__ g3, const float* __restrict__ be3,
    const _Float16* __restrict__ wf2t, const float* __restrict__ bf2,
    const _Float16* __restrict__ wf3t, const float* __restrict__ bf3,
    float* __restrict__ x3c) {
  __shared__ __align__(16) char bufA[65536];  // [64][512] f16, rowB 1024 (pre-swizzled)
  __shared__ float st1[512], st2[512];
  __shared__ float stM[64], stR[64];

  const int tid = threadIdx.x;
  const int p0 = blockIdx.x * 64;

  // ---- stage 64 pre-swizzled rows (64KB) into LDS, fully coalesced ----
  {
    const uint4* src = (const uint4*)((const char*)rowsA + (size_t)p0 * 1024);
    uint4* dst = (uint4*)bufA;
#pragma unroll
    for (int i = 0; i < 8; ++i) dst[tid + i * 512] = src[tid + i * 512];
  }
  __syncthreads();

  {  // fc1: bufA @ wf1 -> LN2 -> bufA (in-place)
    f32x4 acc[4][4];
    init_accn<4, 4>(bf1, 0, acc, tid);
    do_slice<4, 512, 0, 16, 512, 4, true>(wf1t, bufA, 0, acc, tid);
    epi_ln_store(acc, bufA, st1, st2, stM, stR, g2, be2, tid);
  }
  {  // fc2: bufA @ wf2 -> LN3 -> bufA (in-place)
    f32x4 acc[4][4];
    init_accn<4, 4>(bf2, 0, acc, tid);
    do_slice<4, 512, 0, 16, 512, 4, true>(wf2t, bufA, 0, acc, tid);
    epi_ln_store(acc, bufA, st1, st2, stM, stR, g3, be3, tid);
  }
  {  // fc3: bufA @ wf3 [64x512]@[512x16], 4-wave M-split, direct store
    const int w = tid >> 6, lane = tid & 63, ln15 = lane & 15, kg = lane >> 4;
    if (w < 4) {
      f32x4 acc3 = {0.f, 0.f, 0.f, 0.f};
#pragma unroll
      for (int c = 0; c < 16; ++c) {
        half8 b = *(const half8*)((const char*)wf3t + ln15 * 1024 + c * 64 + kg * 16);
        int row = w * 16 + ln15;
        half8 a = *(const half8*)(bufA + ((row * 1024 + c * 64 + kg * 16) ^ ((row & 7) << 4)));
        acc3 = __builtin_amdgcn_mfma_f32_16x16x32_f16(a, b, acc3, 0, 0, 0);
      }
#pragma unroll
      for (int j = 0; j < 4; ++j)
        x3c[(size_t)(p0 + w * 16 + kg * 4 + j) * 16 + ln15] = acc3[j] + bf3[ln15];
    }
  }
}

// ---------------- symmetrize from compact upper-tri x3c ----------------
__global__ void k_sym(const float* __restrict__ x3c, float* __restrict__ out) {
  int t = blockIdx.x * 256 + threadIdx.x;
  if (t >= SEGN * 4) return;
  int q = t & 3;
  int cell = t >> 2;
  int j = cell % Nn;
  int tmp = cell / Nn;
  int i = tmp % Nn;
  int b = tmp / Nn;
  int lo = min(i, j), hi = i ^ j ^ lo;
  int p = b * TRIN + tri_base(lo) + (hi - lo);
  float4 v = *(const float4*)&x3c[(size_t)p * 16 + q * 4];
  if (i == j) { v.x *= 2.f; v.y *= 2.f; v.z *= 2.f; v.w *= 2.f; }
  *(float4*)&out[(size_t)t * 4] = v;
}

extern "C" void kernel_launch(void* const* d_in, const int* in_sizes, int n_in,
                              void* d_out, int out_size, void* d_ws, size_t ws_size,
                              hipStream_t stream) {
  const int*   rel_type  = (const int*)d_in[0];
  const float* rel_error = (const float*)d_in[1];
  const int*   edge_pos  = (const int*)d_in[2];
  const int*   dist      = (const int*)d_in[3];
  const int*   rel_row   = (const int*)d_in[4];
  const float* type_tab = (const float*)d_in[8];
  const float* pos_tab  = (const float*)d_in[9];
  const float* dist_tab = (const float*)d_in[10];
  const float* w1 = (const float*)d_in[11]; const float* b1 = (const float*)d_in[12];
  const float* w2 = (const float*)d_in[13]; const float* b2 = (const float*)d_in[14];
  const float* w3 = (const float*)d_in[15]; const float* b3 = (const float*)d_in[16];
  const float* g1 = (const float*)d_in[17]; const float* be1 = (const float*)d_in[18];
  const float* wf1 = (const float*)d_in[19]; const float* bf1 = (const float*)d_in[20];
  const float* g2 = (const float*)d_in[21]; const float* be2 = (const float*)d_in[22];
  const float* wf2 = (const float*)d_in[23]; const float* bf2 = (const float*)d_in[24];
  const float* g3 = (const float*)d_in[25]; const float* be3 = (const float*)d_in[26];
  const float* wf3 = (const float*)d_in[27]; const float* bf3 = (const float*)d_in[28];

  const int E = in_sizes[0];
  const size_t h3_bytes   = (size_t)E * 512 * 2;        // 204.8 MB (upper bound)
  // rowsA (52.8 MB) overlays the unused h3 tail: EK ~= 0.503*E << 0.55*E boundary
  const size_t rows_off   = ((size_t)E * 55 / 100) * 1024;
  const size_t x3_bytes   = (size_t)CMPN * 16 * 4;      // 3.3 MB
  const size_t ptr_bytes  = (size_t)(SEGN + 1) * 4;
  const size_t tri_bytes  = (size_t)TRIN * 4;
  const size_t cell_bytes = (size_t)SEGN * 4;
  const size_t cst_bytes  = (size_t)(SEGN + 1) * 4;
  const size_t map_bytes  = (size_t)E * 4;
  const size_t wt_elems   = 32768 + 131072 + 262144 * 3 + 8192;
  const size_t total = h3_bytes + x3_bytes + ptr_bytes + tri_bytes + 2 * cell_bytes +
                       cst_bytes + map_bytes + 1024 + 256 * 4 + wt_elems * 2;
  if (ws_size < total) return;

  char* wp = (char*)d_ws;
  _Float16* h3      = (_Float16*)wp;
  _Float16* rowsA   = (_Float16*)(wp + rows_off);       // overlay in h3 tail
  wp += h3_bytes;
  float*    x3c     = (float*)wp;               wp += x3_bytes;
  int*      row_ptr = (int*)wp;                 wp += ptr_bytes;
  int*      tri2ij  = (int*)wp;                 wp += tri_bytes;
  int*      cnt     = (int*)wp;                 wp += cell_bytes;
  int*      pre     = (int*)wp;                 wp += cell_bytes;
  int*      cstart  = (int*)wp;                 wp += cst_bytes;
  int*      edge_map= (int*)wp;                 wp += map_bytes;
  int*      bsum    = (int*)wp;                 wp += 256 * 4;
  int*      ekp     = (int*)wp;                 wp += 1024;
  _Float16* w1t     = (_Float16*)wp;
  _Float16* w2t  = w1t + 32768;
  _Float16* w3t  = w2t + 131072;
  _Float16* wf1t = w3t + 262144;
  _Float16* wf2t = wf1t + 262144;
  _Float16* wf3t = wf2t + 262144;
  float*    out  = (float*)d_out;

  k_prep<<<3744, 256, 0, stream>>>(w1, w2, w3, wf1, wf2, wf3,
                                   w1t, w2t, w3t, wf1t, wf2t, wf3t);
  k_cnt<<<(SEGN + 256) / 256, 256, 0, stream>>>(rel_row, row_ptr, cnt, tri2ij, E);
  k_scan1<<<SCAN_NB, 512, 0, stream>>>(cnt, pre, bsum);
  k_scan2<<<1, 256, 0, stream>>>(bsum, ekp);
  k_map<<<SCAN_NB, 512, 0, stream>>>(row_ptr, cnt, pre, bsum, cstart, edge_map);
  k_edge<<<(E + 63) / 64, 512, 0, stream>>>(rel_type, rel_error, edge_pos, edge_map, ekp,
                                            type_tab, pos_tab, w1t, b1, w2t, b2, w3t, b3,
                                            h3);
  k_gather<<<(CMPN + 31) / 32, 256, 0, stream>>>(h3, cstart, tri2ij, dist, dist_tab,
                                                 g1, be1, rowsA);
  k_fcg<<<CMPN / 64, 512, 0, stream>>>(rowsA,
                                       g2, be2, wf1t, bf1,
                                       g3, be3, wf2t, bf2,
                                       wf3t, bf3, x3c);
  k_sym<<<(SEGN * 4 + 255) / 256, 256, 0, stream>>>(x3c, out);
}